// Round 1
// baseline (1750.895 us; speedup 1.0000x reference)
//
#include <hip/hip_runtime.h>
#include <math.h>

#define BGRAPH 128
#define ETOT   (128*4096)   // 524288
#define K1 256
#define K2 128
#define K3 64

// ---------------- small utility kernels ----------------
__global__ void fill_f32(float* __restrict__ p, float v, int n){
  int i = blockIdx.x*blockDim.x + threadIdx.x;
  if (i < n) p[i] = v;
}
__global__ void set_meta(int* slot, int v){ *slot = v; }

// ---------------- dense GEMM: Y[n][128] = X[n][128] @ W[128][128] ----------------
__global__ void gemm_nn128(const float* __restrict__ X, const float* __restrict__ W,
                           float* __restrict__ Y){
  __shared__ float sW[128*128];   // 64 KB
  __shared__ float sX[32*128];    // 16 KB
  int t = threadIdx.x;            // 256 threads
  const float4* W4 = (const float4*)W;
  float4* sW4 = (float4*)sW;
  #pragma unroll
  for (int i = 0; i < 16; ++i) sW4[t + i*256] = W4[t + i*256];
  int row0 = blockIdx.x * 32;
  const float4* X4 = (const float4*)(X + (size_t)row0*128);
  float4* sX4 = (float4*)sX;
  #pragma unroll
  for (int i = 0; i < 4; ++i) sX4[t + i*256] = X4[t + i*256];
  __syncthreads();
  int c  = t & 127;
  int rg = (t >> 7) * 16;
  float acc[16];
  #pragma unroll
  for (int i = 0; i < 16; ++i) acc[i] = 0.f;
  for (int kk = 0; kk < 128; ++kk){
    float w = sW[kk*128 + c];
    #pragma unroll
    for (int i = 0; i < 16; ++i)
      acc[i] = fmaf(sX[(rg+i)*128 + kk], w, acc[i]);
  }
  #pragma unroll
  for (int i = 0; i < 16; ++i)
    Y[(size_t)(row0+rg+i)*128 + c] = acc[i];
}

// ---------------- degree / dinv ----------------
__global__ void deg_scatter(const int* __restrict__ dst, const int* __restrict__ pe,
                            float* __restrict__ deg){
  int ne = *pe;
  int T = gridDim.x*blockDim.x;
  for (int i = blockIdx.x*blockDim.x + threadIdx.x; i < ne; i += T)
    atomicAdd(&deg[dst[i]], 1.0f);
}
__global__ void to_dinv(float* __restrict__ d, int n){
  int i = blockIdx.x*blockDim.x + threadIdx.x;
  if (i < n) d[i] = 1.0f / sqrtf(d[i]);
}

// ---------------- agg = dinv^2 * hx + b, then edge scatter, then relu ----------------
__global__ void init_agg(const float* __restrict__ hx, const float* __restrict__ dinv,
                         const float* __restrict__ bias, float* __restrict__ agg, int n32){
  int i = blockIdx.x*blockDim.x + threadIdx.x;
  if (i >= n32) return;
  int node = i >> 5, f4 = i & 31;
  float dv = dinv[node]; float d2 = dv*dv;
  float4 v  = ((const float4*)hx)[i];
  float4 bv = ((const float4*)bias)[f4];
  float4 r = { fmaf(d2,v.x,bv.x), fmaf(d2,v.y,bv.y), fmaf(d2,v.z,bv.z), fmaf(d2,v.w,bv.w) };
  ((float4*)agg)[i] = r;
}
__global__ void scatter_feat(const int* __restrict__ src, const int* __restrict__ dst,
                             const int* __restrict__ pe, const float* __restrict__ dinv,
                             const float* __restrict__ hx, float* __restrict__ agg){
  long long total = ((long long)(*pe)) << 5;   // 32 float4-lanes per edge
  long long T = (long long)gridDim.x * blockDim.x;
  for (long long i = blockIdx.x*(long long)blockDim.x + threadIdx.x; i < total; i += T){
    int e  = (int)(i >> 5), f4 = (int)(i & 31);
    int s = src[e], d = dst[e];
    float c = dinv[s] * dinv[d];
    float4 v = ((const float4*)(hx + (size_t)s*128))[f4];
    float* o = agg + (size_t)d*128 + (f4<<2);
    atomicAdd(o+0, c*v.x); atomicAdd(o+1, c*v.y);
    atomicAdd(o+2, c*v.z); atomicAdd(o+3, c*v.w);
  }
}
__global__ void relu4(float* __restrict__ p, int n4){
  int i = blockIdx.x*blockDim.x + threadIdx.x;
  if (i >= n4) return;
  float4 v = ((float4*)p)[i];
  v.x = fmaxf(v.x,0.f); v.y = fmaxf(v.y,0.f);
  v.z = fmaxf(v.z,0.f); v.w = fmaxf(v.w,0.f);
  ((float4*)p)[i] = v;
}

// ---------------- score: hs = h @ Ws  (GEMV), score = dinv^2*hs + bs + scatter ----------------
__global__ void gemv_score(const float* __restrict__ Hm, const float* __restrict__ Ws,
                           float* __restrict__ hs, int n){
  int t = threadIdx.x;                 // 256 threads, 16 lanes per node
  int node = blockIdx.x*16 + (t >> 4);
  if (node >= n) return;
  int l = t & 15;
  const float4* h4 = (const float4*)(Hm + (size_t)node*128);
  float4 a = h4[2*l], b = h4[2*l+1];
  float4 w0 = ((const float4*)Ws)[2*l], w1 = ((const float4*)Ws)[2*l+1];
  float s = a.x*w0.x + a.y*w0.y + a.z*w0.z + a.w*w0.w
          + b.x*w1.x + b.y*w1.y + b.z*w1.z + b.w*w1.w;
  s += __shfl_xor(s, 8, 16);
  s += __shfl_xor(s, 4, 16);
  s += __shfl_xor(s, 2, 16);
  s += __shfl_xor(s, 1, 16);
  if (l == 0) hs[node] = s;
}
__global__ void init_score(const float* __restrict__ hs, const float* __restrict__ dinv,
                           const float* __restrict__ bs, float* __restrict__ score, int n){
  int i = blockIdx.x*blockDim.x + threadIdx.x;
  if (i >= n) return;
  float dv = dinv[i];
  score[i] = fmaf(dv*dv, hs[i], bs[0]);
}
__global__ void scatter_score(const int* __restrict__ src, const int* __restrict__ dst,
                              const int* __restrict__ pe, const float* __restrict__ dinv,
                              const float* __restrict__ hs, float* __restrict__ score){
  int ne = *pe;
  int T = gridDim.x*blockDim.x;
  for (int i = blockIdx.x*blockDim.x + threadIdx.x; i < ne; i += T){
    int s = src[i], d = dst[i];
    atomicAdd(&score[d], dinv[s]*dinv[d]*hs[s]);
  }
}

// ---------------- per-graph top-k via bitonic sort (value desc, index asc) ----------------
template<int NP, int K>
__global__ void topk_kernel(const float* __restrict__ score, float* __restrict__ topv,
                            int* __restrict__ perm, int* __restrict__ newidx){
  __shared__ float sv[NP];
  __shared__ int   si[NP];
  int b = blockIdx.x, t = threadIdx.x;
  sv[t] = score[b*NP + t];
  si[t] = t;
  newidx[b*NP + t] = -1;
  __syncthreads();
  for (int ksz = 2; ksz <= NP; ksz <<= 1){
    for (int j = ksz >> 1; j > 0; j >>= 1){
      int p = t ^ j;
      if (p > t){
        bool dir = ((t & ksz) == 0);     // region sorted "comes-first first"
        float v1 = sv[t], v2 = sv[p];
        int   i1 = si[t], i2 = si[p];
        bool pFirst = (v2 > v1) || (v2 == v1 && i2 < i1);
        if (pFirst == dir){ sv[t]=v2; si[t]=i2; sv[p]=v1; si[p]=i1; }
      }
      __syncthreads();
    }
  }
  if (t < K){
    int g = b*NP + si[t];
    topv[b*K + t] = sv[t];
    perm[b*K + t] = g;
    newidx[g] = b*K + t;
  }
}

// ---------------- xnew = h[perm] * tanh(topv) ----------------
__global__ void gather_scale(const float* __restrict__ Hm, const int* __restrict__ perm,
                             const float* __restrict__ topv, float* __restrict__ xnew, int m){
  int i = blockIdx.x*blockDim.x + threadIdx.x;   // m*32 float4 units
  if (i >= m*32) return;
  int j = i >> 5, f4 = i & 31;
  float tm = tanhf(topv[j]);
  float4 v = ((const float4*)(Hm + (size_t)perm[j]*128))[f4];
  v.x *= tm; v.y *= tm; v.z *= tm; v.w *= tm;
  ((float4*)xnew)[i] = v;
}

// ---------------- edge compaction ----------------
__global__ void compact_edges(const int* __restrict__ src, const int* __restrict__ dst,
                              const int* __restrict__ pe, const int* __restrict__ newidx,
                              int* __restrict__ osrc, int* __restrict__ odst,
                              int* __restrict__ cnt){
  int ne = *pe;
  int T = gridDim.x*blockDim.x;
  for (int i = blockIdx.x*blockDim.x + threadIdx.x; i < ne; i += T){
    int ns = newidx[src[i]], nd = newidx[dst[i]];
    if ((ns | nd) >= 0){
      int pos = atomicAdd(cnt, 1);
      osrc[pos] = ns; odst[pos] = nd;
    }
  }
}

// ---------------- readout: out[b][0:128]+=max, out[b][128:256]+=mean ----------------
__global__ void readout_k(const float* __restrict__ xnew, float* __restrict__ out, int k){
  int b = blockIdx.x, f = threadIdx.x;   // 128 threads
  float mx = -INFINITY, sm = 0.f;
  const float* p = xnew + (size_t)b*k*128 + f;
  for (int j = 0; j < k; ++j){
    float v = p[(size_t)j*128];
    mx = fmaxf(mx, v); sm += v;
  }
  out[b*256 + f]       += mx;
  out[b*256 + 128 + f] += sm / (float)k;
}

// ---------------- host launcher ----------------
extern "C" void kernel_launch(void* const* d_in, const int* in_sizes, int n_in,
                              void* d_out, int out_size, void* d_ws, size_t ws_size,
                              hipStream_t stream){
  const float* x0 = (const float*)d_in[0];
  const int*   ei = (const int*)d_in[1];
  const float* Wl[3]  = {(const float*)d_in[3], (const float*)d_in[7],  (const float*)d_in[11]};
  const float* bl[3]  = {(const float*)d_in[4], (const float*)d_in[8],  (const float*)d_in[12]};
  const float* Wsl[3] = {(const float*)d_in[5], (const float*)d_in[9],  (const float*)d_in[13]};
  const float* bsl[3] = {(const float*)d_in[6], (const float*)d_in[10], (const float*)d_in[14]};

  // workspace layout (floats)
  float* A    = (float*)d_ws;                   // hx           65536*128
  float* C    = A + (size_t)65536*128;          // agg/h        65536*128
  float* D    = C + (size_t)65536*128;          // xnew / next x 32768*128
  float* dinv = D + (size_t)32768*128;          // 65536
  float* hs   = dinv + 65536;                   // 65536
  float* score= hs + 65536;                     // 65536
  float* topv = score + 65536;                  // 32768
  int* newidx = (int*)(topv + 32768);           // 65536
  int* perm   = newidx + 65536;                 // 32768
  int* ea_s   = perm + 32768;                   // 524288
  int* ea_d   = ea_s + ETOT;
  int* eb_s   = ea_d + ETOT;
  int* eb_d   = eb_s + ETOT;
  int* meta   = eb_d + ETOT;                    // 16 ints

  hipMemsetAsync(meta, 0, 64, stream);
  hipMemsetAsync(d_out, 0, (size_t)out_size*sizeof(float), stream);
  set_meta<<<1,1,0,stream>>>(meta, ETOT);

  float* out = (float*)d_out;

  auto level = [&](const float* xin, int n_tot, int np, int k,
                   const float* W, const float* b, const float* Ws, const float* bs,
                   const int* es, const int* ed, const int* pe,
                   int* oes, int* oed, int* ocnt){
    fill_f32<<<(n_tot+255)/256, 256, 0, stream>>>(dinv, 1.0f, n_tot);
    deg_scatter<<<512, 256, 0, stream>>>(ed, pe, dinv);
    to_dinv<<<(n_tot+255)/256, 256, 0, stream>>>(dinv, n_tot);
    gemm_nn128<<<n_tot/32, 256, 0, stream>>>(xin, W, A);
    init_agg<<<(n_tot*32+255)/256, 256, 0, stream>>>(A, dinv, b, C, n_tot*32);
    scatter_feat<<<4096, 256, 0, stream>>>(es, ed, pe, dinv, A, C);
    relu4<<<(n_tot*32+255)/256, 256, 0, stream>>>(C, n_tot*32);
    gemv_score<<<n_tot/16, 256, 0, stream>>>(C, Ws, hs, n_tot);
    init_score<<<(n_tot+255)/256, 256, 0, stream>>>(hs, dinv, bs, score, n_tot);
    scatter_score<<<512, 256, 0, stream>>>(es, ed, pe, dinv, hs, score);
    if (np == 512)      topk_kernel<512,256><<<BGRAPH,512,0,stream>>>(score, topv, perm, newidx);
    else if (np == 256) topk_kernel<256,128><<<BGRAPH,256,0,stream>>>(score, topv, perm, newidx);
    else                topk_kernel<128, 64><<<BGRAPH,128,0,stream>>>(score, topv, perm, newidx);
    gather_scale<<<(BGRAPH*k*32+255)/256, 256, 0, stream>>>(C, perm, topv, D, BGRAPH*k);
    if (oes) compact_edges<<<512, 256, 0, stream>>>(es, ed, pe, newidx, oes, oed, ocnt);
    readout_k<<<BGRAPH, 128, 0, stream>>>(D, out, k);
  };

  // level 1: n_per=512 -> K1=256
  level(x0, 65536, 512, K1, Wl[0], bl[0], Wsl[0], bsl[0],
        ei, ei + ETOT, meta + 0, ea_s, ea_d, meta + 1);
  // level 2: n_per=256 -> K2=128   (x = D, consumed by the GEMM before D is overwritten)
  level(D, 32768, 256, K2, Wl[1], bl[1], Wsl[1], bsl[1],
        ea_s, ea_d, meta + 1, eb_s, eb_d, meta + 2);
  // level 3: n_per=128 -> K3=64
  level(D, 16384, 128, K3, Wl[2], bl[2], Wsl[2], bsl[2],
        eb_s, eb_d, meta + 2, nullptr, nullptr, nullptr);
}

// Round 2
// 606.691 us; speedup vs baseline: 2.8860x; 2.8860x over previous
//
#include <hip/hip_runtime.h>
#include <math.h>

#define BGRAPH 128
#define ETOT   (128*4096)   // 524288
#define EPG    4096
#define K1 256
#define K2 128
#define K3 64

// ---------------- small utility kernels ----------------
__global__ void zero_i32(int* __restrict__ p, int n){
  int i = blockIdx.x*blockDim.x + threadIdx.x;
  if (i < n) p[i] = 0;
}
__global__ void set_meta(int* slot, int v){ *slot = v; }

// ---------------- dense GEMM: Y[n][128] = X[n][128] @ W[128][128] ----------------
__global__ void gemm_nn128(const float* __restrict__ X, const float* __restrict__ W,
                           float* __restrict__ Y){
  __shared__ float sW[128*128];   // 64 KB
  __shared__ float sX[32*128];    // 16 KB
  int t = threadIdx.x;            // 256 threads
  const float4* W4 = (const float4*)W;
  float4* sW4 = (float4*)sW;
  #pragma unroll
  for (int i = 0; i < 16; ++i) sW4[t + i*256] = W4[t + i*256];
  int row0 = blockIdx.x * 32;
  const float4* X4 = (const float4*)(X + (size_t)row0*128);
  float4* sX4 = (float4*)sX;
  #pragma unroll
  for (int i = 0; i < 4; ++i) sX4[t + i*256] = X4[t + i*256];
  __syncthreads();
  int c  = t & 127;
  int rg = (t >> 7) * 16;
  float acc[16];
  #pragma unroll
  for (int i = 0; i < 16; ++i) acc[i] = 0.f;
  for (int kk = 0; kk < 128; ++kk){
    float w = sW[kk*128 + c];
    #pragma unroll
    for (int i = 0; i < 16; ++i)
      acc[i] = fmaf(sX[(rg+i)*128 + kk], w, acc[i]);
  }
  #pragma unroll
  for (int i = 0; i < 16; ++i)
    Y[(size_t)(row0+rg+i)*128 + c] = acc[i];
}

// ---------------- degree count (int) + dinv ----------------
__global__ void deg_cnt(const int* __restrict__ dst, const int* __restrict__ pe,
                        int* __restrict__ cnt){
  int ne = *pe;
  int T = gridDim.x*blockDim.x;
  for (int i = blockIdx.x*blockDim.x + threadIdx.x; i < ne; i += T)
    atomicAdd(&cnt[dst[i]], 1);
}
__global__ void dinv_from_cnt(const int* __restrict__ cnt, float* __restrict__ dinv, int n){
  int i = blockIdx.x*blockDim.x + threadIdx.x;
  if (i < n) dinv[i] = rsqrtf((float)cnt[i] + 1.0f);
}

// ---------------- per-graph exclusive scan -> absolute CSR offsets ----------------
template<int NP>
__global__ void scan_graph(const int* __restrict__ cnt, int* __restrict__ off,
                           int* __restrict__ cursor){
  __shared__ int s[NP];
  int g = blockIdx.x, t = threadIdx.x;
  int v = cnt[g*NP + t];
  s[t] = v;
  __syncthreads();
  for (int d = 1; d < NP; d <<= 1){
    int u = (t >= d) ? s[t-d] : 0;
    __syncthreads();
    s[t] += u;
    __syncthreads();
  }
  off[g*NP + t] = g*EPG + (s[t] - v);   // exclusive, absolute
  cursor[g*NP + t] = 0;
}

// ---------------- CSR fill ----------------
__global__ void fill_csr(const int* __restrict__ src, const int* __restrict__ dst,
                         const int* __restrict__ pe, const int* __restrict__ off,
                         int* __restrict__ cursor, int* __restrict__ csr){
  int ne = *pe;
  int T = gridDim.x*blockDim.x;
  for (int i = blockIdx.x*blockDim.x + threadIdx.x; i < ne; i += T){
    int d = dst[i];
    int slot = off[d] + atomicAdd(&cursor[d], 1);
    csr[slot] = src[i];
  }
}

// ---------------- fused aggregation: one wave per dst node ----------------
// out[d] = relu( sum_e dinv[s]*dinv[d]*hx[s] + dinv[d]^2*hx[d] + b )
__global__ void gather_agg(const float* __restrict__ hx, const int* __restrict__ csr,
                           const int* __restrict__ off, const int* __restrict__ cnt,
                           const float* __restrict__ dinv, const float* __restrict__ bias,
                           float* __restrict__ out, int n){
  int node = blockIdx.x*4 + (threadIdx.x >> 6);
  if (node >= n) return;
  int lane = threadIdx.x & 63;
  float dd = dinv[node];
  int o = off[node], deg = cnt[node];
  float2 acc = {0.f, 0.f};
  for (int e = 0; e < deg; ++e){
    int s = csr[o + e];                       // wave-uniform broadcast
    float c = dinv[s] * dd;
    float2 v = ((const float2*)(hx + (size_t)s*128))[lane];
    acc.x = fmaf(c, v.x, acc.x);
    acc.y = fmaf(c, v.y, acc.y);
  }
  float2 own = ((const float2*)(hx + (size_t)node*128))[lane];
  float2 bv  = ((const float2*)bias)[lane];
  float d2 = dd*dd;
  float2 r;
  r.x = fmaxf(fmaf(d2, own.x, acc.x + bv.x), 0.f);
  r.y = fmaxf(fmaf(d2, own.y, acc.y + bv.y), 0.f);
  ((float2*)(out + (size_t)node*128))[lane] = r;
}

// ---------------- score: hs = h @ Ws  (GEMV) ----------------
__global__ void gemv_score(const float* __restrict__ Hm, const float* __restrict__ Ws,
                           float* __restrict__ hs, int n){
  int t = threadIdx.x;                 // 256 threads, 16 lanes per node
  int node = blockIdx.x*16 + (t >> 4);
  if (node >= n) return;
  int l = t & 15;
  const float4* h4 = (const float4*)(Hm + (size_t)node*128);
  float4 a = h4[2*l], b = h4[2*l+1];
  float4 w0 = ((const float4*)Ws)[2*l], w1 = ((const float4*)Ws)[2*l+1];
  float s = a.x*w0.x + a.y*w0.y + a.z*w0.z + a.w*w0.w
          + b.x*w1.x + b.y*w1.y + b.z*w1.z + b.w*w1.w;
  s += __shfl_xor(s, 8, 16);
  s += __shfl_xor(s, 4, 16);
  s += __shfl_xor(s, 2, 16);
  s += __shfl_xor(s, 1, 16);
  if (l == 0) hs[node] = s;
}

// ---------------- fused score aggregation (per-node gather) ----------------
__global__ void score_gather(const float* __restrict__ hs, const int* __restrict__ csr,
                             const int* __restrict__ off, const int* __restrict__ cnt,
                             const float* __restrict__ dinv, const float* __restrict__ bs,
                             float* __restrict__ score, int n){
  int i = blockIdx.x*blockDim.x + threadIdx.x;
  if (i >= n) return;
  float dd = dinv[i];
  int o = off[i], deg = cnt[i];
  float acc = 0.f;
  for (int e = 0; e < deg; ++e){
    int s = csr[o + e];
    acc = fmaf(dinv[s]*dd, hs[s], acc);
  }
  score[i] = acc + fmaf(dd*dd, hs[i], bs[0]);
}

// ---------------- per-graph top-k via bitonic sort (value desc, index asc) ----------------
template<int NP, int K>
__global__ void topk_kernel(const float* __restrict__ score, float* __restrict__ topv,
                            int* __restrict__ perm, int* __restrict__ newidx){
  __shared__ float sv[NP];
  __shared__ int   si[NP];
  int b = blockIdx.x, t = threadIdx.x;
  sv[t] = score[b*NP + t];
  si[t] = t;
  newidx[b*NP + t] = -1;
  __syncthreads();
  for (int ksz = 2; ksz <= NP; ksz <<= 1){
    for (int j = ksz >> 1; j > 0; j >>= 1){
      int p = t ^ j;
      if (p > t){
        bool dir = ((t & ksz) == 0);
        float v1 = sv[t], v2 = sv[p];
        int   i1 = si[t], i2 = si[p];
        bool pFirst = (v2 > v1) || (v2 == v1 && i2 < i1);
        if (pFirst == dir){ sv[t]=v2; si[t]=i2; sv[p]=v1; si[p]=i1; }
      }
      __syncthreads();
    }
  }
  if (t < K){
    int g = b*NP + si[t];
    topv[b*K + t] = sv[t];
    perm[b*K + t] = g;
    newidx[g] = b*K + t;
  }
}

// ---------------- xnew = h[perm] * tanh(topv) ----------------
__global__ void gather_scale(const float* __restrict__ Hm, const int* __restrict__ perm,
                             const float* __restrict__ topv, float* __restrict__ xnew, int m){
  int i = blockIdx.x*blockDim.x + threadIdx.x;   // m*32 float4 units
  if (i >= m*32) return;
  int j = i >> 5, f4 = i & 31;
  float tm = tanhf(topv[j]);
  float4 v = ((const float4*)(Hm + (size_t)perm[j]*128))[f4];
  v.x *= tm; v.y *= tm; v.z *= tm; v.w *= tm;
  ((float4*)xnew)[i] = v;
}

// ---------------- edge compaction ----------------
__global__ void compact_edges(const int* __restrict__ src, const int* __restrict__ dst,
                              const int* __restrict__ pe, const int* __restrict__ newidx,
                              int* __restrict__ osrc, int* __restrict__ odst,
                              int* __restrict__ cnt){
  int ne = *pe;
  int T = gridDim.x*blockDim.x;
  for (int i = blockIdx.x*blockDim.x + threadIdx.x; i < ne; i += T){
    int ns = newidx[src[i]], nd = newidx[dst[i]];
    if ((ns | nd) >= 0){
      int pos = atomicAdd(cnt, 1);
      osrc[pos] = ns; odst[pos] = nd;
    }
  }
}

// ---------------- readout: out[b][0:128]+=max, out[b][128:256]+=mean ----------------
__global__ void readout_k(const float* __restrict__ xnew, float* __restrict__ out, int k){
  int b = blockIdx.x, f = threadIdx.x;   // 128 threads
  float mx = -INFINITY, sm = 0.f;
  const float* p = xnew + (size_t)b*k*128 + f;
  for (int j = 0; j < k; ++j){
    float v = p[(size_t)j*128];
    mx = fmaxf(mx, v); sm += v;
  }
  out[b*256 + f]       += mx;
  out[b*256 + 128 + f] += sm / (float)k;
}

// ---------------- host launcher ----------------
extern "C" void kernel_launch(void* const* d_in, const int* in_sizes, int n_in,
                              void* d_out, int out_size, void* d_ws, size_t ws_size,
                              hipStream_t stream){
  const float* x0 = (const float*)d_in[0];
  const int*   ei = (const int*)d_in[1];
  const float* Wl[3]  = {(const float*)d_in[3], (const float*)d_in[7],  (const float*)d_in[11]};
  const float* bl[3]  = {(const float*)d_in[4], (const float*)d_in[8],  (const float*)d_in[12]};
  const float* Wsl[3] = {(const float*)d_in[5], (const float*)d_in[9],  (const float*)d_in[13]};
  const float* bsl[3] = {(const float*)d_in[6], (const float*)d_in[10], (const float*)d_in[14]};

  // workspace layout (floats)
  float* A     = (float*)d_ws;                   // hx            65536*128
  float* C     = A + (size_t)65536*128;          // h (post agg)  65536*128
  float* D     = C + (size_t)65536*128;          // xnew / next x 32768*128
  float* dinv  = D + (size_t)32768*128;          // 65536
  float* hs    = dinv + 65536;                   // 65536
  float* score = hs + 65536;                     // 65536
  float* topv  = score + 65536;                  // 32768
  int* newidx  = (int*)(topv + 32768);           // 65536
  int* perm    = newidx + 65536;                 // 32768
  int* ea_s    = perm + 32768;                   // 524288
  int* ea_d    = ea_s + ETOT;
  int* eb_s    = ea_d + ETOT;
  int* eb_d    = eb_s + ETOT;
  int* meta    = eb_d + ETOT;                    // 16 ints
  int* cnt     = meta + 16;                      // 65536
  int* off     = cnt + 65536;                    // 65536
  int* cursor  = off + 65536;                    // 65536
  int* csr     = cursor + 65536;                 // 524288

  hipMemsetAsync(meta, 0, 64, stream);
  hipMemsetAsync(d_out, 0, (size_t)out_size*sizeof(float), stream);
  set_meta<<<1,1,0,stream>>>(meta, ETOT);

  float* out = (float*)d_out;

  auto level = [&](const float* xin, int n_tot, int np, int k,
                   const float* W, const float* b, const float* Ws, const float* bs,
                   const int* es, const int* ed, const int* pe,
                   int* oes, int* oed, int* ocnt){
    zero_i32<<<(n_tot+255)/256, 256, 0, stream>>>(cnt, n_tot);
    deg_cnt<<<512, 256, 0, stream>>>(ed, pe, cnt);
    dinv_from_cnt<<<(n_tot+255)/256, 256, 0, stream>>>(cnt, dinv, n_tot);
    if (np == 512)      scan_graph<512><<<BGRAPH,512,0,stream>>>(cnt, off, cursor);
    else if (np == 256) scan_graph<256><<<BGRAPH,256,0,stream>>>(cnt, off, cursor);
    else                scan_graph<128><<<BGRAPH,128,0,stream>>>(cnt, off, cursor);
    fill_csr<<<512, 256, 0, stream>>>(es, ed, pe, off, cursor, csr);
    gemm_nn128<<<n_tot/32, 256, 0, stream>>>(xin, W, A);
    gather_agg<<<(n_tot+3)/4, 256, 0, stream>>>(A, csr, off, cnt, dinv, b, C, n_tot);
    gemv_score<<<n_tot/16, 256, 0, stream>>>(C, Ws, hs, n_tot);
    score_gather<<<(n_tot+255)/256, 256, 0, stream>>>(hs, csr, off, cnt, dinv, bs, score, n_tot);
    if (np == 512)      topk_kernel<512,256><<<BGRAPH,512,0,stream>>>(score, topv, perm, newidx);
    else if (np == 256) topk_kernel<256,128><<<BGRAPH,256,0,stream>>>(score, topv, perm, newidx);
    else                topk_kernel<128, 64><<<BGRAPH,128,0,stream>>>(score, topv, perm, newidx);
    gather_scale<<<(BGRAPH*k*32+255)/256, 256, 0, stream>>>(C, perm, topv, D, BGRAPH*k);
    if (oes) compact_edges<<<512, 256, 0, stream>>>(es, ed, pe, newidx, oes, oed, ocnt);
    readout_k<<<BGRAPH, 128, 0, stream>>>(D, out, k);
  };

  // level 1: n_per=512 -> K1=256
  level(x0, 65536, 512, K1, Wl[0], bl[0], Wsl[0], bsl[0],
        ei, ei + ETOT, meta + 0, ea_s, ea_d, meta + 1);
  // level 2: n_per=256 -> K2=128
  level(D, 32768, 256, K2, Wl[1], bl[1], Wsl[1], bsl[1],
        ea_s, ea_d, meta + 1, eb_s, eb_d, meta + 2);
  // level 3: n_per=128 -> K3=64
  level(D, 16384, 128, K3, Wl[2], bl[2], Wsl[2], bsl[2],
        eb_s, eb_d, meta + 2, nullptr, nullptr, nullptr);
}

// Round 3
// 478.192 us; speedup vs baseline: 3.6615x; 1.2687x over previous
//
#include <hip/hip_runtime.h>
#include <math.h>

#define BGRAPH 128
#define ETOT   (128*4096)   // 524288
#define EPG    4096
#define K1 256
#define K2 128
#define K3 64

// ---------------- dense GEMM: Y[n][128] = X[n][128] @ W[128][128] ----------------
__global__ void gemm_nn128(const float* __restrict__ X, const float* __restrict__ W,
                           float* __restrict__ Y){
  __shared__ float sW[128*128];   // 64 KB
  __shared__ float sX[32*128];    // 16 KB
  int t = threadIdx.x;            // 256 threads
  const float4* W4 = (const float4*)W;
  float4* sW4 = (float4*)sW;
  #pragma unroll
  for (int i = 0; i < 16; ++i) sW4[t + i*256] = W4[t + i*256];
  int row0 = blockIdx.x * 32;
  const float4* X4 = (const float4*)(X + (size_t)row0*128);
  float4* sX4 = (float4*)sX;
  #pragma unroll
  for (int i = 0; i < 4; ++i) sX4[t + i*256] = X4[t + i*256];
  __syncthreads();
  int c  = t & 127;
  int rg = (t >> 7) * 16;
  float acc[16];
  #pragma unroll
  for (int i = 0; i < 16; ++i) acc[i] = 0.f;
  for (int kk = 0; kk < 128; ++kk){
    float w = sW[kk*128 + c];
    #pragma unroll
    for (int i = 0; i < 16; ++i)
      acc[i] = fmaf(sX[(rg+i)*128 + kk], w, acc[i]);
  }
  #pragma unroll
  for (int i = 0; i < 16; ++i)
    Y[(size_t)(row0+rg+i)*128 + c] = acc[i];
}

// ---------------- degree count over fixed-length masked edge list ----------------
__global__ void deg_cnt(const int* __restrict__ dst, int* __restrict__ cnt){
  int i = blockIdx.x*blockDim.x + threadIdx.x;   // ETOT threads
  int d = dst[i];
  if (d >= 0) atomicAdd(&cnt[d], 1);
}

// ---------------- per-graph exclusive scan -> absolute CSR offsets + dinv ----------------
template<int NP>
__global__ void scan_graph(const int* __restrict__ cnt, int* __restrict__ off,
                           int* __restrict__ cursor, float* __restrict__ dinv){
  __shared__ int s[NP];
  int g = blockIdx.x, t = threadIdx.x;
  int v = cnt[g*NP + t];
  dinv[g*NP + t] = rsqrtf((float)v + 1.0f);
  s[t] = v;
  __syncthreads();
  for (int d = 1; d < NP; d <<= 1){
    int u = (t >= d) ? s[t-d] : 0;
    __syncthreads();
    s[t] += u;
    __syncthreads();
  }
  off[g*NP + t] = g*EPG + (s[t] - v);   // exclusive, absolute
  cursor[g*NP + t] = 0;
}

// ---------------- CSR fill (masked) ----------------
__global__ void fill_csr(const int* __restrict__ src, const int* __restrict__ dst,
                         const int* __restrict__ off, int* __restrict__ cursor,
                         int* __restrict__ csr){
  int i = blockIdx.x*blockDim.x + threadIdx.x;   // ETOT threads
  int d = dst[i];
  if (d < 0) return;
  int slot = off[d] + atomicAdd(&cursor[d], 1);
  csr[slot] = src[i];
}

// ---------------- fused aggregation: one wave per dst node ----------------
// out[d] = relu( sum_e dinv[s]*dinv[d]*hx[s] + dinv[d]^2*hx[d] + b )
__global__ void gather_agg(const float* __restrict__ hx, const int* __restrict__ csr,
                           const int* __restrict__ off, const int* __restrict__ cnt,
                           const float* __restrict__ dinv, const float* __restrict__ bias,
                           float* __restrict__ out, int n){
  int node = blockIdx.x*4 + (threadIdx.x >> 6);
  if (node >= n) return;
  int lane = threadIdx.x & 63;
  float dd = dinv[node];
  int o = off[node], deg = cnt[node];
  float2 acc = {0.f, 0.f};
  for (int e = 0; e < deg; ++e){
    int s = csr[o + e];                       // wave-uniform broadcast
    float c = dinv[s] * dd;
    float2 v = ((const float2*)(hx + (size_t)s*128))[lane];
    acc.x = fmaf(c, v.x, acc.x);
    acc.y = fmaf(c, v.y, acc.y);
  }
  float2 own = ((const float2*)(hx + (size_t)node*128))[lane];
  float2 bv  = ((const float2*)bias)[lane];
  float d2 = dd*dd;
  float2 r;
  r.x = fmaxf(fmaf(d2, own.x, acc.x + bv.x), 0.f);
  r.y = fmaxf(fmaf(d2, own.y, acc.y + bv.y), 0.f);
  ((float2*)(out + (size_t)node*128))[lane] = r;
}

// ---------------- score: hs = h @ Ws  (GEMV) ----------------
__global__ void gemv_score(const float* __restrict__ Hm, const float* __restrict__ Ws,
                           float* __restrict__ hs, int n){
  int t = threadIdx.x;                 // 256 threads, 16 lanes per node
  int node = blockIdx.x*16 + (t >> 4);
  if (node >= n) return;
  int l = t & 15;
  const float4* h4 = (const float4*)(Hm + (size_t)node*128);
  float4 a = h4[2*l], b = h4[2*l+1];
  float4 w0 = ((const float4*)Ws)[2*l], w1 = ((const float4*)Ws)[2*l+1];
  float s = a.x*w0.x + a.y*w0.y + a.z*w0.z + a.w*w0.w
          + b.x*w1.x + b.y*w1.y + b.z*w1.z + b.w*w1.w;
  s += __shfl_xor(s, 8, 16);
  s += __shfl_xor(s, 4, 16);
  s += __shfl_xor(s, 2, 16);
  s += __shfl_xor(s, 1, 16);
  if (l == 0) hs[node] = s;
}

// ---------------- fused score aggregation (per-node gather) ----------------
__global__ void score_gather(const float* __restrict__ hs, const int* __restrict__ csr,
                             const int* __restrict__ off, const int* __restrict__ cnt,
                             const float* __restrict__ dinv, const float* __restrict__ bs,
                             float* __restrict__ score, int n){
  int i = blockIdx.x*blockDim.x + threadIdx.x;
  if (i >= n) return;
  float dd = dinv[i];
  int o = off[i], deg = cnt[i];
  float acc = 0.f;
  for (int e = 0; e < deg; ++e){
    int s = csr[o + e];
    acc = fmaf(dinv[s]*dd, hs[s], acc);
  }
  score[i] = acc + fmaf(dd*dd, hs[i], bs[0]);
}

// ---------------- per-graph top-k via bitonic sort (value desc, index asc) ----------------
template<int NP, int K>
__global__ void topk_kernel(const float* __restrict__ score, float* __restrict__ topv,
                            int* __restrict__ perm, int* __restrict__ newidx){
  __shared__ float sv[NP];
  __shared__ int   si[NP];
  int b = blockIdx.x, t = threadIdx.x;
  sv[t] = score[b*NP + t];
  si[t] = t;
  newidx[b*NP + t] = -1;
  __syncthreads();
  for (int ksz = 2; ksz <= NP; ksz <<= 1){
    for (int j = ksz >> 1; j > 0; j >>= 1){
      int p = t ^ j;
      if (p > t){
        bool dir = ((t & ksz) == 0);
        float v1 = sv[t], v2 = sv[p];
        int   i1 = si[t], i2 = si[p];
        bool pFirst = (v2 > v1) || (v2 == v1 && i2 < i1);
        if (pFirst == dir){ sv[t]=v2; si[t]=i2; sv[p]=v1; si[p]=i1; }
      }
      __syncthreads();
    }
  }
  if (t < K){
    int g = b*NP + si[t];
    topv[b*K + t] = sv[t];
    perm[b*K + t] = g;
    newidx[g] = b*K + t;
  }
}

// ---------------- xnew = h[perm] * tanh(topv) ----------------
__global__ void gather_scale(const float* __restrict__ Hm, const int* __restrict__ perm,
                             const float* __restrict__ topv, float* __restrict__ xnew, int m){
  int i = blockIdx.x*blockDim.x + threadIdx.x;   // m*32 float4 units
  if (i >= m*32) return;
  int j = i >> 5, f4 = i & 31;
  float tm = tanhf(topv[j]);
  float4 v = ((const float4*)(Hm + (size_t)perm[j]*128))[f4];
  v.x *= tm; v.y *= tm; v.z *= tm; v.w *= tm;
  ((float4*)xnew)[i] = v;
}

// ---------------- edge remap (replaces compaction; no global cursor) ----------------
__global__ void remap_edges(const int* __restrict__ is, const int* __restrict__ id,
                            const int* __restrict__ newidx,
                            int* __restrict__ os, int* __restrict__ od){
  int i = blockIdx.x*blockDim.x + threadIdx.x;   // ETOT threads
  int s = is[i], d = id[i];
  int ns = -1, nd = -1;
  if ((s | d) >= 0){ ns = newidx[s]; nd = newidx[d]; }
  bool v = (ns >= 0) & (nd >= 0);
  os[i] = v ? ns : -1;
  od[i] = v ? nd : -1;
}

// ---------------- readout: out[b][0:128]+=max, out[b][128:256]+=mean ----------------
__global__ void readout_k(const float* __restrict__ xnew, float* __restrict__ out, int k){
  int b = blockIdx.x, f = threadIdx.x;   // 128 threads
  float mx = -INFINITY, sm = 0.f;
  const float* p = xnew + (size_t)b*k*128 + f;
  for (int j = 0; j < k; ++j){
    float v = p[(size_t)j*128];
    mx = fmaxf(mx, v); sm += v;
  }
  out[b*256 + f]       += mx;
  out[b*256 + 128 + f] += sm / (float)k;
}

// ---------------- host launcher ----------------
extern "C" void kernel_launch(void* const* d_in, const int* in_sizes, int n_in,
                              void* d_out, int out_size, void* d_ws, size_t ws_size,
                              hipStream_t stream){
  const float* x0 = (const float*)d_in[0];
  const int*   ei = (const int*)d_in[1];
  const float* Wl[3]  = {(const float*)d_in[3], (const float*)d_in[7],  (const float*)d_in[11]};
  const float* bl[3]  = {(const float*)d_in[4], (const float*)d_in[8],  (const float*)d_in[12]};
  const float* Wsl[3] = {(const float*)d_in[5], (const float*)d_in[9],  (const float*)d_in[13]};
  const float* bsl[3] = {(const float*)d_in[6], (const float*)d_in[10], (const float*)d_in[14]};

  // workspace layout (floats)
  float* A     = (float*)d_ws;                   // hx            65536*128
  float* C     = A + (size_t)65536*128;          // h (post agg)  65536*128
  float* D     = C + (size_t)65536*128;          // xnew / next x 32768*128
  float* dinv  = D + (size_t)32768*128;          // 65536
  float* hs    = dinv + 65536;                   // 65536
  float* score = hs + 65536;                     // 65536
  float* topv  = score + 65536;                  // 32768
  int* newidx  = (int*)(topv + 32768);           // 65536
  int* perm    = newidx + 65536;                 // 32768
  int* ea_s    = perm + 32768;                   // 524288
  int* ea_d    = ea_s + ETOT;
  int* eb_s    = ea_d + ETOT;
  int* eb_d    = eb_s + ETOT;
  int* cnt     = eb_d + ETOT;                    // 65536
  int* off     = cnt + 65536;                    // 65536
  int* cursor  = off + 65536;                    // 65536
  int* csr     = cursor + 65536;                 // 524288

  hipMemsetAsync(d_out, 0, (size_t)out_size*sizeof(float), stream);

  float* out = (float*)d_out;

  auto level = [&](const float* xin, int n_tot, int np, int k,
                   const float* W, const float* b, const float* Ws, const float* bs,
                   const int* es, const int* ed,
                   int* oes, int* oed){
    hipMemsetAsync(cnt, 0, (size_t)n_tot*sizeof(int), stream);
    deg_cnt<<<ETOT/256, 256, 0, stream>>>(ed, cnt);
    if (np == 512)      scan_graph<512><<<BGRAPH,512,0,stream>>>(cnt, off, cursor, dinv);
    else if (np == 256) scan_graph<256><<<BGRAPH,256,0,stream>>>(cnt, off, cursor, dinv);
    else                scan_graph<128><<<BGRAPH,128,0,stream>>>(cnt, off, cursor, dinv);
    fill_csr<<<ETOT/256, 256, 0, stream>>>(es, ed, off, cursor, csr);
    gemm_nn128<<<n_tot/32, 256, 0, stream>>>(xin, W, A);
    gather_agg<<<(n_tot+3)/4, 256, 0, stream>>>(A, csr, off, cnt, dinv, b, C, n_tot);
    gemv_score<<<n_tot/16, 256, 0, stream>>>(C, Ws, hs, n_tot);
    score_gather<<<(n_tot+255)/256, 256, 0, stream>>>(hs, csr, off, cnt, dinv, bs, score, n_tot);
    if (np == 512)      topk_kernel<512,256><<<BGRAPH,512,0,stream>>>(score, topv, perm, newidx);
    else if (np == 256) topk_kernel<256,128><<<BGRAPH,256,0,stream>>>(score, topv, perm, newidx);
    else                topk_kernel<128, 64><<<BGRAPH,128,0,stream>>>(score, topv, perm, newidx);
    gather_scale<<<(BGRAPH*k*32+255)/256, 256, 0, stream>>>(C, perm, topv, D, BGRAPH*k);
    if (oes) remap_edges<<<ETOT/256, 256, 0, stream>>>(es, ed, newidx, oes, oed);
    readout_k<<<BGRAPH, 128, 0, stream>>>(D, out, k);
  };

  // level 1: n_per=512 -> K1=256
  level(x0, 65536, 512, K1, Wl[0], bl[0], Wsl[0], bsl[0],
        ei, ei + ETOT, ea_s, ea_d);
  // level 2: n_per=256 -> K2=128
  level(D, 32768, 256, K2, Wl[1], bl[1], Wsl[1], bsl[1],
        ea_s, ea_d, eb_s, eb_d);
  // level 3: n_per=128 -> K3=64
  level(D, 16384, 128, K3, Wl[2], bl[2], Wsl[2], bsl[2],
        eb_s, eb_d, nullptr, nullptr);
}

// Round 4
// 386.257 us; speedup vs baseline: 4.5330x; 1.2380x over previous
//
#include <hip/hip_runtime.h>
#include <math.h>

#define BGRAPH 128
#define ETOT   (128*4096)   // 524288
#define EPG    4096
#define K1 256
#define K2 128
#define K3 64

// ---------------- tiled GEMM: Y[n][128] = X[n][128] @ W[128][128] ----------------
// BM=64, BN=128, BK=32; 256 threads; per-thread 8 rows x 4 cols.
__global__ __launch_bounds__(256) void gemm_tile(const float* __restrict__ X,
                                                 const float* __restrict__ W,
                                                 float* __restrict__ Y){
  __shared__ float sA[32*64];    // X tile transposed [k][m]  (8 KB)
  __shared__ float sB[32*128];   // W tile [k][c]            (16 KB)
  int tid = threadIdx.x;
  int row0 = blockIdx.x * 64;
  int tx = tid & 31;             // col group: cols tx*4..+4
  int ty = tid >> 5;             // row group: rows ty*8..+8
  int xm  = tid >> 2;            // staging: row within tile
  int xf4 = tid & 3;             // staging: which float4 pair
  float acc[8][4];
  #pragma unroll
  for (int i = 0; i < 8; ++i)
    #pragma unroll
    for (int j = 0; j < 4; ++j) acc[i][j] = 0.f;

  for (int k0 = 0; k0 < 128; k0 += 32){
    const float4* Wg = (const float4*)(W + k0*128);
    float4* sB4 = (float4*)sB;
    #pragma unroll
    for (int j = 0; j < 4; ++j) sB4[tid + j*256] = Wg[tid + j*256];
    const float4* Xg = (const float4*)(X + (size_t)(row0 + xm)*128 + k0);
    #pragma unroll
    for (int j = 0; j < 2; ++j){
      float4 v = Xg[xf4 + j*4];
      int kk = (xf4 + j*4) * 4;
      sA[(kk+0)*64 + xm] = v.x;
      sA[(kk+1)*64 + xm] = v.y;
      sA[(kk+2)*64 + xm] = v.z;
      sA[(kk+3)*64 + xm] = v.w;
    }
    __syncthreads();
    #pragma unroll
    for (int kk = 0; kk < 32; ++kk){
      float4 b  = *(const float4*)(sB + kk*128 + tx*4);
      float4 a0 = *(const float4*)(sA + kk*64 + ty*8);
      float4 a1 = *(const float4*)(sA + kk*64 + ty*8 + 4);
      float av[8] = {a0.x,a0.y,a0.z,a0.w,a1.x,a1.y,a1.z,a1.w};
      #pragma unroll
      for (int i = 0; i < 8; ++i){
        acc[i][0] = fmaf(av[i], b.x, acc[i][0]);
        acc[i][1] = fmaf(av[i], b.y, acc[i][1]);
        acc[i][2] = fmaf(av[i], b.z, acc[i][2]);
        acc[i][3] = fmaf(av[i], b.w, acc[i][3]);
      }
    }
    __syncthreads();
  }
  #pragma unroll
  for (int i = 0; i < 8; ++i)
    *(float4*)(Y + (size_t)(row0 + ty*8 + i)*128 + tx*4) = *(float4*)acc[i];
}

// ---------------- degree count over fixed-length edge list (level 1 only) ----------------
__global__ void deg_cnt(const int* __restrict__ dst, int* __restrict__ cnt){
  int i = blockIdx.x*blockDim.x + threadIdx.x;   // ETOT threads
  int d = dst[i];
  if (d >= 0) atomicAdd(&cnt[d], 1);
}

// ---------------- per-graph exclusive scan -> absolute CSR offsets + dinv ----------------
template<int NP>
__global__ void scan_graph(const int* __restrict__ cnt, int* __restrict__ off,
                           int* __restrict__ cursor, float* __restrict__ dinv){
  __shared__ int s[NP];
  int g = blockIdx.x, t = threadIdx.x;
  int v = cnt[g*NP + t];
  dinv[g*NP + t] = rsqrtf((float)v + 1.0f);
  s[t] = v;
  __syncthreads();
  for (int d = 1; d < NP; d <<= 1){
    int u = (t >= d) ? s[t-d] : 0;
    __syncthreads();
    s[t] += u;
    __syncthreads();
  }
  off[g*NP + t] = g*EPG + (s[t] - v);   // exclusive, absolute
  cursor[g*NP + t] = 0;
}

// ---------------- CSR fill (masked) ----------------
__global__ void fill_csr(const int* __restrict__ src, const int* __restrict__ dst,
                         const int* __restrict__ off, int* __restrict__ cursor,
                         int* __restrict__ csr){
  int i = blockIdx.x*blockDim.x + threadIdx.x;   // ETOT threads
  int d = dst[i];
  if (d < 0) return;
  int slot = off[d] + atomicAdd(&cursor[d], 1);
  csr[slot] = src[i];
}

// ---------------- fused aggregation + score GEMV: one wave per dst node ----------------
// h[d] = relu( sum_e dinv[s]*dinv[d]*hx[s] + dinv[d]^2*hx[d] + b );  hs[d] = h[d]·Ws
__global__ void gather_agg(const float* __restrict__ hx, const int* __restrict__ csr,
                           const int* __restrict__ off, const int* __restrict__ cnt,
                           const float* __restrict__ dinv, const float* __restrict__ bias,
                           const float* __restrict__ Ws, float* __restrict__ out,
                           float* __restrict__ hs, int n){
  int node = blockIdx.x*4 + (threadIdx.x >> 6);
  if (node >= n) return;
  int lane = threadIdx.x & 63;
  float dd = dinv[node];
  int o = off[node], deg = cnt[node];
  float2 acc = {0.f, 0.f};
  for (int e = 0; e < deg; ++e){
    int s = csr[o + e];                       // wave-uniform broadcast
    float c = dinv[s] * dd;
    float2 v = ((const float2*)(hx + (size_t)s*128))[lane];
    acc.x = fmaf(c, v.x, acc.x);
    acc.y = fmaf(c, v.y, acc.y);
  }
  float2 own = ((const float2*)(hx + (size_t)node*128))[lane];
  float2 bv  = ((const float2*)bias)[lane];
  float d2 = dd*dd;
  float2 r;
  r.x = fmaxf(fmaf(d2, own.x, acc.x + bv.x), 0.f);
  r.y = fmaxf(fmaf(d2, own.y, acc.y + bv.y), 0.f);
  ((float2*)(out + (size_t)node*128))[lane] = r;
  // fused hs = h · Ws
  float2 w = ((const float2*)Ws)[lane];
  float p = r.x*w.x + r.y*w.y;
  p += __shfl_xor(p, 32);
  p += __shfl_xor(p, 16);
  p += __shfl_xor(p, 8);
  p += __shfl_xor(p, 4);
  p += __shfl_xor(p, 2);
  p += __shfl_xor(p, 1);
  if (lane == 0) hs[node] = p;
}

// ---------------- fused score aggregation (per-node gather) ----------------
__global__ void score_gather(const float* __restrict__ hs, const int* __restrict__ csr,
                             const int* __restrict__ off, const int* __restrict__ cnt,
                             const float* __restrict__ dinv, const float* __restrict__ bs,
                             float* __restrict__ score, int n){
  int i = blockIdx.x*blockDim.x + threadIdx.x;
  if (i >= n) return;
  float dd = dinv[i];
  int o = off[i], deg = cnt[i];
  float acc = 0.f;
  for (int e = 0; e < deg; ++e){
    int s = csr[o + e];
    acc = fmaf(dinv[s]*dd, hs[s], acc);
  }
  score[i] = acc + fmaf(dd*dd, hs[i], bs[0]);
}

// ---------------- per-graph top-k via bitonic sort (value desc, index asc) ----------------
template<int NP, int K>
__global__ void topk_kernel(const float* __restrict__ score, float* __restrict__ topv,
                            int* __restrict__ perm, int* __restrict__ newidx){
  __shared__ float sv[NP];
  __shared__ int   si[NP];
  int b = blockIdx.x, t = threadIdx.x;
  sv[t] = score[b*NP + t];
  si[t] = t;
  newidx[b*NP + t] = -1;
  __syncthreads();
  for (int ksz = 2; ksz <= NP; ksz <<= 1){
    for (int j = ksz >> 1; j > 0; j >>= 1){
      int p = t ^ j;
      if (p > t){
        bool dir = ((t & ksz) == 0);
        float v1 = sv[t], v2 = sv[p];
        int   i1 = si[t], i2 = si[p];
        bool pFirst = (v2 > v1) || (v2 == v1 && i2 < i1);
        if (pFirst == dir){ sv[t]=v2; si[t]=i2; sv[p]=v1; si[p]=i1; }
      }
      __syncthreads();
    }
  }
  if (t < K){
    int g = b*NP + si[t];
    topv[b*K + t] = sv[t];
    perm[b*K + t] = g;
    newidx[g] = b*K + t;
  }
}

// ---------------- xnew = h[perm] * tanh(topv) ----------------
__global__ void gather_scale(const float* __restrict__ Hm, const int* __restrict__ perm,
                             const float* __restrict__ topv, float* __restrict__ xnew, int m){
  int i = blockIdx.x*blockDim.x + threadIdx.x;   // m*32 float4 units
  if (i >= m*32) return;
  int j = i >> 5, f4 = i & 31;
  float tm = tanhf(topv[j]);
  float4 v = ((const float4*)(Hm + (size_t)perm[j]*128))[f4];
  v.x *= tm; v.y *= tm; v.z *= tm; v.w *= tm;
  ((float4*)xnew)[i] = v;
}

// ---------------- edge remap + next-level degree count ----------------
__global__ void remap_edges_cnt(const int* __restrict__ is, const int* __restrict__ id,
                                const int* __restrict__ newidx,
                                int* __restrict__ os, int* __restrict__ od,
                                int* __restrict__ cnt){
  int i = blockIdx.x*blockDim.x + threadIdx.x;   // ETOT threads
  int s = is[i], d = id[i];
  int ns = -1, nd = -1;
  if ((s | d) >= 0){ ns = newidx[s]; nd = newidx[d]; }
  bool v = (ns >= 0) & (nd >= 0);
  os[i] = v ? ns : -1;
  od[i] = v ? nd : -1;
  if (v) atomicAdd(&cnt[nd], 1);
}

// ---------------- readout: out[b][0:128]+=max, out[b][128:256]+=mean ----------------
__global__ void readout_k(const float* __restrict__ xnew, float* __restrict__ out, int k){
  int b = blockIdx.x, f = threadIdx.x;   // 128 threads
  float mx = -INFINITY, sm = 0.f;
  const float* p = xnew + (size_t)b*k*128 + f;
  for (int j = 0; j < k; ++j){
    float v = p[(size_t)j*128];
    mx = fmaxf(mx, v); sm += v;
  }
  out[b*256 + f]       += mx;
  out[b*256 + 128 + f] += sm / (float)k;
}

// ---------------- host launcher ----------------
extern "C" void kernel_launch(void* const* d_in, const int* in_sizes, int n_in,
                              void* d_out, int out_size, void* d_ws, size_t ws_size,
                              hipStream_t stream){
  const float* x0 = (const float*)d_in[0];
  const int*   ei = (const int*)d_in[1];
  const float* Wl[3]  = {(const float*)d_in[3], (const float*)d_in[7],  (const float*)d_in[11]};
  const float* bl[3]  = {(const float*)d_in[4], (const float*)d_in[8],  (const float*)d_in[12]};
  const float* Wsl[3] = {(const float*)d_in[5], (const float*)d_in[9],  (const float*)d_in[13]};
  const float* bsl[3] = {(const float*)d_in[6], (const float*)d_in[10], (const float*)d_in[14]};

  // workspace layout (floats)
  float* A     = (float*)d_ws;                   // hx            65536*128
  float* C     = A + (size_t)65536*128;          // h (post agg)  65536*128
  float* D     = C + (size_t)65536*128;          // xnew / next x 32768*128
  float* dinv  = D + (size_t)32768*128;          // 65536
  float* hs    = dinv + 65536;                   // 65536
  float* score = hs + 65536;                     // 65536
  float* topv  = score + 65536;                  // 32768
  int* newidx  = (int*)(topv + 32768);           // 65536
  int* perm    = newidx + 65536;                 // 32768
  int* ea_s    = perm + 32768;                   // 524288
  int* ea_d    = ea_s + ETOT;
  int* eb_s    = ea_d + ETOT;
  int* eb_d    = eb_s + ETOT;
  int* cntA    = eb_d + ETOT;                    // 65536
  int* cntB    = cntA + 65536;                   // 32768
  int* cntC    = cntB + 32768;                   // 16384
  int* off     = cntC + 16384;                   // 65536
  int* cursor  = off + 65536;                    // 65536
  int* csr     = cursor + 65536;                 // 524288

  hipMemsetAsync(cntA, 0, (size_t)(65536+32768+16384)*sizeof(int), stream);
  hipMemsetAsync(d_out, 0, (size_t)out_size*sizeof(float), stream);

  float* out = (float*)d_out;

  auto level = [&](const float* xin, int n_tot, int np, int k,
                   const float* W, const float* b, const float* Ws, const float* bs,
                   const int* es, const int* ed, int* cnt,
                   int* oes, int* oed, int* ocnt){
    if (np == 512)      scan_graph<512><<<BGRAPH,512,0,stream>>>(cnt, off, cursor, dinv);
    else if (np == 256) scan_graph<256><<<BGRAPH,256,0,stream>>>(cnt, off, cursor, dinv);
    else                scan_graph<128><<<BGRAPH,128,0,stream>>>(cnt, off, cursor, dinv);
    fill_csr<<<ETOT/256, 256, 0, stream>>>(es, ed, off, cursor, csr);
    gemm_tile<<<n_tot/64, 256, 0, stream>>>(xin, W, A);
    gather_agg<<<(n_tot+3)/4, 256, 0, stream>>>(A, csr, off, cnt, dinv, b, Ws, C, hs, n_tot);
    score_gather<<<(n_tot+255)/256, 256, 0, stream>>>(hs, csr, off, cnt, dinv, bs, score, n_tot);
    if (np == 512)      topk_kernel<512,256><<<BGRAPH,512,0,stream>>>(score, topv, perm, newidx);
    else if (np == 256) topk_kernel<256,128><<<BGRAPH,256,0,stream>>>(score, topv, perm, newidx);
    else                topk_kernel<128, 64><<<BGRAPH,128,0,stream>>>(score, topv, perm, newidx);
    gather_scale<<<(BGRAPH*k*32+255)/256, 256, 0, stream>>>(C, perm, topv, D, BGRAPH*k);
    if (oes) remap_edges_cnt<<<ETOT/256, 256, 0, stream>>>(es, ed, newidx, oes, oed, ocnt);
    readout_k<<<BGRAPH, 128, 0, stream>>>(D, out, k);
  };

  // level 1: degree of the initial (all-valid) edges
  deg_cnt<<<ETOT/256, 256, 0, stream>>>(ei + ETOT, cntA);
  level(x0, 65536, 512, K1, Wl[0], bl[0], Wsl[0], bsl[0],
        ei, ei + ETOT, cntA, ea_s, ea_d, cntB);
  // level 2
  level(D, 32768, 256, K2, Wl[1], bl[1], Wsl[1], bsl[1],
        ea_s, ea_d, cntB, eb_s, eb_d, cntC);
  // level 3
  level(D, 16384, 128, K3, Wl[2], bl[2], Wsl[2], bsl[2],
        eb_s, eb_d, cntC, nullptr, nullptr, nullptr);
}

// Round 5
// 297.276 us; speedup vs baseline: 5.8898x; 1.2993x over previous
//
#include <hip/hip_runtime.h>
#include <math.h>

#define BGRAPH 128
#define ETOT   (128*4096)   // 524288
#define EPG    4096
#define K1 256
#define K2 128
#define K3 64

// ---------------- tiled GEMM: Y[n][128] = X[n][128] @ W[128][128] ----------------
__global__ __launch_bounds__(256) void gemm_tile(const float* __restrict__ X,
                                                 const float* __restrict__ W,
                                                 float* __restrict__ Y){
  __shared__ float sA[32*64];
  __shared__ float sB[32*128];
  int tid = threadIdx.x;
  int row0 = blockIdx.x * 64;
  int tx = tid & 31;
  int ty = tid >> 5;
  int xm  = tid >> 2;
  int xf4 = tid & 3;
  float acc[8][4];
  #pragma unroll
  for (int i = 0; i < 8; ++i)
    #pragma unroll
    for (int j = 0; j < 4; ++j) acc[i][j] = 0.f;

  for (int k0 = 0; k0 < 128; k0 += 32){
    const float4* Wg = (const float4*)(W + k0*128);
    float4* sB4 = (float4*)sB;
    #pragma unroll
    for (int j = 0; j < 4; ++j) sB4[tid + j*256] = Wg[tid + j*256];
    const float4* Xg = (const float4*)(X + (size_t)(row0 + xm)*128 + k0);
    #pragma unroll
    for (int j = 0; j < 2; ++j){
      float4 v = Xg[xf4 + j*4];
      int kk = (xf4 + j*4) * 4;
      sA[(kk+0)*64 + xm] = v.x;
      sA[(kk+1)*64 + xm] = v.y;
      sA[(kk+2)*64 + xm] = v.z;
      sA[(kk+3)*64 + xm] = v.w;
    }
    __syncthreads();
    #pragma unroll
    for (int kk = 0; kk < 32; ++kk){
      float4 b  = *(const float4*)(sB + kk*128 + tx*4);
      float4 a0 = *(const float4*)(sA + kk*64 + ty*8);
      float4 a1 = *(const float4*)(sA + kk*64 + ty*8 + 4);
      float av[8] = {a0.x,a0.y,a0.z,a0.w,a1.x,a1.y,a1.z,a1.w};
      #pragma unroll
      for (int i = 0; i < 8; ++i){
        acc[i][0] = fmaf(av[i], b.x, acc[i][0]);
        acc[i][1] = fmaf(av[i], b.y, acc[i][1]);
        acc[i][2] = fmaf(av[i], b.z, acc[i][2]);
        acc[i][3] = fmaf(av[i], b.w, acc[i][3]);
      }
    }
    __syncthreads();
  }
  #pragma unroll
  for (int i = 0; i < 8; ++i)
    *(float4*)(Y + (size_t)(row0 + ty*8 + i)*128 + tx*4) = *(float4*)acc[i];
}

// ---------------- degree count (level 1 only) ----------------
__global__ void deg_cnt(const int* __restrict__ dst, int* __restrict__ cnt){
  int i = blockIdx.x*blockDim.x + threadIdx.x;
  int d = dst[i];
  if (d >= 0) atomicAdd(&cnt[d], 1);
}

// ---------------- per-graph exclusive scan -> CSR offsets + dinv ----------------
template<int NP>
__global__ void scan_graph(const int* __restrict__ cnt, int* __restrict__ off,
                           int* __restrict__ cursor, float* __restrict__ dinv){
  __shared__ int s[NP];
  int g = blockIdx.x, t = threadIdx.x;
  int v = cnt[g*NP + t];
  dinv[g*NP + t] = rsqrtf((float)v + 1.0f);
  s[t] = v;
  __syncthreads();
  for (int d = 1; d < NP; d <<= 1){
    int u = (t >= d) ? s[t-d] : 0;
    __syncthreads();
    s[t] += u;
    __syncthreads();
  }
  off[g*NP + t] = g*EPG + (s[t] - v);
  cursor[g*NP + t] = 0;
}

// ---------------- CSR fill (masked) ----------------
__global__ void fill_csr(const int* __restrict__ src, const int* __restrict__ dst,
                         const int* __restrict__ off, int* __restrict__ cursor,
                         int* __restrict__ csr){
  int i = blockIdx.x*blockDim.x + threadIdx.x;
  int d = dst[i];
  if (d < 0) return;
  int slot = off[d] + atomicAdd(&cursor[d], 1);
  csr[slot] = src[i];
}

// ---------------- fused aggregation + score GEMV, graph->XCD pinned ----------------
// h[d] = relu( sum_e dinv[s]*dinv[d]*hx[s] + dinv[d]^2*hx[d] + b );  hs[d] = h[d]·Ws
__global__ void gather_agg(const float* __restrict__ hx, const int* __restrict__ csr,
                           const int* __restrict__ off, const int* __restrict__ cnt,
                           const float* __restrict__ dinv, const float* __restrict__ bias,
                           const float* __restrict__ Ws, float* __restrict__ out,
                           float* __restrict__ hs, int npg, int n){
  // pin all blocks of one graph to one XCD (assumes XCD = blockIdx % 8 round-robin)
  int bpg = npg >> 2;                 // blocks per graph (4 nodes/block)
  int x = blockIdx.x >> 3, r = blockIdx.x & 7;
  int pos = x % bpg, grp = x / bpg;   // grp in [0,16)
  int g = grp*8 + r;
  int node = g*npg + pos*4 + (threadIdx.x >> 6);
  if (node >= n) return;
  int lane = threadIdx.x & 63;
  float dd = dinv[node];
  int o = off[node], deg = cnt[node];
  float2 acc = {0.f, 0.f};
  for (int e = 0; e < deg; ++e){
    int s = csr[o + e];
    float c = dinv[s] * dd;
    float2 v = ((const float2*)(hx + (size_t)s*128))[lane];
    acc.x = fmaf(c, v.x, acc.x);
    acc.y = fmaf(c, v.y, acc.y);
  }
  float2 own = ((const float2*)(hx + (size_t)node*128))[lane];
  float2 bv  = ((const float2*)bias)[lane];
  float d2 = dd*dd;
  float2 rr;
  rr.x = fmaxf(fmaf(d2, own.x, acc.x + bv.x), 0.f);
  rr.y = fmaxf(fmaf(d2, own.y, acc.y + bv.y), 0.f);
  ((float2*)(out + (size_t)node*128))[lane] = rr;
  float2 w = ((const float2*)Ws)[lane];
  float p = rr.x*w.x + rr.y*w.y;
  p += __shfl_xor(p, 32);
  p += __shfl_xor(p, 16);
  p += __shfl_xor(p, 8);
  p += __shfl_xor(p, 4);
  p += __shfl_xor(p, 2);
  p += __shfl_xor(p, 1);
  if (lane == 0) hs[node] = p;
}

// ---------------- score aggregation (per-node gather) ----------------
__global__ void score_gather(const float* __restrict__ hs, const int* __restrict__ csr,
                             const int* __restrict__ off, const int* __restrict__ cnt,
                             const float* __restrict__ dinv, const float* __restrict__ bs,
                             float* __restrict__ score, int n){
  int i = blockIdx.x*blockDim.x + threadIdx.x;
  if (i >= n) return;
  float dd = dinv[i];
  int o = off[i], deg = cnt[i];
  float acc = 0.f;
  for (int e = 0; e < deg; ++e){
    int s = csr[o + e];
    acc = fmaf(dinv[s]*dd, hs[s], acc);
  }
  score[i] = acc + fmaf(dd*dd, hs[i], bs[0]);
}

// ---------------- per-graph top-k via bitonic sort (value desc, index asc) ----------------
template<int NP, int K>
__global__ void topk_kernel(const float* __restrict__ score, float* __restrict__ topv,
                            int* __restrict__ perm, int* __restrict__ newidx){
  __shared__ float sv[NP];
  __shared__ int   si[NP];
  int b = blockIdx.x, t = threadIdx.x;
  sv[t] = score[b*NP + t];
  si[t] = t;
  newidx[b*NP + t] = -1;
  __syncthreads();
  for (int ksz = 2; ksz <= NP; ksz <<= 1){
    for (int j = ksz >> 1; j > 0; j >>= 1){
      int p = t ^ j;
      if (p > t){
        bool dir = ((t & ksz) == 0);
        float v1 = sv[t], v2 = sv[p];
        int   i1 = si[t], i2 = si[p];
        bool pFirst = (v2 > v1) || (v2 == v1 && i2 < i1);
        if (pFirst == dir){ sv[t]=v2; si[t]=i2; sv[p]=v1; si[p]=i1; }
      }
      __syncthreads();
    }
  }
  if (t < K){
    int g = b*NP + si[t];
    topv[b*K + t] = sv[t];
    perm[b*K + t] = g;
    newidx[g] = b*K + t;
  }
}

// ---------------- fused xnew = h[perm]*tanh(topv) + partial readout ----------------
template<int S>
__global__ void gather_scale_ro(const float* __restrict__ Hm, const int* __restrict__ perm,
                                const float* __restrict__ topv, float* __restrict__ xnew,
                                float* __restrict__ pmx, float* __restrict__ psm, int k){
  __shared__ float smx[128], ssm[128];
  int b = blockIdx.x / S, s = blockIdx.x % S;
  int t = threadIdx.x;        // 256
  int f = t & 127, h = t >> 7;
  int rows = k / S;
  int j0 = s * rows;
  float mx = -INFINITY, sm = 0.f;
  for (int j = j0 + h; j < j0 + rows; j += 2){
    int idx = b*k + j;
    float tm = tanhf(topv[idx]);
    float v = Hm[(size_t)perm[idx]*128 + f] * tm;
    xnew[(size_t)idx*128 + f] = v;
    mx = fmaxf(mx, v); sm += v;
  }
  if (h == 1){ smx[f] = mx; ssm[f] = sm; }
  __syncthreads();
  if (h == 0){
    mx = fmaxf(mx, smx[f]); sm += ssm[f];
    pmx[(size_t)(b*S+s)*128 + f] = mx;
    psm[(size_t)(b*S+s)*128 + f] = sm;
  }
}

template<int S>
__global__ void readout_fin(const float* __restrict__ pmx, const float* __restrict__ psm,
                            float* __restrict__ out, int k){
  int b = blockIdx.x, f = threadIdx.x;   // 128 threads
  float mx = -INFINITY, sm = 0.f;
  #pragma unroll
  for (int s = 0; s < S; ++s){
    mx = fmaxf(mx, pmx[(size_t)(b*S+s)*128 + f]);
    sm += psm[(size_t)(b*S+s)*128 + f];
  }
  out[b*256 + f]       += mx;
  out[b*256 + 128 + f] += sm / (float)k;
}

// ---------------- edge remap + next-level degree count ----------------
__global__ void remap_edges_cnt(const int* __restrict__ is, const int* __restrict__ id,
                                const int* __restrict__ newidx,
                                int* __restrict__ os, int* __restrict__ od,
                                int* __restrict__ cnt){
  int i = blockIdx.x*blockDim.x + threadIdx.x;
  int s = is[i], d = id[i];
  int ns = -1, nd = -1;
  if ((s | d) >= 0){ ns = newidx[s]; nd = newidx[d]; }
  bool v = (ns >= 0) & (nd >= 0);
  os[i] = v ? ns : -1;
  od[i] = v ? nd : -1;
  if (v) atomicAdd(&cnt[nd], 1);
}

// ---------------- host launcher ----------------
extern "C" void kernel_launch(void* const* d_in, const int* in_sizes, int n_in,
                              void* d_out, int out_size, void* d_ws, size_t ws_size,
                              hipStream_t stream){
  const float* x0 = (const float*)d_in[0];
  const int*   ei = (const int*)d_in[1];
  const float* Wl[3]  = {(const float*)d_in[3], (const float*)d_in[7],  (const float*)d_in[11]};
  const float* bl[3]  = {(const float*)d_in[4], (const float*)d_in[8],  (const float*)d_in[12]};
  const float* Wsl[3] = {(const float*)d_in[5], (const float*)d_in[9],  (const float*)d_in[13]};
  const float* bsl[3] = {(const float*)d_in[6], (const float*)d_in[10], (const float*)d_in[14]};

  // workspace layout (floats)
  float* A     = (float*)d_ws;                   // hx            65536*128
  float* C     = A + (size_t)65536*128;          // h (post agg)  65536*128
  float* D     = C + (size_t)65536*128;          // xnew / next x 32768*128
  float* dinv  = D + (size_t)32768*128;          // 65536
  float* hs    = dinv + 65536;                   // 65536
  float* score = hs + 65536;                     // 65536
  float* topv  = score + 65536;                  // 32768
  int* newidx  = (int*)(topv + 32768);           // 65536
  int* perm    = newidx + 65536;                 // 32768
  int* ea_s    = perm + 32768;                   // 524288
  int* ea_d    = ea_s + ETOT;
  int* eb_s    = ea_d + ETOT;
  int* eb_d    = eb_s + ETOT;
  int* cntA    = eb_d + ETOT;                    // 65536
  int* cntB    = cntA + 65536;                   // 32768
  int* cntC    = cntB + 32768;                   // 16384
  int* off     = cntC + 16384;                   // 65536
  int* cursor  = off + 65536;                    // 65536
  int* csr     = cursor + 65536;                 // 524288
  float* pmx   = (float*)(csr + 524288);         // 65536
  float* psm   = pmx + 65536;                    // 65536

  hipMemsetAsync(cntA, 0, (size_t)(65536+32768+16384)*sizeof(int), stream);
  hipMemsetAsync(d_out, 0, (size_t)out_size*sizeof(float), stream);

  float* out = (float*)d_out;

  auto level = [&](const float* xin, int n_tot, int np, int k,
                   const float* W, const float* b, const float* Ws, const float* bs,
                   const int* es, const int* ed, int* cnt,
                   int* oes, int* oed, int* ocnt){
    if (np == 512)      scan_graph<512><<<BGRAPH,512,0,stream>>>(cnt, off, cursor, dinv);
    else if (np == 256) scan_graph<256><<<BGRAPH,256,0,stream>>>(cnt, off, cursor, dinv);
    else                scan_graph<128><<<BGRAPH,128,0,stream>>>(cnt, off, cursor, dinv);
    fill_csr<<<ETOT/256, 256, 0, stream>>>(es, ed, off, cursor, csr);
    gemm_tile<<<n_tot/64, 256, 0, stream>>>(xin, W, A);
    gather_agg<<<n_tot/4, 256, 0, stream>>>(A, csr, off, cnt, dinv, b, Ws, C, hs, np, n_tot);
    score_gather<<<(n_tot+255)/256, 256, 0, stream>>>(hs, csr, off, cnt, dinv, bs, score, n_tot);
    if (np == 512)      topk_kernel<512,256><<<BGRAPH,512,0,stream>>>(score, topv, perm, newidx);
    else if (np == 256) topk_kernel<256,128><<<BGRAPH,256,0,stream>>>(score, topv, perm, newidx);
    else                topk_kernel<128, 64><<<BGRAPH,128,0,stream>>>(score, topv, perm, newidx);
    gather_scale_ro<4><<<BGRAPH*4, 256, 0, stream>>>(C, perm, topv, D, pmx, psm, k);
    if (oes) remap_edges_cnt<<<ETOT/256, 256, 0, stream>>>(es, ed, newidx, oes, oed, ocnt);
    readout_fin<4><<<BGRAPH, 128, 0, stream>>>(pmx, psm, out, k);
  };

  // level 1: degree of the initial (all-valid) edges
  deg_cnt<<<ETOT/256, 256, 0, stream>>>(ei + ETOT, cntA);
  level(x0, 65536, 512, K1, Wl[0], bl[0], Wsl[0], bsl[0],
        ei, ei + ETOT, cntA, ea_s, ea_d, cntB);
  // level 2
  level(D, 32768, 256, K2, Wl[1], bl[1], Wsl[1], bsl[1],
        ea_s, ea_d, cntB, eb_s, eb_d, cntC);
  // level 3
  level(D, 16384, 128, K3, Wl[2], bl[2], Wsl[2], bsl[2],
        eb_s, eb_d, cntC, nullptr, nullptr, nullptr);
}

// Round 6
// 260.397 us; speedup vs baseline: 6.7239x; 1.1416x over previous
//
#include <hip/hip_runtime.h>
#include <math.h>

#define BGRAPH 128
#define ETOT   (128*4096)   // 524288
#define EPG    4096
#define K1 256
#define K2 128
#define K3 64

// ---------------- tiled GEMM: Y[n][128] = X[n][128] @ W[128][128] ----------------
__global__ __launch_bounds__(256) void gemm_tile(const float* __restrict__ X,
                                                 const float* __restrict__ W,
                                                 float* __restrict__ Y){
  __shared__ float sA[32*64];
  __shared__ float sB[32*128];
  int tid = threadIdx.x;
  int row0 = blockIdx.x * 64;
  int tx = tid & 31;
  int ty = tid >> 5;
  int xm  = tid >> 2;
  int xf4 = tid & 3;
  float acc[8][4];
  #pragma unroll
  for (int i = 0; i < 8; ++i)
    #pragma unroll
    for (int j = 0; j < 4; ++j) acc[i][j] = 0.f;

  for (int k0 = 0; k0 < 128; k0 += 32){
    const float4* Wg = (const float4*)(W + k0*128);
    float4* sB4 = (float4*)sB;
    #pragma unroll
    for (int j = 0; j < 4; ++j) sB4[tid + j*256] = Wg[tid + j*256];
    const float4* Xg = (const float4*)(X + (size_t)(row0 + xm)*128 + k0);
    #pragma unroll
    for (int j = 0; j < 2; ++j){
      float4 v = Xg[xf4 + j*4];
      int kk = (xf4 + j*4) * 4;
      sA[(kk+0)*64 + xm] = v.x;
      sA[(kk+1)*64 + xm] = v.y;
      sA[(kk+2)*64 + xm] = v.z;
      sA[(kk+3)*64 + xm] = v.w;
    }
    __syncthreads();
    #pragma unroll
    for (int kk = 0; kk < 32; ++kk){
      float4 b  = *(const float4*)(sB + kk*128 + tx*4);
      float4 a0 = *(const float4*)(sA + kk*64 + ty*8);
      float4 a1 = *(const float4*)(sA + kk*64 + ty*8 + 4);
      float av[8] = {a0.x,a0.y,a0.z,a0.w,a1.x,a1.y,a1.z,a1.w};
      #pragma unroll
      for (int i = 0; i < 8; ++i){
        acc[i][0] = fmaf(av[i], b.x, acc[i][0]);
        acc[i][1] = fmaf(av[i], b.y, acc[i][1]);
        acc[i][2] = fmaf(av[i], b.z, acc[i][2]);
        acc[i][3] = fmaf(av[i], b.w, acc[i][3]);
      }
    }
    __syncthreads();
  }
  #pragma unroll
  for (int i = 0; i < 8; ++i)
    *(float4*)(Y + (size_t)(row0 + ty*8 + i)*128 + tx*4) = *(float4*)acc[i];
}

// ---------------- degree count (level 1 only) ----------------
__global__ void deg_cnt(const int* __restrict__ dst, int* __restrict__ cnt){
  int i = blockIdx.x*blockDim.x + threadIdx.x;
  int d = dst[i];
  if (d >= 0) atomicAdd(&cnt[d], 1);
}

// ---------------- per-graph exclusive scan -> CSR offsets + dinv ----------------
template<int NP>
__global__ void scan_graph(const int* __restrict__ cnt, int* __restrict__ off,
                           int* __restrict__ cursor, float* __restrict__ dinv){
  __shared__ int s[NP];
  int g = blockIdx.x, t = threadIdx.x;
  int v = cnt[g*NP + t];
  dinv[g*NP + t] = rsqrtf((float)v + 1.0f);
  s[t] = v;
  __syncthreads();
  for (int d = 1; d < NP; d <<= 1){
    int u = (t >= d) ? s[t-d] : 0;
    __syncthreads();
    s[t] += u;
    __syncthreads();
  }
  off[g*NP + t] = g*EPG + (s[t] - v);
  cursor[g*NP + t] = 0;
}

// ---------------- CSR fill (masked) ----------------
__global__ void fill_csr(const int* __restrict__ src, const int* __restrict__ dst,
                         const int* __restrict__ off, int* __restrict__ cursor,
                         int* __restrict__ csr){
  int i = blockIdx.x*blockDim.x + threadIdx.x;
  int d = dst[i];
  if (d < 0) return;
  int slot = off[d] + atomicAdd(&cursor[d], 1);
  csr[slot] = src[i];
}

// ---------------- fused aggregation + score GEMV, graph->XCD pinned ----------------
// half-wave (32 lanes, float4) per node; edge loop unrolled x2 (4 load chains/wave)
__global__ void gather_agg(const float* __restrict__ hx, const int* __restrict__ csr,
                           const int* __restrict__ off, const int* __restrict__ cnt,
                           const float* __restrict__ dinv, const float* __restrict__ bias,
                           const float* __restrict__ Ws, float* __restrict__ out,
                           float* __restrict__ hs, int npg, int n){
  int bpg = npg >> 3;                 // blocks per graph (8 nodes/block)
  int x = blockIdx.x >> 3, r = blockIdx.x & 7;
  int pos = x % bpg, grp = x / bpg;
  int g = grp*8 + r;
  int t = threadIdx.x;
  int node = g*npg + pos*8 + (t >> 5);  // 8 half-waves per block
  int fl = t & 31;                      // float4 slot within the row
  float dd = dinv[node];
  int o = off[node], deg = cnt[node];
  const float4* rows = (const float4*)hx;
  float4 acc0 = {0.f,0.f,0.f,0.f}, acc1 = {0.f,0.f,0.f,0.f};
  int e = o, end = o + deg;
  for (; e + 1 < end; e += 2){
    int s0 = csr[e], s1 = csr[e+1];
    float c0 = dinv[s0]*dd, c1 = dinv[s1]*dd;
    float4 v0 = rows[(size_t)s0*32 + fl];
    float4 v1 = rows[(size_t)s1*32 + fl];
    acc0.x = fmaf(c0, v0.x, acc0.x); acc0.y = fmaf(c0, v0.y, acc0.y);
    acc0.z = fmaf(c0, v0.z, acc0.z); acc0.w = fmaf(c0, v0.w, acc0.w);
    acc1.x = fmaf(c1, v1.x, acc1.x); acc1.y = fmaf(c1, v1.y, acc1.y);
    acc1.z = fmaf(c1, v1.z, acc1.z); acc1.w = fmaf(c1, v1.w, acc1.w);
  }
  if (e < end){
    int s0 = csr[e];
    float c0 = dinv[s0]*dd;
    float4 v0 = rows[(size_t)s0*32 + fl];
    acc0.x = fmaf(c0, v0.x, acc0.x); acc0.y = fmaf(c0, v0.y, acc0.y);
    acc0.z = fmaf(c0, v0.z, acc0.z); acc0.w = fmaf(c0, v0.w, acc0.w);
  }
  float4 own = rows[(size_t)node*32 + fl];
  float4 bv  = ((const float4*)bias)[fl];
  float d2 = dd*dd;
  float4 rr;
  rr.x = fmaxf(fmaf(d2, own.x, acc0.x + acc1.x + bv.x), 0.f);
  rr.y = fmaxf(fmaf(d2, own.y, acc0.y + acc1.y + bv.y), 0.f);
  rr.z = fmaxf(fmaf(d2, own.z, acc0.z + acc1.z + bv.z), 0.f);
  rr.w = fmaxf(fmaf(d2, own.w, acc0.w + acc1.w + bv.w), 0.f);
  ((float4*)(out + (size_t)node*128))[fl] = rr;
  float4 w = ((const float4*)Ws)[fl];
  float p = rr.x*w.x + rr.y*w.y + rr.z*w.z + rr.w*w.w;
  p += __shfl_xor(p, 16);
  p += __shfl_xor(p, 8);
  p += __shfl_xor(p, 4);
  p += __shfl_xor(p, 2);
  p += __shfl_xor(p, 1);
  if (fl == 0) hs[node] = p;
}

// ---------------- score aggregation (per-node gather) ----------------
__global__ void score_gather(const float* __restrict__ hs, const int* __restrict__ csr,
                             const int* __restrict__ off, const int* __restrict__ cnt,
                             const float* __restrict__ dinv, const float* __restrict__ bs,
                             float* __restrict__ score, int n){
  int i = blockIdx.x*blockDim.x + threadIdx.x;
  if (i >= n) return;
  float dd = dinv[i];
  int o = off[i], deg = cnt[i];
  float a0 = 0.f, a1 = 0.f;
  int e = o, end = o + deg;
  for (; e + 1 < end; e += 2){
    int s0 = csr[e], s1 = csr[e+1];
    a0 = fmaf(dinv[s0]*dd, hs[s0], a0);
    a1 = fmaf(dinv[s1]*dd, hs[s1], a1);
  }
  if (e < end){
    int s0 = csr[e];
    a0 = fmaf(dinv[s0]*dd, hs[s0], a0);
  }
  score[i] = a0 + a1 + fmaf(dd*dd, hs[i], bs[0]);
}

// ---------------- per-graph top-k via bitonic sort (value desc, index asc) ----------------
template<int NP, int K>
__global__ void topk_kernel(const float* __restrict__ score, float* __restrict__ topv,
                            int* __restrict__ perm, int* __restrict__ newidx){
  __shared__ float sv[NP];
  __shared__ int   si[NP];
  int b = blockIdx.x, t = threadIdx.x;
  sv[t] = score[b*NP + t];
  si[t] = t;
  newidx[b*NP + t] = -1;
  __syncthreads();
  for (int ksz = 2; ksz <= NP; ksz <<= 1){
    for (int j = ksz >> 1; j > 0; j >>= 1){
      int p = t ^ j;
      if (p > t){
        bool dir = ((t & ksz) == 0);
        float v1 = sv[t], v2 = sv[p];
        int   i1 = si[t], i2 = si[p];
        bool pFirst = (v2 > v1) || (v2 == v1 && i2 < i1);
        if (pFirst == dir){ sv[t]=v2; si[t]=i2; sv[p]=v1; si[p]=i1; }
      }
      __syncthreads();
    }
  }
  if (t < K){
    int g = b*NP + si[t];
    topv[b*K + t] = sv[t];
    perm[b*K + t] = g;
    newidx[g] = b*K + t;
  }
}

// ---------------- fused xnew = h[perm]*tanh(topv) + partial readout ----------------
template<int S>
__global__ void gather_scale_ro(const float* __restrict__ Hm, const int* __restrict__ perm,
                                const float* __restrict__ topv, float* __restrict__ xnew,
                                float* __restrict__ pmx, float* __restrict__ psm, int k){
  __shared__ float smx[128], ssm[128];
  int b = blockIdx.x / S, s = blockIdx.x % S;
  int t = threadIdx.x;        // 256
  int f = t & 127, h = t >> 7;
  int rows = k / S;
  int j0 = s * rows;
  float mx = -INFINITY, sm = 0.f;
  for (int j = j0 + h; j < j0 + rows; j += 2){
    int idx = b*k + j;
    float tm = tanhf(topv[idx]);
    float v = Hm[(size_t)perm[idx]*128 + f] * tm;
    xnew[(size_t)idx*128 + f] = v;
    mx = fmaxf(mx, v); sm += v;
  }
  if (h == 1){ smx[f] = mx; ssm[f] = sm; }
  __syncthreads();
  if (h == 0){
    mx = fmaxf(mx, smx[f]); sm += ssm[f];
    pmx[(size_t)(b*S+s)*128 + f] = mx;
    psm[(size_t)(b*S+s)*128 + f] = sm;
  }
}

template<int S>
__global__ void readout_fin(const float* __restrict__ pmx, const float* __restrict__ psm,
                            float* __restrict__ out, int k){
  int b = blockIdx.x, f = threadIdx.x;   // 128 threads
  float mx = -INFINITY, sm = 0.f;
  #pragma unroll
  for (int s = 0; s < S; ++s){
    mx = fmaxf(mx, pmx[(size_t)(b*S+s)*128 + f]);
    sm += psm[(size_t)(b*S+s)*128 + f];
  }
  out[b*256 + f]       += mx;
  out[b*256 + 128 + f] += sm / (float)k;
}

// ---------------- edge remap + next-level degree count ----------------
__global__ void remap_edges_cnt(const int* __restrict__ is, const int* __restrict__ id,
                                const int* __restrict__ newidx,
                                int* __restrict__ os, int* __restrict__ od,
                                int* __restrict__ cnt){
  int i = blockIdx.x*blockDim.x + threadIdx.x;
  int s = is[i], d = id[i];
  int ns = -1, nd = -1;
  if ((s | d) >= 0){ ns = newidx[s]; nd = newidx[d]; }
  bool v = (ns >= 0) & (nd >= 0);
  os[i] = v ? ns : -1;
  od[i] = v ? nd : -1;
  if (v) atomicAdd(&cnt[nd], 1);
}

// ---------------- host launcher ----------------
extern "C" void kernel_launch(void* const* d_in, const int* in_sizes, int n_in,
                              void* d_out, int out_size, void* d_ws, size_t ws_size,
                              hipStream_t stream){
  const float* x0 = (const float*)d_in[0];
  const int*   ei = (const int*)d_in[1];
  const float* Wl[3]  = {(const float*)d_in[3], (const float*)d_in[7],  (const float*)d_in[11]};
  const float* bl[3]  = {(const float*)d_in[4], (const float*)d_in[8],  (const float*)d_in[12]};
  const float* Wsl[3] = {(const float*)d_in[5], (const float*)d_in[9],  (const float*)d_in[13]};
  const float* bsl[3] = {(const float*)d_in[6], (const float*)d_in[10], (const float*)d_in[14]};

  // workspace layout (floats)
  float* A     = (float*)d_ws;                   // hx            65536*128
  float* C     = A + (size_t)65536*128;          // h (post agg)  65536*128
  float* D     = C + (size_t)65536*128;          // xnew / next x 32768*128
  float* dinv  = D + (size_t)32768*128;          // 65536
  float* hs    = dinv + 65536;                   // 65536
  float* score = hs + 65536;                     // 65536
  float* topv  = score + 65536;                  // 32768
  int* newidx  = (int*)(topv + 32768);           // 65536
  int* perm    = newidx + 65536;                 // 32768
  int* ea_s    = perm + 32768;                   // 524288
  int* ea_d    = ea_s + ETOT;
  int* eb_s    = ea_d + ETOT;
  int* eb_d    = eb_s + ETOT;
  int* cntA    = eb_d + ETOT;                    // 65536
  int* cntB    = cntA + 65536;                   // 32768
  int* cntC    = cntB + 32768;                   // 16384
  int* off     = cntC + 16384;                   // 65536
  int* cursor  = off + 65536;                    // 65536
  int* csr     = cursor + 65536;                 // 524288
  float* pmx   = (float*)(csr + 524288);         // 65536
  float* psm   = pmx + 65536;                    // 65536

  hipMemsetAsync(cntA, 0, (size_t)(65536+32768+16384)*sizeof(int), stream);
  hipMemsetAsync(d_out, 0, (size_t)out_size*sizeof(float), stream);

  float* out = (float*)d_out;

  auto level = [&](const float* xin, int n_tot, int np, int k,
                   const float* W, const float* b, const float* Ws, const float* bs,
                   const int* es, const int* ed, int* cnt,
                   int* oes, int* oed, int* ocnt){
    if (np == 512)      scan_graph<512><<<BGRAPH,512,0,stream>>>(cnt, off, cursor, dinv);
    else if (np == 256) scan_graph<256><<<BGRAPH,256,0,stream>>>(cnt, off, cursor, dinv);
    else                scan_graph<128><<<BGRAPH,128,0,stream>>>(cnt, off, cursor, dinv);
    fill_csr<<<ETOT/256, 256, 0, stream>>>(es, ed, off, cursor, csr);
    gemm_tile<<<n_tot/64, 256, 0, stream>>>(xin, W, A);
    gather_agg<<<n_tot/8, 256, 0, stream>>>(A, csr, off, cnt, dinv, b, Ws, C, hs, np, n_tot);
    score_gather<<<(n_tot+255)/256, 256, 0, stream>>>(hs, csr, off, cnt, dinv, bs, score, n_tot);
    if (np == 512)      topk_kernel<512,256><<<BGRAPH,512,0,stream>>>(score, topv, perm, newidx);
    else if (np == 256) topk_kernel<256,128><<<BGRAPH,256,0,stream>>>(score, topv, perm, newidx);
    else                topk_kernel<128, 64><<<BGRAPH,128,0,stream>>>(score, topv, perm, newidx);
    gather_scale_ro<4><<<BGRAPH*4, 256, 0, stream>>>(C, perm, topv, D, pmx, psm, k);
    if (oes) remap_edges_cnt<<<ETOT/256, 256, 0, stream>>>(es, ed, newidx, oes, oed, ocnt);
    readout_fin<4><<<BGRAPH, 128, 0, stream>>>(pmx, psm, out, k);
  };

  // level 1: degree of the initial (all-valid) edges
  deg_cnt<<<ETOT/256, 256, 0, stream>>>(ei + ETOT, cntA);
  level(x0, 65536, 512, K1, Wl[0], bl[0], Wsl[0], bsl[0],
        ei, ei + ETOT, cntA, ea_s, ea_d, cntB);
  // level 2
  level(D, 32768, 256, K2, Wl[1], bl[1], Wsl[1], bsl[1],
        ea_s, ea_d, cntB, eb_s, eb_d, cntC);
  // level 3
  level(D, 16384, 128, K3, Wl[2], bl[2], Wsl[2], bsl[2],
        eb_s, eb_d, cntC, nullptr, nullptr, nullptr);
}

// Round 7
// 258.241 us; speedup vs baseline: 6.7801x; 1.0083x over previous
//
#include <hip/hip_runtime.h>
#include <math.h>

#define BGRAPH 128
#define ETOT   (128*4096)   // 524288
#define EPG    4096
#define K1 256
#define K2 128
#define K3 64

// ---------------- tiled GEMM: Y[n][128] = X[n][128] @ W[128][128] ----------------
__global__ __launch_bounds__(256) void gemm_tile(const float* __restrict__ X,
                                                 const float* __restrict__ W,
                                                 float* __restrict__ Y){
  __shared__ float sA[32*64];
  __shared__ float sB[32*128];
  int tid = threadIdx.x;
  int row0 = blockIdx.x * 64;
  int tx = tid & 31;
  int ty = tid >> 5;
  int xm  = tid >> 2;
  int xf4 = tid & 3;
  float acc[8][4];
  #pragma unroll
  for (int i = 0; i < 8; ++i)
    #pragma unroll
    for (int j = 0; j < 4; ++j) acc[i][j] = 0.f;

  for (int k0 = 0; k0 < 128; k0 += 32){
    const float4* Wg = (const float4*)(W + k0*128);
    float4* sB4 = (float4*)sB;
    #pragma unroll
    for (int j = 0; j < 4; ++j) sB4[tid + j*256] = Wg[tid + j*256];
    const float4* Xg = (const float4*)(X + (size_t)(row0 + xm)*128 + k0);
    #pragma unroll
    for (int j = 0; j < 2; ++j){
      float4 v = Xg[xf4 + j*4];
      int kk = (xf4 + j*4) * 4;
      sA[(kk+0)*64 + xm] = v.x;
      sA[(kk+1)*64 + xm] = v.y;
      sA[(kk+2)*64 + xm] = v.z;
      sA[(kk+3)*64 + xm] = v.w;
    }
    __syncthreads();
    #pragma unroll
    for (int kk = 0; kk < 32; ++kk){
      float4 b  = *(const float4*)(sB + kk*128 + tx*4);
      float4 a0 = *(const float4*)(sA + kk*64 + ty*8);
      float4 a1 = *(const float4*)(sA + kk*64 + ty*8 + 4);
      float av[8] = {a0.x,a0.y,a0.z,a0.w,a1.x,a1.y,a1.z,a1.w};
      #pragma unroll
      for (int i = 0; i < 8; ++i){
        acc[i][0] = fmaf(av[i], b.x, acc[i][0]);
        acc[i][1] = fmaf(av[i], b.y, acc[i][1]);
        acc[i][2] = fmaf(av[i], b.z, acc[i][2]);
        acc[i][3] = fmaf(av[i], b.w, acc[i][3]);
      }
    }
    __syncthreads();
  }
  #pragma unroll
  for (int i = 0; i < 8; ++i)
    *(float4*)(Y + (size_t)(row0 + ty*8 + i)*128 + tx*4) = *(float4*)acc[i];
}

// ---------------- degree count (level 1 only) ----------------
__global__ void deg_cnt(const int* __restrict__ dst, int* __restrict__ cnt){
  int i = blockIdx.x*blockDim.x + threadIdx.x;
  int d = dst[i];
  if (d >= 0) atomicAdd(&cnt[d], 1);
}

// ---------------- fused: per-graph scan -> off/dinv, then CSR fill w/ LDS cursors ----------------
// Relies on edges of graph g living in slice [g*EPG, (g+1)*EPG) (position-preserving remap).
template<int NP>
__global__ void scanfill(const int* __restrict__ cnt, const int* __restrict__ src,
                         const int* __restrict__ dst, int* __restrict__ off,
                         float* __restrict__ dinv, int* __restrict__ csr){
  __shared__ int s[NP];
  __shared__ int loc[NP];    // local exclusive prefix
  __shared__ int cur[NP];    // LDS cursors
  int g = blockIdx.x, t = threadIdx.x;
  int v = cnt[g*NP + t];
  dinv[g*NP + t] = rsqrtf((float)v + 1.0f);
  s[t] = v;
  __syncthreads();
  for (int d = 1; d < NP; d <<= 1){
    int u = (t >= d) ? s[t-d] : 0;
    __syncthreads();
    s[t] += u;
    __syncthreads();
  }
  int pre = s[t] - v;
  loc[t] = pre;
  cur[t] = 0;
  off[g*NP + t] = g*EPG + pre;
  __syncthreads();
  const int* sg = src + g*EPG;
  const int* dg = dst + g*EPG;
  int* cg = csr + g*EPG;
  #pragma unroll
  for (int e = t; e < EPG; e += NP){
    int d = dg[e];
    if (d < 0) continue;
    int dl = d - g*NP;
    int slot = loc[dl] + atomicAdd(&cur[dl], 1);
    cg[slot] = sg[e];
  }
}

// ---------------- fused aggregation + score GEMV, graph->XCD pinned ----------------
// half-wave (32 lanes, float4) per node; edge loop unrolled x4 (8 load chains/wave)
__global__ void gather_agg(const float* __restrict__ hx, const int* __restrict__ csr,
                           const int* __restrict__ off, const int* __restrict__ cnt,
                           const float* __restrict__ dinv, const float* __restrict__ bias,
                           const float* __restrict__ Ws, float* __restrict__ out,
                           float* __restrict__ hs, int npg, int n){
  int bpg = npg >> 3;                 // blocks per graph (8 nodes/block)
  int x = blockIdx.x >> 3, r = blockIdx.x & 7;
  int pos = x % bpg, grp = x / bpg;
  int g = grp*8 + r;
  int t = threadIdx.x;
  int node = g*npg + pos*8 + (t >> 5);
  int fl = t & 31;
  float dd = dinv[node];
  int o = off[node], deg = cnt[node];
  const float4* rows = (const float4*)hx;
  float4 a0 = {0,0,0,0}, a1 = {0,0,0,0}, a2 = {0,0,0,0}, a3 = {0,0,0,0};
  int e = o, end = o + deg;
  for (; e + 3 < end; e += 4){
    int s0 = csr[e], s1 = csr[e+1], s2 = csr[e+2], s3 = csr[e+3];
    float c0 = dinv[s0]*dd, c1 = dinv[s1]*dd, c2 = dinv[s2]*dd, c3 = dinv[s3]*dd;
    float4 v0 = rows[(size_t)s0*32 + fl];
    float4 v1 = rows[(size_t)s1*32 + fl];
    float4 v2 = rows[(size_t)s2*32 + fl];
    float4 v3 = rows[(size_t)s3*32 + fl];
    a0.x=fmaf(c0,v0.x,a0.x); a0.y=fmaf(c0,v0.y,a0.y); a0.z=fmaf(c0,v0.z,a0.z); a0.w=fmaf(c0,v0.w,a0.w);
    a1.x=fmaf(c1,v1.x,a1.x); a1.y=fmaf(c1,v1.y,a1.y); a1.z=fmaf(c1,v1.z,a1.z); a1.w=fmaf(c1,v1.w,a1.w);
    a2.x=fmaf(c2,v2.x,a2.x); a2.y=fmaf(c2,v2.y,a2.y); a2.z=fmaf(c2,v2.z,a2.z); a2.w=fmaf(c2,v2.w,a2.w);
    a3.x=fmaf(c3,v3.x,a3.x); a3.y=fmaf(c3,v3.y,a3.y); a3.z=fmaf(c3,v3.z,a3.z); a3.w=fmaf(c3,v3.w,a3.w);
  }
  for (; e < end; ++e){
    int s0 = csr[e];
    float c0 = dinv[s0]*dd;
    float4 v0 = rows[(size_t)s0*32 + fl];
    a0.x=fmaf(c0,v0.x,a0.x); a0.y=fmaf(c0,v0.y,a0.y); a0.z=fmaf(c0,v0.z,a0.z); a0.w=fmaf(c0,v0.w,a0.w);
  }
  float4 own = rows[(size_t)node*32 + fl];
  float4 bv  = ((const float4*)bias)[fl];
  float d2 = dd*dd;
  float4 rr;
  rr.x = fmaxf(fmaf(d2, own.x, (a0.x+a1.x)+(a2.x+a3.x) + bv.x), 0.f);
  rr.y = fmaxf(fmaf(d2, own.y, (a0.y+a1.y)+(a2.y+a3.y) + bv.y), 0.f);
  rr.z = fmaxf(fmaf(d2, own.z, (a0.z+a1.z)+(a2.z+a3.z) + bv.z), 0.f);
  rr.w = fmaxf(fmaf(d2, own.w, (a0.w+a1.w)+(a2.w+a3.w) + bv.w), 0.f);
  ((float4*)(out + (size_t)node*128))[fl] = rr;
  float4 w = ((const float4*)Ws)[fl];
  float p = rr.x*w.x + rr.y*w.y + rr.z*w.z + rr.w*w.w;
  p += __shfl_xor(p, 16);
  p += __shfl_xor(p, 8);
  p += __shfl_xor(p, 4);
  p += __shfl_xor(p, 2);
  p += __shfl_xor(p, 1);
  if (fl == 0) hs[node] = p;
}

// ---------------- fused score + per-graph top-k bitonic (value desc, index asc) ----------------
template<int NP, int K>
__global__ void topk_score(const float* __restrict__ hs, const int* __restrict__ csr,
                           const int* __restrict__ off, const int* __restrict__ cnt,
                           const float* __restrict__ dinv, const float* __restrict__ bs,
                           float* __restrict__ topv, int* __restrict__ perm,
                           int* __restrict__ newidx){
  __shared__ float sv[NP];
  __shared__ int   si[NP];
  int b = blockIdx.x, t = threadIdx.x;
  int i = b*NP + t;
  // score for node i
  {
    float dd = dinv[i];
    int o = off[i], deg = cnt[i];
    float a0 = 0.f, a1 = 0.f;
    int e = o, end = o + deg;
    for (; e + 1 < end; e += 2){
      int s0 = csr[e], s1 = csr[e+1];
      a0 = fmaf(dinv[s0]*dd, hs[s0], a0);
      a1 = fmaf(dinv[s1]*dd, hs[s1], a1);
    }
    if (e < end){ int s0 = csr[e]; a0 = fmaf(dinv[s0]*dd, hs[s0], a0); }
    sv[t] = a0 + a1 + fmaf(dd*dd, hs[i], bs[0]);
  }
  si[t] = t;
  newidx[i] = -1;
  __syncthreads();
  for (int ksz = 2; ksz <= NP; ksz <<= 1){
    for (int j = ksz >> 1; j > 0; j >>= 1){
      int p = t ^ j;
      if (p > t){
        bool dir = ((t & ksz) == 0);
        float v1 = sv[t], v2 = sv[p];
        int   i1 = si[t], i2 = si[p];
        bool pFirst = (v2 > v1) || (v2 == v1 && i2 < i1);
        if (pFirst == dir){ sv[t]=v2; si[t]=i2; sv[p]=v1; si[p]=i1; }
      }
      __syncthreads();
    }
  }
  if (t < K){
    int g = b*NP + si[t];
    topv[b*K + t] = sv[t];
    perm[b*K + t] = g;
    newidx[g] = b*K + t;
  }
}

// ---------------- fused xnew = h[perm]*tanh(topv) + partial readout ----------------
template<int S>
__global__ void gather_scale_ro(const float* __restrict__ Hm, const int* __restrict__ perm,
                                const float* __restrict__ topv, float* __restrict__ xnew,
                                float* __restrict__ pmx, float* __restrict__ psm, int k){
  __shared__ float smx[128], ssm[128];
  int b = blockIdx.x / S, s = blockIdx.x % S;
  int t = threadIdx.x;        // 256
  int f = t & 127, h = t >> 7;
  int rows = k / S;
  int j0 = s * rows;
  float mx = -INFINITY, sm = 0.f;
  for (int j = j0 + h; j < j0 + rows; j += 2){
    int idx = b*k + j;
    float tm = tanhf(topv[idx]);
    float v = Hm[(size_t)perm[idx]*128 + f] * tm;
    xnew[(size_t)idx*128 + f] = v;
    mx = fmaxf(mx, v); sm += v;
  }
  if (h == 1){ smx[f] = mx; ssm[f] = sm; }
  __syncthreads();
  if (h == 0){
    mx = fmaxf(mx, smx[f]); sm += ssm[f];
    pmx[(size_t)(b*S+s)*128 + f] = mx;
    psm[(size_t)(b*S+s)*128 + f] = sm;
  }
}

template<int S>
__global__ void readout_fin(const float* __restrict__ pmx, const float* __restrict__ psm,
                            float* __restrict__ out, int k){
  int b = blockIdx.x, f = threadIdx.x;   // 128 threads
  float mx = -INFINITY, sm = 0.f;
  #pragma unroll
  for (int s = 0; s < S; ++s){
    mx = fmaxf(mx, pmx[(size_t)(b*S+s)*128 + f]);
    sm += psm[(size_t)(b*S+s)*128 + f];
  }
  out[b*256 + f]       += mx;
  out[b*256 + 128 + f] += sm / (float)k;
}

// ---------------- edge remap + next-level degree count ----------------
__global__ void remap_edges_cnt(const int* __restrict__ is, const int* __restrict__ id,
                                const int* __restrict__ newidx,
                                int* __restrict__ os, int* __restrict__ od,
                                int* __restrict__ cnt){
  int i = blockIdx.x*blockDim.x + threadIdx.x;
  int s = is[i], d = id[i];
  int ns = -1, nd = -1;
  if ((s | d) >= 0){ ns = newidx[s]; nd = newidx[d]; }
  bool v = (ns >= 0) & (nd >= 0);
  os[i] = v ? ns : -1;
  od[i] = v ? nd : -1;
  if (v) atomicAdd(&cnt[nd], 1);
}

// ---------------- host launcher ----------------
extern "C" void kernel_launch(void* const* d_in, const int* in_sizes, int n_in,
                              void* d_out, int out_size, void* d_ws, size_t ws_size,
                              hipStream_t stream){
  const float* x0 = (const float*)d_in[0];
  const int*   ei = (const int*)d_in[1];
  const float* Wl[3]  = {(const float*)d_in[3], (const float*)d_in[7],  (const float*)d_in[11]};
  const float* bl[3]  = {(const float*)d_in[4], (const float*)d_in[8],  (const float*)d_in[12]};
  const float* Wsl[3] = {(const float*)d_in[5], (const float*)d_in[9],  (const float*)d_in[13]};
  const float* bsl[3] = {(const float*)d_in[6], (const float*)d_in[10], (const float*)d_in[14]};

  // workspace layout (floats)
  float* A     = (float*)d_ws;                   // hx            65536*128
  float* C     = A + (size_t)65536*128;          // h (post agg)  65536*128
  float* D     = C + (size_t)65536*128;          // xnew / next x 32768*128
  float* dinv  = D + (size_t)32768*128;          // 65536
  float* hs    = dinv + 65536;                   // 65536
  float* topv  = hs + 65536;                     // 32768
  int* newidx  = (int*)(topv + 32768);           // 65536
  int* perm    = newidx + 65536;                 // 32768
  int* ea_s    = perm + 32768;                   // 524288
  int* ea_d    = ea_s + ETOT;
  int* eb_s    = ea_d + ETOT;
  int* eb_d    = eb_s + ETOT;
  int* cntA    = eb_d + ETOT;                    // 65536
  int* cntB    = cntA + 65536;                   // 32768
  int* cntC    = cntB + 32768;                   // 16384
  int* off     = cntC + 16384;                   // 65536
  int* csr     = off + 65536;                    // 524288
  float* pmx   = (float*)(csr + 524288);         // 65536
  float* psm   = pmx + 65536;                    // 65536

  hipMemsetAsync(cntA, 0, (size_t)(65536+32768+16384)*sizeof(int), stream);
  hipMemsetAsync(d_out, 0, (size_t)out_size*sizeof(float), stream);

  float* out = (float*)d_out;

  auto level = [&](const float* xin, int n_tot, int np, int k,
                   const float* W, const float* b, const float* Ws, const float* bs,
                   const int* es, const int* ed, int* cnt,
                   int* oes, int* oed, int* ocnt){
    if (np == 512)      scanfill<512><<<BGRAPH,512,0,stream>>>(cnt, es, ed, off, dinv, csr);
    else if (np == 256) scanfill<256><<<BGRAPH,256,0,stream>>>(cnt, es, ed, off, dinv, csr);
    else                scanfill<128><<<BGRAPH,128,0,stream>>>(cnt, es, ed, off, dinv, csr);
    gemm_tile<<<n_tot/64, 256, 0, stream>>>(xin, W, A);
    gather_agg<<<n_tot/8, 256, 0, stream>>>(A, csr, off, cnt, dinv, b, Ws, C, hs, np, n_tot);
    if (np == 512)      topk_score<512,256><<<BGRAPH,512,0,stream>>>(hs, csr, off, cnt, dinv, bs, topv, perm, newidx);
    else if (np == 256) topk_score<256,128><<<BGRAPH,256,0,stream>>>(hs, csr, off, cnt, dinv, bs, topv, perm, newidx);
    else                topk_score<128, 64><<<BGRAPH,128,0,stream>>>(hs, csr, off, cnt, dinv, bs, topv, perm, newidx);
    gather_scale_ro<4><<<BGRAPH*4, 256, 0, stream>>>(C, perm, topv, D, pmx, psm, k);
    if (oes) remap_edges_cnt<<<ETOT/256, 256, 0, stream>>>(es, ed, newidx, oes, oed, ocnt);
    readout_fin<4><<<BGRAPH, 128, 0, stream>>>(pmx, psm, out, k);
  };

  // level 1: degree of the initial (all-valid) edges
  deg_cnt<<<ETOT/256, 256, 0, stream>>>(ei + ETOT, cntA);
  level(x0, 65536, 512, K1, Wl[0], bl[0], Wsl[0], bsl[0],
        ei, ei + ETOT, cntA, ea_s, ea_d, cntB);
  // level 2
  level(D, 32768, 256, K2, Wl[1], bl[1], Wsl[1], bsl[1],
        ea_s, ea_d, cntB, eb_s, eb_d, cntC);
  // level 3
  level(D, 16384, 128, K3, Wl[2], bl[2], Wsl[2], bsl[2],
        eb_s, eb_d, cntC, nullptr, nullptr, nullptr);
}

// Round 8
// 252.356 us; speedup vs baseline: 6.9382x; 1.0233x over previous
//
#include <hip/hip_runtime.h>
#include <math.h>

#define BGRAPH 128
#define ETOT   (128*4096)   // 524288
#define EPG    4096
#define K1 256
#define K2 128
#define K3 64

// ---------------- tiled GEMM: Y[n][128] = X[n][128] @ W[128][128] ----------------
__global__ __launch_bounds__(256) void gemm_tile(const float* __restrict__ X,
                                                 const float* __restrict__ W,
                                                 float* __restrict__ Y){
  __shared__ float sA[32*64];
  __shared__ float sB[32*128];
  int tid = threadIdx.x;
  int row0 = blockIdx.x * 64;
  int tx = tid & 31;
  int ty = tid >> 5;
  int xm  = tid >> 2;
  int xf4 = tid & 3;
  float acc[8][4];
  #pragma unroll
  for (int i = 0; i < 8; ++i)
    #pragma unroll
    for (int j = 0; j < 4; ++j) acc[i][j] = 0.f;

  for (int k0 = 0; k0 < 128; k0 += 32){
    const float4* Wg = (const float4*)(W + k0*128);
    float4* sB4 = (float4*)sB;
    #pragma unroll
    for (int j = 0; j < 4; ++j) sB4[tid + j*256] = Wg[tid + j*256];
    const float4* Xg = (const float4*)(X + (size_t)(row0 + xm)*128 + k0);
    #pragma unroll
    for (int j = 0; j < 2; ++j){
      float4 v = Xg[xf4 + j*4];
      int kk = (xf4 + j*4) * 4;
      sA[(kk+0)*64 + xm] = v.x;
      sA[(kk+1)*64 + xm] = v.y;
      sA[(kk+2)*64 + xm] = v.z;
      sA[(kk+3)*64 + xm] = v.w;
    }
    __syncthreads();
    #pragma unroll
    for (int kk = 0; kk < 32; ++kk){
      float4 b  = *(const float4*)(sB + kk*128 + tx*4);
      float4 a0 = *(const float4*)(sA + kk*64 + ty*8);
      float4 a1 = *(const float4*)(sA + kk*64 + ty*8 + 4);
      float av[8] = {a0.x,a0.y,a0.z,a0.w,a1.x,a1.y,a1.z,a1.w};
      #pragma unroll
      for (int i = 0; i < 8; ++i){
        acc[i][0] = fmaf(av[i], b.x, acc[i][0]);
        acc[i][1] = fmaf(av[i], b.y, acc[i][1]);
        acc[i][2] = fmaf(av[i], b.z, acc[i][2]);
        acc[i][3] = fmaf(av[i], b.w, acc[i][3]);
      }
    }
    __syncthreads();
  }
  #pragma unroll
  for (int i = 0; i < 8; ++i)
    *(float4*)(Y + (size_t)(row0 + ty*8 + i)*128 + tx*4) = *(float4*)acc[i];
}

// ---------------- degree count (level 1 only) ----------------
__global__ void deg_cnt(const int* __restrict__ dst, int* __restrict__ cnt){
  int i = blockIdx.x*blockDim.x + threadIdx.x;
  int d = dst[i];
  if (d >= 0) atomicAdd(&cnt[d], 1);
}

// ---------------- fused: per-graph scan -> off/dinv, CSR fill + edge coef ----------------
// Edges of graph g live in slice [g*EPG, (g+1)*EPG) (position-preserving remap).
template<int NP>
__global__ void scanfill(const int* __restrict__ cnt, const int* __restrict__ src,
                         const int* __restrict__ dst, int* __restrict__ off,
                         float* __restrict__ dinv, int* __restrict__ csr,
                         float* __restrict__ coef){
  __shared__ int s[NP];
  __shared__ int loc[NP];
  __shared__ int cur[NP];
  __shared__ float sdv[NP];
  int g = blockIdx.x, t = threadIdx.x;
  int v = cnt[g*NP + t];
  float dv = rsqrtf((float)v + 1.0f);
  dinv[g*NP + t] = dv;
  sdv[t] = dv;
  s[t] = v;
  __syncthreads();
  for (int d = 1; d < NP; d <<= 1){
    int u = (t >= d) ? s[t-d] : 0;
    __syncthreads();
    s[t] += u;
    __syncthreads();
  }
  int pre = s[t] - v;
  loc[t] = pre;
  cur[t] = 0;
  off[g*NP + t] = g*EPG + pre;
  __syncthreads();
  const int* sg = src + g*EPG;
  const int* dg = dst + g*EPG;
  int* cg = csr + g*EPG;
  float* cf = coef + g*EPG;
  for (int e = t; e < EPG; e += NP){
    int d = dg[e];
    if (d < 0) continue;
    int srcv = sg[e];
    int sl = srcv - g*NP;
    int dl = d - g*NP;
    int slot = loc[dl] + atomicAdd(&cur[dl], 1);
    cg[slot] = srcv;
    cf[slot] = sdv[sl]*sdv[dl];
  }
}

// ---------------- fused aggregation + score GEMV, graph->XCD pinned ----------------
// half-wave (32 lanes, float4) per node; edge loop unrolled x4; coef precomputed
__global__ void gather_agg(const float* __restrict__ hx, const int* __restrict__ csr,
                           const float* __restrict__ coef,
                           const int* __restrict__ off, const int* __restrict__ cnt,
                           const float* __restrict__ dinv, const float* __restrict__ bias,
                           const float* __restrict__ Ws, float* __restrict__ out,
                           float* __restrict__ hs, int npg, int n){
  int bpg = npg >> 3;
  int x = blockIdx.x >> 3, r = blockIdx.x & 7;
  int pos = x % bpg, grp = x / bpg;
  int g = grp*8 + r;
  int t = threadIdx.x;
  int node = g*npg + pos*8 + (t >> 5);
  int fl = t & 31;
  float dd = dinv[node];
  int o = off[node], deg = cnt[node];
  const float4* rows = (const float4*)hx;
  float4 a0 = {0,0,0,0}, a1 = {0,0,0,0}, a2 = {0,0,0,0}, a3 = {0,0,0,0};
  int e = o, end = o + deg;
  for (; e + 3 < end; e += 4){
    int s0 = csr[e], s1 = csr[e+1], s2 = csr[e+2], s3 = csr[e+3];
    float c0 = coef[e], c1 = coef[e+1], c2 = coef[e+2], c3 = coef[e+3];
    float4 v0 = rows[(size_t)s0*32 + fl];
    float4 v1 = rows[(size_t)s1*32 + fl];
    float4 v2 = rows[(size_t)s2*32 + fl];
    float4 v3 = rows[(size_t)s3*32 + fl];
    a0.x=fmaf(c0,v0.x,a0.x); a0.y=fmaf(c0,v0.y,a0.y); a0.z=fmaf(c0,v0.z,a0.z); a0.w=fmaf(c0,v0.w,a0.w);
    a1.x=fmaf(c1,v1.x,a1.x); a1.y=fmaf(c1,v1.y,a1.y); a1.z=fmaf(c1,v1.z,a1.z); a1.w=fmaf(c1,v1.w,a1.w);
    a2.x=fmaf(c2,v2.x,a2.x); a2.y=fmaf(c2,v2.y,a2.y); a2.z=fmaf(c2,v2.z,a2.z); a2.w=fmaf(c2,v2.w,a2.w);
    a3.x=fmaf(c3,v3.x,a3.x); a3.y=fmaf(c3,v3.y,a3.y); a3.z=fmaf(c3,v3.z,a3.z); a3.w=fmaf(c3,v3.w,a3.w);
  }
  for (; e < end; ++e){
    int s0 = csr[e];
    float c0 = coef[e];
    float4 v0 = rows[(size_t)s0*32 + fl];
    a0.x=fmaf(c0,v0.x,a0.x); a0.y=fmaf(c0,v0.y,a0.y); a0.z=fmaf(c0,v0.z,a0.z); a0.w=fmaf(c0,v0.w,a0.w);
  }
  float4 own = rows[(size_t)node*32 + fl];
  float4 bv  = ((const float4*)bias)[fl];
  float d2 = dd*dd;
  float4 rr;
  rr.x = fmaxf(fmaf(d2, own.x, (a0.x+a1.x)+(a2.x+a3.x) + bv.x), 0.f);
  rr.y = fmaxf(fmaf(d2, own.y, (a0.y+a1.y)+(a2.y+a3.y) + bv.y), 0.f);
  rr.z = fmaxf(fmaf(d2, own.z, (a0.z+a1.z)+(a2.z+a3.z) + bv.z), 0.f);
  rr.w = fmaxf(fmaf(d2, own.w, (a0.w+a1.w)+(a2.w+a3.w) + bv.w), 0.f);
  ((float4*)(out + (size_t)node*128))[fl] = rr;
  float4 w = ((const float4*)Ws)[fl];
  float p = rr.x*w.x + rr.y*w.y + rr.z*w.z + rr.w*w.w;
  p += __shfl_xor(p, 16);
  p += __shfl_xor(p, 8);
  p += __shfl_xor(p, 4);
  p += __shfl_xor(p, 2);
  p += __shfl_xor(p, 1);
  if (fl == 0) hs[node] = p;
}

// ---------------- fused score + hybrid bitonic top-k (shfl for j<64, LDS for j>=64) ----------------
template<int NP, int K>
__global__ void topk_score(const float* __restrict__ hs, const int* __restrict__ csr,
                           const float* __restrict__ coef,
                           const int* __restrict__ off, const int* __restrict__ cnt,
                           const float* __restrict__ dinv, const float* __restrict__ bs,
                           float* __restrict__ topv, int* __restrict__ perm,
                           int* __restrict__ newidx){
  __shared__ float sv[NP];
  __shared__ int   si[NP];
  int b = blockIdx.x, t = threadIdx.x;
  int i = b*NP + t;
  float v;
  int idx = t;
  {
    float dd = dinv[i];
    int o = off[i], deg = cnt[i];
    float a0 = 0.f, a1 = 0.f;
    int e = o, end = o + deg;
    for (; e + 1 < end; e += 2){
      int s0 = csr[e], s1 = csr[e+1];
      a0 = fmaf(coef[e],   hs[s0], a0);
      a1 = fmaf(coef[e+1], hs[s1], a1);
    }
    if (e < end){ a0 = fmaf(coef[e], hs[csr[e]], a0); }
    v = a0 + a1 + fmaf(dd*dd, hs[i], bs[0]);
  }
  newidx[i] = -1;
  #pragma unroll
  for (int ksz = 2; ksz <= NP; ksz <<= 1){
    #pragma unroll
    for (int j = ksz >> 1; j > 0; j >>= 1){
      bool dir = ((t & ksz) == 0);
      float v2; int i2;
      if (j >= 64){
        __syncthreads();
        sv[t] = v; si[t] = idx;
        __syncthreads();
        v2 = sv[t^j]; i2 = si[t^j];
      } else {
        v2 = __shfl_xor(v, j);
        i2 = __shfl_xor(idx, j);
      }
      bool pf = (v2 > v) || (v2 == v && i2 < idx);
      bool lower = (t & j) == 0;
      bool take = (pf == (lower ? dir : !dir));
      if (take){ v = v2; idx = i2; }
    }
  }
  // descending order across t; barriers inside the loop ordered the -1 writes
  if (t < K){
    int g = b*NP + idx;
    topv[b*K + t] = v;
    perm[b*K + t] = g;
    newidx[g] = b*K + t;
  }
}

// ---------------- fused xnew = h[perm]*tanh(topv) + partial readout ----------------
template<int S>
__global__ void gather_scale_ro(const float* __restrict__ Hm, const int* __restrict__ perm,
                                const float* __restrict__ topv, float* __restrict__ xnew,
                                float* __restrict__ pmx, float* __restrict__ psm, int k){
  __shared__ float smx[128], ssm[128];
  int b = blockIdx.x / S, s = blockIdx.x % S;
  int t = threadIdx.x;        // 256
  int f = t & 127, h = t >> 7;
  int rows = k / S;
  int j0 = s * rows;
  float mx = -INFINITY, sm = 0.f;
  for (int j = j0 + h; j < j0 + rows; j += 2){
    int idx = b*k + j;
    float tm = tanhf(topv[idx]);
    float v = Hm[(size_t)perm[idx]*128 + f] * tm;
    xnew[(size_t)idx*128 + f] = v;
    mx = fmaxf(mx, v); sm += v;
  }
  if (h == 1){ smx[f] = mx; ssm[f] = sm; }
  __syncthreads();
  if (h == 0){
    mx = fmaxf(mx, smx[f]); sm += ssm[f];
    pmx[(size_t)(b*S+s)*128 + f] = mx;
    psm[(size_t)(b*S+s)*128 + f] = sm;
  }
}

template<int S>
__global__ void readout_fin(const float* __restrict__ pmx, const float* __restrict__ psm,
                            float* __restrict__ out, int k){
  int b = blockIdx.x, f = threadIdx.x;   // 128 threads
  float mx = -INFINITY, sm = 0.f;
  #pragma unroll
  for (int s = 0; s < S; ++s){
    mx = fmaxf(mx, pmx[(size_t)(b*S+s)*128 + f]);
    sm += psm[(size_t)(b*S+s)*128 + f];
  }
  out[b*256 + f]       += mx;
  out[b*256 + 128 + f] += sm / (float)k;
}

// ---------------- edge remap + next-level degree count ----------------
__global__ void remap_edges_cnt(const int* __restrict__ is, const int* __restrict__ id,
                                const int* __restrict__ newidx,
                                int* __restrict__ os, int* __restrict__ od,
                                int* __restrict__ cnt){
  int i = blockIdx.x*blockDim.x + threadIdx.x;
  int s = is[i], d = id[i];
  int ns = -1, nd = -1;
  if ((s | d) >= 0){ ns = newidx[s]; nd = newidx[d]; }
  bool v = (ns >= 0) & (nd >= 0);
  os[i] = v ? ns : -1;
  od[i] = v ? nd : -1;
  if (v) atomicAdd(&cnt[nd], 1);
}

// ---------------- host launcher ----------------
extern "C" void kernel_launch(void* const* d_in, const int* in_sizes, int n_in,
                              void* d_out, int out_size, void* d_ws, size_t ws_size,
                              hipStream_t stream){
  const float* x0 = (const float*)d_in[0];
  const int*   ei = (const int*)d_in[1];
  const float* Wl[3]  = {(const float*)d_in[3], (const float*)d_in[7],  (const float*)d_in[11]};
  const float* bl[3]  = {(const float*)d_in[4], (const float*)d_in[8],  (const float*)d_in[12]};
  const float* Wsl[3] = {(const float*)d_in[5], (const float*)d_in[9],  (const float*)d_in[13]};
  const float* bsl[3] = {(const float*)d_in[6], (const float*)d_in[10], (const float*)d_in[14]};

  // workspace layout (floats)
  float* A     = (float*)d_ws;                   // hx            65536*128
  float* C     = A + (size_t)65536*128;          // h (post agg)  65536*128
  float* D     = C + (size_t)65536*128;          // xnew / next x 32768*128
  float* dinv  = D + (size_t)32768*128;          // 65536
  float* hs    = dinv + 65536;                   // 65536
  float* topv  = hs + 65536;                     // 32768
  int* newidx  = (int*)(topv + 32768);           // 65536
  int* perm    = newidx + 65536;                 // 32768
  int* ea_s    = perm + 32768;                   // 524288
  int* ea_d    = ea_s + ETOT;
  int* eb_s    = ea_d + ETOT;
  int* eb_d    = eb_s + ETOT;
  int* cntA    = eb_d + ETOT;                    // 65536
  int* cntB    = cntA + 65536;                   // 32768
  int* cntC    = cntB + 32768;                   // 16384
  int* off     = cntC + 16384;                   // 65536
  int* csr     = off + 65536;                    // 524288
  float* coef  = (float*)(csr + 524288);         // 524288
  float* pmx   = coef + 524288;                  // 65536
  float* psm   = pmx + 65536;                    // 65536

  hipMemsetAsync(cntA, 0, (size_t)(65536+32768+16384)*sizeof(int), stream);
  hipMemsetAsync(d_out, 0, (size_t)out_size*sizeof(float), stream);

  float* out = (float*)d_out;

  auto level = [&](const float* xin, int n_tot, int np, int k,
                   const float* W, const float* b, const float* Ws, const float* bs,
                   const int* es, const int* ed, int* cnt,
                   int* oes, int* oed, int* ocnt){
    if (np == 512)      scanfill<512><<<BGRAPH,512,0,stream>>>(cnt, es, ed, off, dinv, csr, coef);
    else if (np == 256) scanfill<256><<<BGRAPH,256,0,stream>>>(cnt, es, ed, off, dinv, csr, coef);
    else                scanfill<128><<<BGRAPH,128,0,stream>>>(cnt, es, ed, off, dinv, csr, coef);
    gemm_tile<<<n_tot/64, 256, 0, stream>>>(xin, W, A);
    gather_agg<<<n_tot/8, 256, 0, stream>>>(A, csr, coef, off, cnt, dinv, b, Ws, C, hs, np, n_tot);
    if (np == 512)      topk_score<512,256><<<BGRAPH,512,0,stream>>>(hs, csr, coef, off, cnt, dinv, bs, topv, perm, newidx);
    else if (np == 256) topk_score<256,128><<<BGRAPH,256,0,stream>>>(hs, csr, coef, off, cnt, dinv, bs, topv, perm, newidx);
    else                topk_score<128, 64><<<BGRAPH,128,0,stream>>>(hs, csr, coef, off, cnt, dinv, bs, topv, perm, newidx);
    gather_scale_ro<4><<<BGRAPH*4, 256, 0, stream>>>(C, perm, topv, D, pmx, psm, k);
    if (oes) remap_edges_cnt<<<ETOT/256, 256, 0, stream>>>(es, ed, newidx, oes, oed, ocnt);
    readout_fin<4><<<BGRAPH, 128, 0, stream>>>(pmx, psm, out, k);
  };

  // level 1: degree of the initial (all-valid) edges
  deg_cnt<<<ETOT/256, 256, 0, stream>>>(ei + ETOT, cntA);
  level(x0, 65536, 512, K1, Wl[0], bl[0], Wsl[0], bsl[0],
        ei, ei + ETOT, cntA, ea_s, ea_d, cntB);
  // level 2
  level(D, 32768, 256, K2, Wl[1], bl[1], Wsl[1], bsl[1],
        ea_s, ea_d, cntB, eb_s, eb_d, cntC);
  // level 3
  level(D, 16384, 128, K3, Wl[2], bl[2], Wsl[2], bsl[2],
        eb_s, eb_d, cntC, nullptr, nullptr, nullptr);
}

// Round 9
// 219.838 us; speedup vs baseline: 7.9645x; 1.1479x over previous
//
#include <hip/hip_runtime.h>
#include <math.h>

#define BGRAPH 128
#define ETOT   (128*4096)   // 524288
#define EPG    4096
#define K1 256
#define K2 128
#define K3 64

// ---------------- tiled GEMM v2: Y[n][128] = X[n][128] @ W[128][128] ----------------
// BM=128, BK=32, 256 threads, per-thread 8x8 accumulator.
__global__ __launch_bounds__(256) void gemm_tile2(const float* __restrict__ X,
                                                  const float* __restrict__ W,
                                                  float* __restrict__ Y){
  __shared__ float sA[32][132];   // [k][m], padded
  __shared__ float sB[32][128];   // [k][n]
  int t = threadIdx.x;
  int row0 = blockIdx.x * 128;
  int tx = t & 15;                // col group: cols tx*8..+8
  int ty = t >> 4;                // row group: rows ty*8..+8
  float acc[8][8];
  #pragma unroll
  for (int i = 0; i < 8; ++i)
    #pragma unroll
    for (int j = 0; j < 8; ++j) acc[i][j] = 0.f;

  for (int k0 = 0; k0 < 128; k0 += 32){
    // stage X tile (128 rows x 32 k), transposed into sA[k][m]
    #pragma unroll
    for (int i = 0; i < 4; ++i){
      int f = t + i*256;            // 0..1023
      int row = f >> 3, c4 = f & 7; // c4: which float4 of the 32-k strip
      float4 v = *(const float4*)(X + (size_t)(row0 + row)*128 + k0 + c4*4);
      sA[c4*4+0][row] = v.x;
      sA[c4*4+1][row] = v.y;
      sA[c4*4+2][row] = v.z;
      sA[c4*4+3][row] = v.w;
    }
    // stage W tile (32 k x 128 n) direct
    #pragma unroll
    for (int i = 0; i < 4; ++i){
      int f = t + i*256;            // 0..1023
      int kr = f >> 5, c4 = f & 31;
      *(float4*)&sB[kr][c4*4] = *(const float4*)(W + (size_t)(k0 + kr)*128 + c4*4);
    }
    __syncthreads();
    #pragma unroll
    for (int kk = 0; kk < 32; ++kk){
      float4 a0 = *(const float4*)&sA[kk][ty*8];
      float4 a1 = *(const float4*)&sA[kk][ty*8+4];
      float4 b0 = *(const float4*)&sB[kk][tx*8];
      float4 b1 = *(const float4*)&sB[kk][tx*8+4];
      float aa[8] = {a0.x,a0.y,a0.z,a0.w,a1.x,a1.y,a1.z,a1.w};
      float bb[8] = {b0.x,b0.y,b0.z,b0.w,b1.x,b1.y,b1.z,b1.w};
      #pragma unroll
      for (int i = 0; i < 8; ++i)
        #pragma unroll
        for (int j = 0; j < 8; ++j)
          acc[i][j] = fmaf(aa[i], bb[j], acc[i][j]);
    }
    __syncthreads();
  }
  #pragma unroll
  for (int i = 0; i < 8; ++i){
    float* yr = Y + (size_t)(row0 + ty*8 + i)*128 + tx*8;
    *(float4*)yr       = *(float4*)&acc[i][0];
    *(float4*)(yr + 4) = *(float4*)&acc[i][4];
  }
}

// ---------------- level-1 scanfill: LDS count + scan + CSR fill + coef ----------------
__global__ __launch_bounds__(512) void scanfill_l1(const int* __restrict__ src,
    const int* __restrict__ dst, int* __restrict__ off, int* __restrict__ cnt,
    float* __restrict__ dinv, int* __restrict__ csr, float* __restrict__ coef){
  __shared__ int sc[512], sp[512], cur[512];
  __shared__ float sdv[512];
  __shared__ int ss[EPG], sd[EPG];
  int g = blockIdx.x, t = threadIdx.x;
  sc[t] = 0;
  __syncthreads();
  const int* sg = src + g*EPG;
  const int* dg = dst + g*EPG;
  for (int e = t; e < EPG; e += 512){
    int s = sg[e], d = dg[e];
    ss[e] = s; sd[e] = d;
    atomicAdd(&sc[d & 511], 1);
  }
  __syncthreads();
  int v = sc[t];
  float dv = rsqrtf((float)v + 1.f);
  sdv[t] = dv;
  dinv[g*512 + t] = dv;
  cnt[g*512 + t] = v;
  sp[t] = v;
  __syncthreads();
  for (int d = 1; d < 512; d <<= 1){
    int u = (t >= d) ? sp[t-d] : 0;
    __syncthreads();
    sp[t] += u;
    __syncthreads();
  }
  int pre = sp[t] - v;
  off[g*512 + t] = g*EPG + pre;
  sc[t] = pre;     // loc
  cur[t] = 0;
  __syncthreads();
  int* cg = csr + g*EPG;
  float* cf = coef + g*EPG;
  for (int e = t; e < EPG; e += 512){
    int s = ss[e], dl = sd[e] & 511;
    int slot = sc[dl] + atomicAdd(&cur[dl], 1);
    cg[slot] = s;
    cf[slot] = sdv[s & 511] * sdv[dl];
  }
}

// ---------------- fused aggregation + score GEMV, graph->XCD pinned ----------------
__global__ void gather_agg(const float* __restrict__ hx, const int* __restrict__ csr,
                           const float* __restrict__ coef,
                           const int* __restrict__ off, const int* __restrict__ cnt,
                           const float* __restrict__ dinv, const float* __restrict__ bias,
                           const float* __restrict__ Ws, float* __restrict__ out,
                           float* __restrict__ hs, int npg, int n){
  int bpg = npg >> 3;
  int x = blockIdx.x >> 3, r = blockIdx.x & 7;
  int pos = x % bpg, grp = x / bpg;
  int g = grp*8 + r;
  int t = threadIdx.x;
  int node = g*npg + pos*8 + (t >> 5);
  int fl = t & 31;
  float dd = dinv[node];
  int o = off[node], deg = cnt[node];
  const float4* rows = (const float4*)hx;
  float4 a0 = {0,0,0,0}, a1 = {0,0,0,0}, a2 = {0,0,0,0}, a3 = {0,0,0,0};
  int e = o, end = o + deg;
  for (; e + 3 < end; e += 4){
    int s0 = csr[e], s1 = csr[e+1], s2 = csr[e+2], s3 = csr[e+3];
    float c0 = coef[e], c1 = coef[e+1], c2 = coef[e+2], c3 = coef[e+3];
    float4 v0 = rows[(size_t)s0*32 + fl];
    float4 v1 = rows[(size_t)s1*32 + fl];
    float4 v2 = rows[(size_t)s2*32 + fl];
    float4 v3 = rows[(size_t)s3*32 + fl];
    a0.x=fmaf(c0,v0.x,a0.x); a0.y=fmaf(c0,v0.y,a0.y); a0.z=fmaf(c0,v0.z,a0.z); a0.w=fmaf(c0,v0.w,a0.w);
    a1.x=fmaf(c1,v1.x,a1.x); a1.y=fmaf(c1,v1.y,a1.y); a1.z=fmaf(c1,v1.z,a1.z); a1.w=fmaf(c1,v1.w,a1.w);
    a2.x=fmaf(c2,v2.x,a2.x); a2.y=fmaf(c2,v2.y,a2.y); a2.z=fmaf(c2,v2.z,a2.z); a2.w=fmaf(c2,v2.w,a2.w);
    a3.x=fmaf(c3,v3.x,a3.x); a3.y=fmaf(c3,v3.y,a3.y); a3.z=fmaf(c3,v3.z,a3.z); a3.w=fmaf(c3,v3.w,a3.w);
  }
  for (; e < end; ++e){
    int s0 = csr[e];
    float c0 = coef[e];
    float4 v0 = rows[(size_t)s0*32 + fl];
    a0.x=fmaf(c0,v0.x,a0.x); a0.y=fmaf(c0,v0.y,a0.y); a0.z=fmaf(c0,v0.z,a0.z); a0.w=fmaf(c0,v0.w,a0.w);
  }
  float4 own = rows[(size_t)node*32 + fl];
  float4 bv  = ((const float4*)bias)[fl];
  float d2 = dd*dd;
  float4 rr;
  rr.x = fmaxf(fmaf(d2, own.x, (a0.x+a1.x)+(a2.x+a3.x) + bv.x), 0.f);
  rr.y = fmaxf(fmaf(d2, own.y, (a0.y+a1.y)+(a2.y+a3.y) + bv.y), 0.f);
  rr.z = fmaxf(fmaf(d2, own.z, (a0.z+a1.z)+(a2.z+a3.z) + bv.z), 0.f);
  rr.w = fmaxf(fmaf(d2, own.w, (a0.w+a1.w)+(a2.w+a3.w) + bv.w), 0.f);
  ((float4*)(out + (size_t)node*128))[fl] = rr;
  float4 w = ((const float4*)Ws)[fl];
  float p = rr.x*w.x + rr.y*w.y + rr.z*w.z + rr.w*w.w;
  p += __shfl_xor(p, 16);
  p += __shfl_xor(p, 8);
  p += __shfl_xor(p, 4);
  p += __shfl_xor(p, 2);
  p += __shfl_xor(p, 1);
  if (fl == 0) hs[node] = p;
}

// ---------------- per-graph mega: score+topk (LDS) -> pool+readout -> next scanfill ----------------
// NP = nodes/graph this level; K = keep count (= next level nodes/graph); HASNEXT: build next CSR.
template<int NP, int K, int HASNEXT>
__global__ __launch_bounds__(512) void mega(
    const float* __restrict__ hs, const int* __restrict__ csr_in,
    const float* __restrict__ coef_in, const int* __restrict__ off_in,
    const int* __restrict__ cnt_in, const float* __restrict__ dinv_in,
    const float* __restrict__ bs, const float* __restrict__ Hm,
    float* __restrict__ xnew, float* __restrict__ out,
    const int* pes, const int* ped, int* oes, int* oed,
    int* off_o, int* cnt_o, float* dinv_o, int* csr_o, float* coef_o)
{
  __shared__ float sv[NP];
  __shared__ int   si[NP];
  __shared__ int   lnew[NP];
  __shared__ float ltopv[K];
  __shared__ int   lperm[K];
  __shared__ float smx[512], ssm[512];
  __shared__ int   ss[EPG], sd[EPG];
  __shared__ int   sc[K], sp2[K], cur[K];
  __shared__ float sdvn[K];
  int g = blockIdx.x, t = threadIdx.x;

  // ---- phase 1: score + hybrid bitonic top-k (value desc, index asc) ----
  float v = -INFINITY; int idx = t;
  if (t < NP){
    int i = g*NP + t;
    float dd = dinv_in[i];
    int o = off_in[i], deg = cnt_in[i];
    float a0 = 0.f, a1 = 0.f;
    int e = o, end = o + deg;
    for (; e + 1 < end; e += 2){
      a0 = fmaf(coef_in[e],   hs[csr_in[e]],   a0);
      a1 = fmaf(coef_in[e+1], hs[csr_in[e+1]], a1);
    }
    if (e < end) a0 = fmaf(coef_in[e], hs[csr_in[e]], a0);
    v = a0 + a1 + fmaf(dd*dd, hs[i], bs[0]);
    lnew[t] = -1;
  }
  __syncthreads();
  #pragma unroll
  for (int ksz = 2; ksz <= NP; ksz <<= 1){
    #pragma unroll
    for (int j = ksz >> 1; j > 0; j >>= 1){
      float v2 = 0.f; int i2 = 0;
      if (j >= 64){
        __syncthreads();
        if (t < NP){ sv[t] = v; si[t] = idx; }
        __syncthreads();
        if (t < NP){ v2 = sv[t^j]; i2 = si[t^j]; }
      } else if (t < NP){
        v2 = __shfl_xor(v, j);
        i2 = __shfl_xor(idx, j);
      }
      if (t < NP){
        bool dir = ((t & ksz) == 0);
        bool pf = (v2 > v) || (v2 == v && i2 < idx);
        bool lower = (t & j) == 0;
        if (pf == (lower ? dir : !dir)){ v = v2; idx = i2; }
      }
    }
  }
  if (t < K){ ltopv[t] = v; lperm[t] = idx; lnew[idx] = t; }
  __syncthreads();

  // ---- phase 2: pool gather (xnew = h[perm]*tanh) + readout max/mean ----
  {
    int f = t & 127, q = t >> 7;
    float mx = -INFINITY, sm = 0.f;
    for (int j = q; j < K; j += 4){
      float tm = tanhf(ltopv[j]);
      float val = Hm[(size_t)(g*NP + lperm[j])*128 + f] * tm;
      xnew[(size_t)(g*K + j)*128 + f] = val;
      mx = fmaxf(mx, val); sm += val;
    }
    smx[q*128+f] = mx; ssm[q*128+f] = sm;
    __syncthreads();
    if (q == 0){
      mx = fmaxf(fmaxf(smx[f], smx[128+f]), fmaxf(smx[256+f], smx[384+f]));
      sm = ssm[f] + ssm[128+f] + ssm[256+f] + ssm[384+f];
      out[g*256 + f]       += mx;
      out[g*256 + 128 + f] += sm / (float)K;
    }
  }
  if (!HASNEXT) return;
  __syncthreads();

  // ---- phase 3: remap edges + count + scan + fill next-level CSR/coef ----
  if (t < K) sc[t] = 0;
  __syncthreads();
  for (int e = t; e < EPG; e += 512){
    int s = pes[g*EPG + e], d = ped[g*EPG + e];
    int ns = -1, nd = -1;
    if ((s | d) >= 0){
      int rs = lnew[s & (NP-1)];
      int rd = lnew[d & (NP-1)];
      if (rs >= 0 && rd >= 0){ ns = g*K + rs; nd = g*K + rd; }
    }
    ss[e] = ns; sd[e] = nd;
    oes[g*EPG + e] = ns; oed[g*EPG + e] = nd;
    if (nd >= 0) atomicAdd(&sc[nd & (K-1)], 1);
  }
  __syncthreads();
  int cv = 0; float dvn = 0.f;
  if (t < K){
    cv = sc[t];
    dvn = rsqrtf((float)cv + 1.f);
    sdvn[t] = dvn;
    dinv_o[g*K + t] = dvn;
    cnt_o[g*K + t] = cv;
    sp2[t] = cv;
  }
  __syncthreads();
  for (int d = 1; d < K; d <<= 1){
    int u = (t >= d && t < K) ? sp2[t-d] : 0;
    __syncthreads();
    if (t < K) sp2[t] += u;
    __syncthreads();
  }
  if (t < K){
    int pre = sp2[t] - cv;
    off_o[g*K + t] = g*EPG + pre;
    sc[t] = pre;     // loc
    cur[t] = 0;
  }
  __syncthreads();
  for (int e = t; e < EPG; e += 512){
    int d = sd[e];
    if (d < 0) continue;
    int dl = d & (K-1);
    int slot = sc[dl] + atomicAdd(&cur[dl], 1);
    csr_o[g*EPG + slot] = ss[e];
    coef_o[g*EPG + slot] = sdvn[ss[e] & (K-1)] * sdvn[dl];
  }
}

// ---------------- host launcher ----------------
extern "C" void kernel_launch(void* const* d_in, const int* in_sizes, int n_in,
                              void* d_out, int out_size, void* d_ws, size_t ws_size,
                              hipStream_t stream){
  const float* x0 = (const float*)d_in[0];
  const int*   ei = (const int*)d_in[1];
  const float* Wl[3]  = {(const float*)d_in[3], (const float*)d_in[7],  (const float*)d_in[11]};
  const float* bl[3]  = {(const float*)d_in[4], (const float*)d_in[8],  (const float*)d_in[12]};
  const float* Wsl[3] = {(const float*)d_in[5], (const float*)d_in[9],  (const float*)d_in[13]};
  const float* bsl[3] = {(const float*)d_in[6], (const float*)d_in[10], (const float*)d_in[14]};

  // workspace layout (floats)
  float* A     = (float*)d_ws;                   // hx            65536*128
  float* C     = A + (size_t)65536*128;          // h (post agg)  65536*128
  float* D     = C + (size_t)65536*128;          // xnew / next x 32768*128
  float* dinvA = D + (size_t)32768*128;          // 65536
  float* dinvB = dinvA + 65536;                  // 65536
  float* hs    = dinvB + 65536;                  // 65536
  int* cntA    = (int*)(hs + 65536);             // 65536
  int* cntB    = cntA + 65536;                   // 65536
  int* offA    = cntB + 65536;                   // 65536
  int* offB    = offA + 65536;                   // 65536
  int* csrA    = offB + 65536;                   // 524288
  int* csrB    = csrA + ETOT;                    // 524288
  float* coefA = (float*)(csrB + ETOT);          // 524288
  float* coefB = coefA + ETOT;                   // 524288
  int* ea_s    = (int*)(coefB + ETOT);           // 524288
  int* ea_d    = ea_s + ETOT;                    // 524288

  float* out = (float*)d_out;
  hipMemsetAsync(d_out, 0, (size_t)out_size*sizeof(float), stream);

  // ---- level 1 (NP=512 -> K1=256) ----
  scanfill_l1<<<BGRAPH, 512, 0, stream>>>(ei, ei + ETOT, offA, cntA, dinvA, csrA, coefA);
  gemm_tile2<<<65536/128, 256, 0, stream>>>(x0, Wl[0], A);
  gather_agg<<<65536/8, 256, 0, stream>>>(A, csrA, coefA, offA, cntA, dinvA, bl[0], Wsl[0], C, hs, 512, 65536);
  mega<512, K1, 1><<<BGRAPH, 512, 0, stream>>>(hs, csrA, coefA, offA, cntA, dinvA, bsl[0],
      C, D, out, ei, ei + ETOT, ea_s, ea_d, offB, cntB, dinvB, csrB, coefB);
  // ---- level 2 (NP=256 -> K2=128) ----
  gemm_tile2<<<32768/128, 256, 0, stream>>>(D, Wl[1], A);
  gather_agg<<<32768/8, 256, 0, stream>>>(A, csrB, coefB, offB, cntB, dinvB, bl[1], Wsl[1], C, hs, 256, 32768);
  mega<256, K2, 1><<<BGRAPH, 512, 0, stream>>>(hs, csrB, coefB, offB, cntB, dinvB, bsl[1],
      C, D, out, ea_s, ea_d, ea_s, ea_d, offA, cntA, dinvA, csrA, coefA);
  // ---- level 3 (NP=128 -> K3=64) ----
  gemm_tile2<<<16384/128, 256, 0, stream>>>(D, Wl[2], A);
  gather_agg<<<16384/8, 256, 0, stream>>>(A, csrA, coefA, offA, cntA, dinvA, bl[2], Wsl[2], C, hs, 128, 16384);
  mega<128, K3, 0><<<BGRAPH, 512, 0, stream>>>(hs, csrA, coefA, offA, cntA, dinvA, bsl[2],
      C, D, out, ea_s, ea_d, ea_s, ea_d, offB, cntB, dinvB, csrB, coefB);
}

// Round 10
// 190.144 us; speedup vs baseline: 9.2082x; 1.1562x over previous
//
#include <hip/hip_runtime.h>
#include <math.h>

#define BGRAPH 128
#define ETOT   (128*4096)   // 524288
#define EPG    4096
#define K1 256
#define K2 128
#define K3 64

// ---------------- tiled GEMM v2: Y[n][128] = X[n][128] @ W[128][128] ----------------
__global__ __launch_bounds__(256) void gemm_tile2(const float* __restrict__ X,
                                                  const float* __restrict__ W,
                                                  float* __restrict__ Y){
  __shared__ float sA[32][132];   // [k][m], padded
  __shared__ float sB[32][128];   // [k][n]
  int t = threadIdx.x;
  int row0 = blockIdx.x * 128;
  int tx = t & 15;
  int ty = t >> 4;
  float acc[8][8];
  #pragma unroll
  for (int i = 0; i < 8; ++i)
    #pragma unroll
    for (int j = 0; j < 8; ++j) acc[i][j] = 0.f;

  for (int k0 = 0; k0 < 128; k0 += 32){
    #pragma unroll
    for (int i = 0; i < 4; ++i){
      int f = t + i*256;
      int row = f >> 3, c4 = f & 7;
      float4 v = *(const float4*)(X + (size_t)(row0 + row)*128 + k0 + c4*4);
      sA[c4*4+0][row] = v.x;
      sA[c4*4+1][row] = v.y;
      sA[c4*4+2][row] = v.z;
      sA[c4*4+3][row] = v.w;
    }
    #pragma unroll
    for (int i = 0; i < 4; ++i){
      int f = t + i*256;
      int kr = f >> 5, c4 = f & 31;
      *(float4*)&sB[kr][c4*4] = *(const float4*)(W + (size_t)(k0 + kr)*128 + c4*4);
    }
    __syncthreads();
    #pragma unroll
    for (int kk = 0; kk < 32; ++kk){
      float4 a0 = *(const float4*)&sA[kk][ty*8];
      float4 a1 = *(const float4*)&sA[kk][ty*8+4];
      float4 b0 = *(const float4*)&sB[kk][tx*8];
      float4 b1 = *(const float4*)&sB[kk][tx*8+4];
      float aa[8] = {a0.x,a0.y,a0.z,a0.w,a1.x,a1.y,a1.z,a1.w};
      float bb[8] = {b0.x,b0.y,b0.z,b0.w,b1.x,b1.y,b1.z,b1.w};
      #pragma unroll
      for (int i = 0; i < 8; ++i)
        #pragma unroll
        for (int j = 0; j < 8; ++j)
          acc[i][j] = fmaf(aa[i], bb[j], acc[i][j]);
    }
    __syncthreads();
  }
  #pragma unroll
  for (int i = 0; i < 8; ++i){
    float* yr = Y + (size_t)(row0 + ty*8 + i)*128 + tx*8;
    *(float4*)yr       = *(float4*)&acc[i][0];
    *(float4*)(yr + 4) = *(float4*)&acc[i][4];
  }
}

// ---------------- level-1 scanfill: LDS count + scan + CSR fill + coef ----------------
__global__ __launch_bounds__(1024) void scanfill_l1(const int* __restrict__ src,
    const int* __restrict__ dst, int* __restrict__ off, int* __restrict__ cnt,
    float* __restrict__ dinv, int* __restrict__ csr, float* __restrict__ coef){
  __shared__ int sc[512], sp[512], cur[512];
  __shared__ float sdv[512];
  __shared__ int ss[EPG], sd[EPG];
  int g = blockIdx.x, t = threadIdx.x;
  if (t < 512) sc[t] = 0;
  __syncthreads();
  const int* sg = src + g*EPG;
  const int* dg = dst + g*EPG;
  for (int e = t; e < EPG; e += 1024){
    int s = sg[e], d = dg[e];
    ss[e] = s; sd[e] = d;
    atomicAdd(&sc[d & 511], 1);
  }
  __syncthreads();
  int v = 0; float dv = 0.f;
  if (t < 512){
    v = sc[t];
    dv = rsqrtf((float)v + 1.f);
    sdv[t] = dv;
    dinv[g*512 + t] = dv;
    cnt[g*512 + t] = v;
    sp[t] = v;
  }
  __syncthreads();
  for (int d = 1; d < 512; d <<= 1){
    int u = 0;
    if (t >= d && t < 512) u = sp[t-d];
    __syncthreads();
    if (t < 512) sp[t] += u;
    __syncthreads();
  }
  if (t < 512){
    int pre = sp[t] - v;
    off[g*512 + t] = g*EPG + pre;
    sc[t] = pre;
    cur[t] = 0;
  }
  __syncthreads();
  int* cg = csr + g*EPG;
  float* cf = coef + g*EPG;
  for (int e = t; e < EPG; e += 1024){
    int s = ss[e], dl = sd[e] & 511;
    int slot = sc[dl] + atomicAdd(&cur[dl], 1);
    cg[slot] = s;
    cf[slot] = sdv[s & 511] * sdv[dl];
  }
}

// ---------------- fused aggregation + score GEMV, graph->XCD pinned ----------------
__global__ void gather_agg(const float* __restrict__ hx, const int* __restrict__ csr,
                           const float* __restrict__ coef,
                           const int* __restrict__ off, const int* __restrict__ cnt,
                           const float* __restrict__ dinv, const float* __restrict__ bias,
                           const float* __restrict__ Ws, float* __restrict__ out,
                           float* __restrict__ hs, int npg, int n){
  int bpg = npg >> 3;
  int x = blockIdx.x >> 3, r = blockIdx.x & 7;
  int pos = x % bpg, grp = x / bpg;
  int g = grp*8 + r;
  int t = threadIdx.x;
  int node = g*npg + pos*8 + (t >> 5);
  int fl = t & 31;
  float dd = dinv[node];
  int o = off[node], deg = cnt[node];
  const float4* rows = (const float4*)hx;
  float4 a0 = {0,0,0,0}, a1 = {0,0,0,0}, a2 = {0,0,0,0}, a3 = {0,0,0,0};
  int e = o, end = o + deg;
  for (; e + 3 < end; e += 4){
    int s0 = csr[e], s1 = csr[e+1], s2 = csr[e+2], s3 = csr[e+3];
    float c0 = coef[e], c1 = coef[e+1], c2 = coef[e+2], c3 = coef[e+3];
    float4 v0 = rows[(size_t)s0*32 + fl];
    float4 v1 = rows[(size_t)s1*32 + fl];
    float4 v2 = rows[(size_t)s2*32 + fl];
    float4 v3 = rows[(size_t)s3*32 + fl];
    a0.x=fmaf(c0,v0.x,a0.x); a0.y=fmaf(c0,v0.y,a0.y); a0.z=fmaf(c0,v0.z,a0.z); a0.w=fmaf(c0,v0.w,a0.w);
    a1.x=fmaf(c1,v1.x,a1.x); a1.y=fmaf(c1,v1.y,a1.y); a1.z=fmaf(c1,v1.z,a1.z); a1.w=fmaf(c1,v1.w,a1.w);
    a2.x=fmaf(c2,v2.x,a2.x); a2.y=fmaf(c2,v2.y,a2.y); a2.z=fmaf(c2,v2.z,a2.z); a2.w=fmaf(c2,v2.w,a2.w);
    a3.x=fmaf(c3,v3.x,a3.x); a3.y=fmaf(c3,v3.y,a3.y); a3.z=fmaf(c3,v3.z,a3.z); a3.w=fmaf(c3,v3.w,a3.w);
  }
  for (; e < end; ++e){
    int s0 = csr[e];
    float c0 = coef[e];
    float4 v0 = rows[(size_t)s0*32 + fl];
    a0.x=fmaf(c0,v0.x,a0.x); a0.y=fmaf(c0,v0.y,a0.y); a0.z=fmaf(c0,v0.z,a0.z); a0.w=fmaf(c0,v0.w,a0.w);
  }
  float4 own = rows[(size_t)node*32 + fl];
  float4 bv  = ((const float4*)bias)[fl];
  float d2 = dd*dd;
  float4 rr;
  rr.x = fmaxf(fmaf(d2, own.x, (a0.x+a1.x)+(a2.x+a3.x) + bv.x), 0.f);
  rr.y = fmaxf(fmaf(d2, own.y, (a0.y+a1.y)+(a2.y+a3.y) + bv.y), 0.f);
  rr.z = fmaxf(fmaf(d2, own.z, (a0.z+a1.z)+(a2.z+a3.z) + bv.z), 0.f);
  rr.w = fmaxf(fmaf(d2, own.w, (a0.w+a1.w)+(a2.w+a3.w) + bv.w), 0.f);
  ((float4*)(out + (size_t)node*128))[fl] = rr;
  float4 w = ((const float4*)Ws)[fl];
  float p = rr.x*w.x + rr.y*w.y + rr.z*w.z + rr.w*w.w;
  p += __shfl_xor(p, 16);
  p += __shfl_xor(p, 8);
  p += __shfl_xor(p, 4);
  p += __shfl_xor(p, 2);
  p += __shfl_xor(p, 1);
  if (fl == 0) hs[node] = p;
}

// ---------------- per-graph mega (1024 thr): score+topk -> pool+readout -> next CSR ----------------
// COMPACT: input edge list is compacted (length ecnt_in[g]); outputs are always compacted.
template<int NP, int K, int HASNEXT, int COMPACT>
__global__ __launch_bounds__(1024) void mega(
    const float* __restrict__ hs, const int* __restrict__ csr_in,
    const float* __restrict__ coef_in, const int* __restrict__ off_in,
    const int* __restrict__ cnt_in, const float* __restrict__ dinv_in,
    const float* __restrict__ bs, const float* __restrict__ Hm,
    float* __restrict__ xnew, float* __restrict__ out,
    const int* __restrict__ pes, const int* __restrict__ ped,
    const int* __restrict__ ecnt_in,
    int* __restrict__ off_o, int* __restrict__ cnt_o, float* __restrict__ dinv_o,
    int* __restrict__ csr_o, int* __restrict__ dst_o, float* __restrict__ coef_o,
    int* __restrict__ ecnt_o)
{
  constexpr int R   = 1024 / NP;
  constexpr int LNP = (NP == 512) ? 9 : ((NP == 256) ? 8 : 7);
  __shared__ float shs[NP];
  __shared__ float spart[1024];
  __shared__ float sv[NP];
  __shared__ int   si[NP];
  __shared__ int   lnew[NP];
  __shared__ int   lperm[K];
  __shared__ float ltanh[K];
  __shared__ float smx[1024], ssm[1024];
  __shared__ int   ss[EPG], sd[EPG];
  __shared__ int   sc[K], sp2[K], cur[K];
  __shared__ float sdvn[K];
  int g = blockIdx.x, t = threadIdx.x;

  // ---- phase 0: stage hs for this graph into LDS ----
  if (t < NP){ shs[t] = hs[g*NP + t]; lnew[t] = -1; }
  __syncthreads();

  // ---- phase 1: score (R threads per node) ----
  int n = t & (NP-1);
  int p = t >> LNP;
  {
    int i = g*NP + n;
    int o = off_in[i], deg = cnt_in[i];
    float a = 0.f;
    for (int e = o + p; e < o + deg; e += R)
      a = fmaf(coef_in[e], shs[csr_in[e] & (NP-1)], a);
    spart[t] = a;
  }
  __syncthreads();
  float v = -INFINITY; int idx = n;
  if (p == 0){
    float a = spart[n];
    #pragma unroll
    for (int q = 1; q < R; ++q) a += spart[n + q*NP];
    float dd = dinv_in[g*NP + n];
    v = a + fmaf(dd*dd, shs[n], bs[0]);
  }
  // ---- hybrid bitonic sort among t<NP (value desc, index asc) ----
  #pragma unroll
  for (int ksz = 2; ksz <= NP; ksz <<= 1){
    #pragma unroll
    for (int j = ksz >> 1; j > 0; j >>= 1){
      float v2 = 0.f; int i2 = 0;
      if (j >= 64){
        __syncthreads();
        if (t < NP){ sv[t] = v; si[t] = idx; }
        __syncthreads();
        if (t < NP){ v2 = sv[t^j]; i2 = si[t^j]; }
      } else if (t < NP){
        v2 = __shfl_xor(v, j);
        i2 = __shfl_xor(idx, j);
      }
      if (t < NP){
        bool dir = ((t & ksz) == 0);
        bool pf = (v2 > v) || (v2 == v && i2 < idx);
        bool lower = (t & j) == 0;
        if (pf == (lower ? dir : !dir)){ v = v2; idx = i2; }
      }
    }
  }
  if (t < K){
    lperm[t] = idx;
    lnew[idx] = t;
    ltanh[t] = tanhf(v);
  }
  __syncthreads();

  // ---- phase 2: pool gather + readout ----
  {
    int f = t & 127, q = t >> 7;   // 8 row-groups
    float mx = -INFINITY, sm = 0.f;
    for (int j = q; j < K; j += 8){
      float val = Hm[(size_t)(g*NP + lperm[j])*128 + f] * ltanh[j];
      xnew[(size_t)(g*K + j)*128 + f] = val;
      mx = fmaxf(mx, val); sm += val;
    }
    smx[t] = mx; ssm[t] = sm;
  }
  __syncthreads();
  if (t < 128){
    float mx = smx[t], sm = ssm[t];
    #pragma unroll
    for (int q = 1; q < 8; ++q){ mx = fmaxf(mx, smx[q*128+t]); sm += ssm[q*128+t]; }
    out[g*256 + t]       += mx;
    out[g*256 + 128 + t] += sm / (float)K;
  }
  if (!HASNEXT) return;
  __syncthreads();

  // ---- phase 3: remap + count + scan + fill compacted next-level CSR ----
  if (t < K) sc[t] = 0;
  __syncthreads();
  int E_in = COMPACT ? ecnt_in[g] : EPG;
  for (int e = t; e < E_in; e += 1024){
    int s = pes[g*EPG + e], d = ped[g*EPG + e];
    int rs = lnew[s & (NP-1)], rd = lnew[d & (NP-1)];
    bool ok = (rs | rd) >= 0;       // both >= 0
    ss[e] = rs;
    sd[e] = ok ? rd : -1;
    if (ok) atomicAdd(&sc[rd], 1);
  }
  __syncthreads();
  int cv = 0; float dvn = 0.f;
  if (t < K){
    cv = sc[t];
    dvn = rsqrtf((float)cv + 1.f);
    sdvn[t] = dvn;
    dinv_o[g*K + t] = dvn;
    cnt_o[g*K + t] = cv;
    sp2[t] = cv;
  }
  __syncthreads();
  for (int d = 1; d < K; d <<= 1){
    int u = 0;
    if (t >= d && t < K) u = sp2[t-d];
    __syncthreads();
    if (t < K) sp2[t] += u;
    __syncthreads();
  }
  if (t < K){
    int pre = sp2[t] - cv;
    off_o[g*K + t] = g*EPG + pre;
    sc[t] = pre;
    cur[t] = 0;
    if (t == K-1) ecnt_o[g] = pre + cv;
  }
  __syncthreads();
  for (int e = t; e < E_in; e += 1024){
    int ndl = sd[e];
    if (ndl < 0) continue;
    int nsl = ss[e];
    int slot = sc[ndl] + atomicAdd(&cur[ndl], 1);
    csr_o[g*EPG + slot]  = g*K + nsl;
    dst_o[g*EPG + slot]  = g*K + ndl;
    coef_o[g*EPG + slot] = sdvn[nsl] * sdvn[ndl];
  }
}

// ---------------- host launcher ----------------
extern "C" void kernel_launch(void* const* d_in, const int* in_sizes, int n_in,
                              void* d_out, int out_size, void* d_ws, size_t ws_size,
                              hipStream_t stream){
  const float* x0 = (const float*)d_in[0];
  const int*   ei = (const int*)d_in[1];
  const float* Wl[3]  = {(const float*)d_in[3], (const float*)d_in[7],  (const float*)d_in[11]};
  const float* bl[3]  = {(const float*)d_in[4], (const float*)d_in[8],  (const float*)d_in[12]};
  const float* Wsl[3] = {(const float*)d_in[5], (const float*)d_in[9],  (const float*)d_in[13]};
  const float* bsl[3] = {(const float*)d_in[6], (const float*)d_in[10], (const float*)d_in[14]};

  // workspace layout (floats)
  float* A     = (float*)d_ws;                   // hx            65536*128
  float* C     = A + (size_t)65536*128;          // h (post agg)  65536*128
  float* D     = C + (size_t)65536*128;          // xnew / next x 32768*128
  float* dinvA = D + (size_t)32768*128;          // 65536
  float* dinvB = dinvA + 65536;                  // 65536
  float* hs    = dinvB + 65536;                  // 65536
  int* cntA    = (int*)(hs + 65536);             // 65536
  int* cntB    = cntA + 65536;                   // 65536
  int* offA    = cntB + 65536;                   // 65536
  int* offB    = offA + 65536;                   // 65536
  int* csrA    = offB + 65536;                   // 524288
  int* csrB    = csrA + ETOT;                    // 524288
  int* dstA    = csrB + ETOT;                    // 524288
  int* dstB    = dstA + ETOT;                    // 524288
  float* coefA = (float*)(dstB + ETOT);          // 524288
  float* coefB = coefA + ETOT;                   // 524288
  int* ecntA   = (int*)(coefB + ETOT);           // 128
  int* ecntB   = ecntA + 128;                    // 128

  float* out = (float*)d_out;
  hipMemsetAsync(d_out, 0, (size_t)out_size*sizeof(float), stream);

  // ---- level 1 (NP=512 -> K1=256) ----
  scanfill_l1<<<BGRAPH, 1024, 0, stream>>>(ei, ei + ETOT, offA, cntA, dinvA, csrA, coefA);
  gemm_tile2<<<65536/128, 256, 0, stream>>>(x0, Wl[0], A);
  gather_agg<<<65536/8, 256, 0, stream>>>(A, csrA, coefA, offA, cntA, dinvA, bl[0], Wsl[0], C, hs, 512, 65536);
  mega<512, K1, 1, 0><<<BGRAPH, 1024, 0, stream>>>(hs, csrA, coefA, offA, cntA, dinvA, bsl[0],
      C, D, out, ei, ei + ETOT, ecntA,
      offB, cntB, dinvB, csrB, dstB, coefB, ecntB);
  // ---- level 2 (NP=256 -> K2=128) ----
  gemm_tile2<<<32768/128, 256, 0, stream>>>(D, Wl[1], A);
  gather_agg<<<32768/8, 256, 0, stream>>>(A, csrB, coefB, offB, cntB, dinvB, bl[1], Wsl[1], C, hs, 256, 32768);
  mega<256, K2, 1, 1><<<BGRAPH, 1024, 0, stream>>>(hs, csrB, coefB, offB, cntB, dinvB, bsl[1],
      C, D, out, csrB, dstB, ecntB,
      offA, cntA, dinvA, csrA, dstA, coefA, ecntA);
  // ---- level 3 (NP=128 -> K3=64) ----
  gemm_tile2<<<16384/128, 256, 0, stream>>>(D, Wl[2], A);
  gather_agg<<<16384/8, 256, 0, stream>>>(A, csrA, coefA, offA, cntA, dinvA, bl[2], Wsl[2], C, hs, 128, 16384);
  mega<128, K3, 0, 1><<<BGRAPH, 1024, 0, stream>>>(hs, csrA, coefA, offA, cntA, dinvA, bsl[2],
      C, D, out, csrA, dstA, ecntA,
      offB, cntB, dinvB, csrB, dstB, coefB, ecntB);
}

// Round 11
// 189.965 us; speedup vs baseline: 9.2169x; 1.0009x over previous
//
#include <hip/hip_runtime.h>
#include <math.h>

#define BGRAPH 128
#define ETOT   (128*4096)   // 524288
#define EPG    4096
#define K1 256
#define K2 128
#define K3 64

// ---------------- tiled GEMM v2: Y[n][128] = X[n][128] @ W[128][128] ----------------
__global__ __launch_bounds__(256) void gemm_tile2(const float* __restrict__ X,
                                                  const float* __restrict__ W,
                                                  float* __restrict__ Y){
  __shared__ float sA[32][132];   // [k][m], padded
  __shared__ float sB[32][128];   // [k][n]
  int t = threadIdx.x;
  int row0 = blockIdx.x * 128;
  int tx = t & 15;
  int ty = t >> 4;
  float acc[8][8];
  #pragma unroll
  for (int i = 0; i < 8; ++i)
    #pragma unroll
    for (int j = 0; j < 8; ++j) acc[i][j] = 0.f;

  for (int k0 = 0; k0 < 128; k0 += 32){
    #pragma unroll
    for (int i = 0; i < 4; ++i){
      int f = t + i*256;
      int row = f >> 3, c4 = f & 7;
      float4 v = *(const float4*)(X + (size_t)(row0 + row)*128 + k0 + c4*4);
      sA[c4*4+0][row] = v.x;
      sA[c4*4+1][row] = v.y;
      sA[c4*4+2][row] = v.z;
      sA[c4*4+3][row] = v.w;
    }
    #pragma unroll
    for (int i = 0; i < 4; ++i){
      int f = t + i*256;
      int kr = f >> 5, c4 = f & 31;
      *(float4*)&sB[kr][c4*4] = *(const float4*)(W + (size_t)(k0 + kr)*128 + c4*4);
    }
    __syncthreads();
    #pragma unroll
    for (int kk = 0; kk < 32; ++kk){
      float4 a0 = *(const float4*)&sA[kk][ty*8];
      float4 a1 = *(const float4*)&sA[kk][ty*8+4];
      float4 b0 = *(const float4*)&sB[kk][tx*8];
      float4 b1 = *(const float4*)&sB[kk][tx*8+4];
      float aa[8] = {a0.x,a0.y,a0.z,a0.w,a1.x,a1.y,a1.z,a1.w};
      float bb[8] = {b0.x,b0.y,b0.z,b0.w,b1.x,b1.y,b1.z,b1.w};
      #pragma unroll
      for (int i = 0; i < 8; ++i)
        #pragma unroll
        for (int j = 0; j < 8; ++j)
          acc[i][j] = fmaf(aa[i], bb[j], acc[i][j]);
    }
    __syncthreads();
  }
  #pragma unroll
  for (int i = 0; i < 8; ++i){
    float* yr = Y + (size_t)(row0 + ty*8 + i)*128 + tx*8;
    *(float4*)yr       = *(float4*)&acc[i][0];
    *(float4*)(yr + 4) = *(float4*)&acc[i][4];
  }
}

// ---------------- level-1 scanfill: LDS count + scan + CSR(+dst) fill + coef ----------------
__global__ __launch_bounds__(1024) void scanfill_l1(const int* __restrict__ src,
    const int* __restrict__ dst, int* __restrict__ off, int* __restrict__ cnt,
    float* __restrict__ dinv, int* __restrict__ csr, int* __restrict__ dsto,
    float* __restrict__ coef, int* __restrict__ ecnt){
  __shared__ int sc[512], sp[512], cur[512];
  __shared__ float sdv[512];
  __shared__ int ss[EPG], sd[EPG];
  int g = blockIdx.x, t = threadIdx.x;
  if (t < 512) sc[t] = 0;
  __syncthreads();
  const int* sg = src + g*EPG;
  const int* dg = dst + g*EPG;
  for (int e = t; e < EPG; e += 1024){
    int s = sg[e], d = dg[e];
    ss[e] = s; sd[e] = d;
    atomicAdd(&sc[d & 511], 1);
  }
  __syncthreads();
  int v = 0; float dv = 0.f;
  if (t < 512){
    v = sc[t];
    dv = rsqrtf((float)v + 1.f);
    sdv[t] = dv;
    dinv[g*512 + t] = dv;
    cnt[g*512 + t] = v;
    sp[t] = v;
  }
  __syncthreads();
  for (int d = 1; d < 512; d <<= 1){
    int u = 0;
    if (t >= d && t < 512) u = sp[t-d];
    __syncthreads();
    if (t < 512) sp[t] += u;
    __syncthreads();
  }
  if (t < 512){
    int pre = sp[t] - v;
    off[g*512 + t] = g*EPG + pre;
    sc[t] = pre;
    cur[t] = 0;
  }
  if (t == 0) ecnt[g] = EPG;
  __syncthreads();
  int* cg = csr + g*EPG;
  int* dg2 = dsto + g*EPG;
  float* cf = coef + g*EPG;
  for (int e = t; e < EPG; e += 1024){
    int s = ss[e], dl = sd[e] & 511;
    int slot = sc[dl] + atomicAdd(&cur[dl], 1);
    cg[slot]  = s;
    dg2[slot] = g*512 + dl;
    cf[slot]  = sdv[s & 511] * sdv[dl];
  }
}

// ---------------- fused aggregation + score GEMV, graph->XCD pinned, unroll x8 ----------------
__global__ void gather_agg(const float* __restrict__ hx, const int* __restrict__ csr,
                           const float* __restrict__ coef,
                           const int* __restrict__ off, const int* __restrict__ cnt,
                           const float* __restrict__ dinv, const float* __restrict__ bias,
                           const float* __restrict__ Ws, float* __restrict__ out,
                           float* __restrict__ hs, int npg, int n){
  int bpg = npg >> 3;
  int x = blockIdx.x >> 3, r = blockIdx.x & 7;
  int pos = x % bpg, grp = x / bpg;
  int g = grp*8 + r;
  int t = threadIdx.x;
  int node = g*npg + pos*8 + (t >> 5);
  int fl = t & 31;
  float dd = dinv[node];
  int o = off[node], deg = cnt[node];
  const float4* rows = (const float4*)hx;
  float4 a0 = {0,0,0,0}, a1 = {0,0,0,0}, a2 = {0,0,0,0}, a3 = {0,0,0,0};
  int e = o, end = o + deg;
  for (; e + 7 < end; e += 8){
    int sx[8]; float cx[8]; float4 vv[8];
    #pragma unroll
    for (int q = 0; q < 8; ++q){ sx[q] = csr[e+q]; cx[q] = coef[e+q]; }
    #pragma unroll
    for (int q = 0; q < 8; ++q) vv[q] = rows[(size_t)sx[q]*32 + fl];
    #pragma unroll
    for (int q = 0; q < 8; ++q){
      float4& aq = (q&3)==0 ? a0 : ((q&3)==1 ? a1 : ((q&3)==2 ? a2 : a3));
      aq.x = fmaf(cx[q], vv[q].x, aq.x);
      aq.y = fmaf(cx[q], vv[q].y, aq.y);
      aq.z = fmaf(cx[q], vv[q].z, aq.z);
      aq.w = fmaf(cx[q], vv[q].w, aq.w);
    }
  }
  for (; e + 3 < end; e += 4){
    int sx[4]; float cx[4]; float4 vv[4];
    #pragma unroll
    for (int q = 0; q < 4; ++q){ sx[q] = csr[e+q]; cx[q] = coef[e+q]; }
    #pragma unroll
    for (int q = 0; q < 4; ++q) vv[q] = rows[(size_t)sx[q]*32 + fl];
    #pragma unroll
    for (int q = 0; q < 4; ++q){
      float4& aq = (q==0) ? a0 : ((q==1) ? a1 : ((q==2) ? a2 : a3));
      aq.x = fmaf(cx[q], vv[q].x, aq.x);
      aq.y = fmaf(cx[q], vv[q].y, aq.y);
      aq.z = fmaf(cx[q], vv[q].z, aq.z);
      aq.w = fmaf(cx[q], vv[q].w, aq.w);
    }
  }
  for (; e < end; ++e){
    int s0 = csr[e];
    float c0 = coef[e];
    float4 v0 = rows[(size_t)s0*32 + fl];
    a0.x=fmaf(c0,v0.x,a0.x); a0.y=fmaf(c0,v0.y,a0.y); a0.z=fmaf(c0,v0.z,a0.z); a0.w=fmaf(c0,v0.w,a0.w);
  }
  float4 own = rows[(size_t)node*32 + fl];
  float4 bv  = ((const float4*)bias)[fl];
  float d2 = dd*dd;
  float4 rr;
  rr.x = fmaxf(fmaf(d2, own.x, (a0.x+a1.x)+(a2.x+a3.x) + bv.x), 0.f);
  rr.y = fmaxf(fmaf(d2, own.y, (a0.y+a1.y)+(a2.y+a3.y) + bv.y), 0.f);
  rr.z = fmaxf(fmaf(d2, own.z, (a0.z+a1.z)+(a2.z+a3.z) + bv.z), 0.f);
  rr.w = fmaxf(fmaf(d2, own.w, (a0.w+a1.w)+(a2.w+a3.w) + bv.w), 0.f);
  ((float4*)(out + (size_t)node*128))[fl] = rr;
  float4 w = ((const float4*)Ws)[fl];
  float p = rr.x*w.x + rr.y*w.y + rr.z*w.z + rr.w*w.w;
  p += __shfl_xor(p, 16);
  p += __shfl_xor(p, 8);
  p += __shfl_xor(p, 4);
  p += __shfl_xor(p, 2);
  p += __shfl_xor(p, 1);
  if (fl == 0) hs[node] = p;
}

// ---------------- per-graph mega (1024 thr, LDS-resident edges) ----------------
// FIRST: write out with '=' (kills d_out memset). Edge arrays staged once into LDS.
template<int NP, int K, int HASNEXT, int FIRST>
__global__ __launch_bounds__(1024) void mega(
    const float* __restrict__ hs, const int* __restrict__ csr_in,
    const int* __restrict__ dst_in, const float* __restrict__ coef_in,
    const int* __restrict__ off_in, const int* __restrict__ cnt_in,
    const float* __restrict__ dinv_in, const float* __restrict__ bs,
    const float* __restrict__ Hm, float* __restrict__ xnew, float* __restrict__ out,
    const int* __restrict__ ecnt_in,
    int* __restrict__ off_o, int* __restrict__ cnt_o, float* __restrict__ dinv_o,
    int* __restrict__ csr_o, int* __restrict__ dst_o, float* __restrict__ coef_o,
    int* __restrict__ ecnt_o)
{
  constexpr int R   = 1024 / NP;
  constexpr int LNP = (NP == 512) ? 9 : ((NP == 256) ? 8 : 7);
  __shared__ int   ss[EPG];      // staged csr (global src ids) -> remapped src
  __shared__ int   sd[EPG];      // staged dst (global ids)     -> remapped dst
  __shared__ float scf[EPG];     // staged coef
  __shared__ float shs[NP];
  __shared__ float spart[1024];
  __shared__ float sv[NP];
  __shared__ int   si[NP];
  __shared__ int   lnew[NP];
  __shared__ int   lperm[K];
  __shared__ float ltanh[K];
  __shared__ float smx[1024], ssm[1024];
  __shared__ int   sc[K], sp2[K], cur[K];
  __shared__ float sdvn[K];
  int g = blockIdx.x, t = threadIdx.x;
  int E_in = ecnt_in[g];

  // ---- phase 0: stage everything for this graph into LDS ----
  if (t < NP){ shs[t] = hs[g*NP + t]; lnew[t] = -1; }
  for (int e = t; e < E_in; e += 1024){
    ss[e]  = csr_in[g*EPG + e];
    sd[e]  = dst_in[g*EPG + e];
    scf[e] = coef_in[g*EPG + e];
  }
  __syncthreads();

  // ---- phase 1: score (R threads per node), all from LDS ----
  int n = t & (NP-1);
  int p = t >> LNP;
  {
    int lo = off_in[g*NP + n] - g*EPG, deg = cnt_in[g*NP + n];
    float a = 0.f;
    for (int e = lo + p; e < lo + deg; e += R)
      a = fmaf(scf[e], shs[ss[e] & (NP-1)], a);
    spart[t] = a;
  }
  __syncthreads();
  float v = -INFINITY; int idx = n;
  if (p == 0){
    float a = spart[n];
    #pragma unroll
    for (int q = 1; q < R; ++q) a += spart[n + q*NP];
    float dd = dinv_in[g*NP + n];
    v = a + fmaf(dd*dd, shs[n], bs[0]);
  }
  // ---- hybrid bitonic sort among t<NP (value desc, index asc) ----
  #pragma unroll
  for (int ksz = 2; ksz <= NP; ksz <<= 1){
    #pragma unroll
    for (int j = ksz >> 1; j > 0; j >>= 1){
      float v2 = 0.f; int i2 = 0;
      if (j >= 64){
        __syncthreads();
        if (t < NP){ sv[t] = v; si[t] = idx; }
        __syncthreads();
        if (t < NP){ v2 = sv[t^j]; i2 = si[t^j]; }
      } else if (t < NP){
        v2 = __shfl_xor(v, j);
        i2 = __shfl_xor(idx, j);
      }
      if (t < NP){
        bool dir = ((t & ksz) == 0);
        bool pf = (v2 > v) || (v2 == v && i2 < idx);
        bool lower = (t & j) == 0;
        if (pf == (lower ? dir : !dir)){ v = v2; idx = i2; }
      }
    }
  }
  if (t < K){
    lperm[t] = idx;
    lnew[idx] = t;
    ltanh[t] = tanhf(v);
  }
  __syncthreads();

  // ---- phase 2: pool gather + readout ----
  {
    int f = t & 127, q = t >> 7;   // 8 row-groups
    float mx = -INFINITY, sm = 0.f;
    for (int j = q; j < K; j += 8){
      float val = Hm[(size_t)(g*NP + lperm[j])*128 + f] * ltanh[j];
      xnew[(size_t)(g*K + j)*128 + f] = val;
      mx = fmaxf(mx, val); sm += val;
    }
    smx[t] = mx; ssm[t] = sm;
  }
  __syncthreads();
  if (t < 128){
    float mx = smx[t], sm = ssm[t];
    #pragma unroll
    for (int q = 1; q < 8; ++q){ mx = fmaxf(mx, smx[q*128+t]); sm += ssm[q*128+t]; }
    if (FIRST){
      out[g*256 + t]       = mx;
      out[g*256 + 128 + t] = sm / (float)K;
    } else {
      out[g*256 + t]       += mx;
      out[g*256 + 128 + t] += sm / (float)K;
    }
  }
  if (!HASNEXT) return;
  __syncthreads();

  // ---- phase 3: remap (in LDS) + count + scan + fill compacted next-level CSR ----
  if (t < K) sc[t] = 0;
  __syncthreads();
  for (int e = t; e < E_in; e += 1024){
    int rs = lnew[ss[e] & (NP-1)], rd = lnew[sd[e] & (NP-1)];
    bool ok = (rs | rd) >= 0;
    ss[e] = rs;
    sd[e] = ok ? rd : -1;
    if (ok) atomicAdd(&sc[rd], 1);
  }
  __syncthreads();
  int cv = 0; float dvn = 0.f;
  if (t < K){
    cv = sc[t];
    dvn = rsqrtf((float)cv + 1.f);
    sdvn[t] = dvn;
    dinv_o[g*K + t] = dvn;
    cnt_o[g*K + t] = cv;
    sp2[t] = cv;
  }
  __syncthreads();
  for (int d = 1; d < K; d <<= 1){
    int u = 0;
    if (t >= d && t < K) u = sp2[t-d];
    __syncthreads();
    if (t < K) sp2[t] += u;
    __syncthreads();
  }
  if (t < K){
    int pre = sp2[t] - cv;
    off_o[g*K + t] = g*EPG + pre;
    sc[t] = pre;
    cur[t] = 0;
    if (t == K-1) ecnt_o[g] = pre + cv;
  }
  __syncthreads();
  for (int e = t; e < E_in; e += 1024){
    int ndl = sd[e];
    if (ndl < 0) continue;
    int nsl = ss[e];
    int slot = sc[ndl] + atomicAdd(&cur[ndl], 1);
    csr_o[g*EPG + slot]  = g*K + nsl;
    dst_o[g*EPG + slot]  = g*K + ndl;
    coef_o[g*EPG + slot] = sdvn[nsl] * sdvn[ndl];
  }
}

// ---------------- host launcher ----------------
extern "C" void kernel_launch(void* const* d_in, const int* in_sizes, int n_in,
                              void* d_out, int out_size, void* d_ws, size_t ws_size,
                              hipStream_t stream){
  const float* x0 = (const float*)d_in[0];
  const int*   ei = (const int*)d_in[1];
  const float* Wl[3]  = {(const float*)d_in[3], (const float*)d_in[7],  (const float*)d_in[11]};
  const float* bl[3]  = {(const float*)d_in[4], (const float*)d_in[8],  (const float*)d_in[12]};
  const float* Wsl[3] = {(const float*)d_in[5], (const float*)d_in[9],  (const float*)d_in[13]};
  const float* bsl[3] = {(const float*)d_in[6], (const float*)d_in[10], (const float*)d_in[14]};

  // workspace layout (floats)
  float* A     = (float*)d_ws;                   // hx            65536*128
  float* C     = A + (size_t)65536*128;          // h (post agg)  65536*128
  float* D     = C + (size_t)65536*128;          // xnew / next x 32768*128
  float* dinvA = D + (size_t)32768*128;          // 65536
  float* dinvB = dinvA + 65536;                  // 65536
  float* hs    = dinvB + 65536;                  // 65536
  int* cntA    = (int*)(hs + 65536);             // 65536
  int* cntB    = cntA + 65536;                   // 65536
  int* offA    = cntB + 65536;                   // 65536
  int* offB    = offA + 65536;                   // 65536
  int* csrA    = offB + 65536;                   // 524288
  int* csrB    = csrA + ETOT;                    // 524288
  int* dstA    = csrB + ETOT;                    // 524288
  int* dstB    = dstA + ETOT;                    // 524288
  float* coefA = (float*)(dstB + ETOT);          // 524288
  float* coefB = coefA + ETOT;                   // 524288
  int* ecntA   = (int*)(coefB + ETOT);           // 128
  int* ecntB   = ecntA + 128;                    // 128

  float* out = (float*)d_out;

  // ---- level 1 (NP=512 -> K1=256) ----
  scanfill_l1<<<BGRAPH, 1024, 0, stream>>>(ei, ei + ETOT, offA, cntA, dinvA, csrA, dstA, coefA, ecntA);
  gemm_tile2<<<65536/128, 256, 0, stream>>>(x0, Wl[0], A);
  gather_agg<<<65536/8, 256, 0, stream>>>(A, csrA, coefA, offA, cntA, dinvA, bl[0], Wsl[0], C, hs, 512, 65536);
  mega<512, K1, 1, 1><<<BGRAPH, 1024, 0, stream>>>(hs, csrA, dstA, coefA, offA, cntA, dinvA, bsl[0],
      C, D, out, ecntA, offB, cntB, dinvB, csrB, dstB, coefB, ecntB);
  // ---- level 2 (NP=256 -> K2=128) ----
  gemm_tile2<<<32768/128, 256, 0, stream>>>(D, Wl[1], A);
  gather_agg<<<32768/8, 256, 0, stream>>>(A, csrB, coefB, offB, cntB, dinvB, bl[1], Wsl[1], C, hs, 256, 32768);
  mega<256, K2, 1, 0><<<BGRAPH, 1024, 0, stream>>>(hs, csrB, dstB, coefB, offB, cntB, dinvB, bsl[1],
      C, D, out, ecntB, offA, cntA, dinvA, csrA, dstA, coefA, ecntA);
  // ---- level 3 (NP=128 -> K3=64) ----
  gemm_tile2<<<16384/128, 256, 0, stream>>>(D, Wl[2], A);
  gather_agg<<<16384/8, 256, 0, stream>>>(A, csrA, coefA, offA, cntA, dinvA, bl[2], Wsl[2], C, hs, 128, 16384);
  mega<128, K3, 0, 0><<<BGRAPH, 1024, 0, stream>>>(hs, csrA, dstA, coefA, offA, cntA, dinvA, bsl[2],
      C, D, out, ecntA, offB, cntB, dinvB, csrB, dstB, coefB, ecntB);
}

// Round 12
// 189.708 us; speedup vs baseline: 9.2294x; 1.0014x over previous
//
#include <hip/hip_runtime.h>
#include <math.h>

#define BGRAPH 128
#define ETOT   (128*4096)   // 524288
#define EPG    4096
#define K1 256
#define K2 128
#define K3 64

// ---------------- tiled GEMM v3: Y[n][128] = X[n][128] @ W[128][128] ----------------
// BM=128, BK=32, 256 threads, 8x8 acc. Conflict-free LDS by construction:
//   sA[128][33] natural layout: scalar writes (2-way even = free), scalar reads (bcast, distinct banks)
//   sB[32][192]: 16 groups x (8 floats + 4 pad): aligned b128 reads at 2-round minimum
__global__ __launch_bounds__(256) void gemm_tile3(const float* __restrict__ X,
                                                  const float* __restrict__ W,
                                                  float* __restrict__ Y){
  __shared__ float sA[128][33];
  __shared__ float sB[32][192];
  int t = threadIdx.x;
  int row0 = blockIdx.x * 128;
  int tx = t & 15;                // col group: cols tx*8..+8
  int ty = t >> 4;                // row group: rows ty*8..+8
  float acc[8][8];
  #pragma unroll
  for (int i = 0; i < 8; ++i)
    #pragma unroll
    for (int j = 0; j < 8; ++j) acc[i][j] = 0.f;

  for (int k0 = 0; k0 < 128; k0 += 32){
    // stage A (natural layout, scalar writes)
    #pragma unroll
    for (int i = 0; i < 4; ++i){
      int f = t + i*256;
      int row = f >> 3, c4 = f & 7;
      float4 v = *(const float4*)(X + (size_t)(row0 + row)*128 + k0 + c4*4);
      sA[row][c4*4+0] = v.x;
      sA[row][c4*4+1] = v.y;
      sA[row][c4*4+2] = v.z;
      sA[row][c4*4+3] = v.w;
    }
    // stage B (group-padded layout)
    #pragma unroll
    for (int i = 0; i < 4; ++i){
      int f = t + i*256;
      int kr = f >> 5, c4 = f & 31;   // c4: which float4 of the 128-col row
      int gg = c4 >> 1, hh = c4 & 1;
      float4 v = *(const float4*)(W + (size_t)(k0 + kr)*128 + c4*4);
      *(float4*)&sB[kr][gg*12 + hh*4] = v;
    }
    __syncthreads();
    #pragma unroll
    for (int kk = 0; kk < 32; ++kk){
      float4 b0 = *(const float4*)&sB[kk][tx*12];
      float4 b1 = *(const float4*)&sB[kk][tx*12 + 4];
      float aa[8];
      #pragma unroll
      for (int i = 0; i < 8; ++i) aa[i] = sA[ty*8 + i][kk];
      float bb[8] = {b0.x,b0.y,b0.z,b0.w,b1.x,b1.y,b1.z,b1.w};
      #pragma unroll
      for (int i = 0; i < 8; ++i)
        #pragma unroll
        for (int j = 0; j < 8; ++j)
          acc[i][j] = fmaf(aa[i], bb[j], acc[i][j]);
    }
    __syncthreads();
  }
  #pragma unroll
  for (int i = 0; i < 8; ++i){
    float* yr = Y + (size_t)(row0 + ty*8 + i)*128 + tx*8;
    *(float4*)yr       = *(float4*)&acc[i][0];
    *(float4*)(yr + 4) = *(float4*)&acc[i][4];
  }
}

// ---------------- level-1 scanfill: LDS count + scan + CSR(+dst) fill + coef ----------------
__global__ __launch_bounds__(1024) void scanfill_l1(const int* __restrict__ src,
    const int* __restrict__ dst, int* __restrict__ off, int* __restrict__ cnt,
    float* __restrict__ dinv, int* __restrict__ csr, int* __restrict__ dsto,
    float* __restrict__ coef, int* __restrict__ ecnt){
  __shared__ int sc[512], sp[512], cur[512];
  __shared__ float sdv[512];
  __shared__ int ss[EPG], sd[EPG];
  int g = blockIdx.x, t = threadIdx.x;
  if (t < 512) sc[t] = 0;
  __syncthreads();
  const int* sg = src + g*EPG;
  const int* dg = dst + g*EPG;
  for (int e = t; e < EPG; e += 1024){
    int s = sg[e], d = dg[e];
    ss[e] = s; sd[e] = d;
    atomicAdd(&sc[d & 511], 1);
  }
  __syncthreads();
  int v = 0; float dv = 0.f;
  if (t < 512){
    v = sc[t];
    dv = rsqrtf((float)v + 1.f);
    sdv[t] = dv;
    dinv[g*512 + t] = dv;
    cnt[g*512 + t] = v;
    sp[t] = v;
  }
  __syncthreads();
  for (int d = 1; d < 512; d <<= 1){
    int u = 0;
    if (t >= d && t < 512) u = sp[t-d];
    __syncthreads();
    if (t < 512) sp[t] += u;
    __syncthreads();
  }
  if (t < 512){
    int pre = sp[t] - v;
    off[g*512 + t] = g*EPG + pre;
    sc[t] = pre;
    cur[t] = 0;
  }
  if (t == 0) ecnt[g] = EPG;
  __syncthreads();
  int* cg = csr + g*EPG;
  int* dg2 = dsto + g*EPG;
  float* cf = coef + g*EPG;
  for (int e = t; e < EPG; e += 1024){
    int s = ss[e], dl = sd[e] & 511;
    int slot = sc[dl] + atomicAdd(&cur[dl], 1);
    cg[slot]  = s;
    dg2[slot] = g*512 + dl;
    cf[slot]  = sdv[s & 511] * sdv[dl];
  }
}

// ---------------- fused aggregation + score GEMV, graph->XCD pinned, unroll x8 ----------------
__global__ void gather_agg(const float* __restrict__ hx, const int* __restrict__ csr,
                           const float* __restrict__ coef,
                           const int* __restrict__ off, const int* __restrict__ cnt,
                           const float* __restrict__ dinv, const float* __restrict__ bias,
                           const float* __restrict__ Ws, float* __restrict__ out,
                           float* __restrict__ hs, int npg, int n){
  int bpg = npg >> 3;
  int x = blockIdx.x >> 3, r = blockIdx.x & 7;
  int pos = x % bpg, grp = x / bpg;
  int g = grp*8 + r;
  int t = threadIdx.x;
  int node = g*npg + pos*8 + (t >> 5);
  int fl = t & 31;
  float dd = dinv[node];
  int o = off[node], deg = cnt[node];
  const float4* rows = (const float4*)hx;
  float4 a0 = {0,0,0,0}, a1 = {0,0,0,0}, a2 = {0,0,0,0}, a3 = {0,0,0,0};
  int e = o, end = o + deg;
  for (; e + 7 < end; e += 8){
    int sx[8]; float cx[8]; float4 vv[8];
    #pragma unroll
    for (int q = 0; q < 8; ++q){ sx[q] = csr[e+q]; cx[q] = coef[e+q]; }
    #pragma unroll
    for (int q = 0; q < 8; ++q) vv[q] = rows[(size_t)sx[q]*32 + fl];
    #pragma unroll
    for (int q = 0; q < 8; ++q){
      float4& aq = (q&3)==0 ? a0 : ((q&3)==1 ? a1 : ((q&3)==2 ? a2 : a3));
      aq.x = fmaf(cx[q], vv[q].x, aq.x);
      aq.y = fmaf(cx[q], vv[q].y, aq.y);
      aq.z = fmaf(cx[q], vv[q].z, aq.z);
      aq.w = fmaf(cx[q], vv[q].w, aq.w);
    }
  }
  for (; e + 3 < end; e += 4){
    int sx[4]; float cx[4]; float4 vv[4];
    #pragma unroll
    for (int q = 0; q < 4; ++q){ sx[q] = csr[e+q]; cx[q] = coef[e+q]; }
    #pragma unroll
    for (int q = 0; q < 4; ++q) vv[q] = rows[(size_t)sx[q]*32 + fl];
    #pragma unroll
    for (int q = 0; q < 4; ++q){
      float4& aq = (q==0) ? a0 : ((q==1) ? a1 : ((q==2) ? a2 : a3));
      aq.x = fmaf(cx[q], vv[q].x, aq.x);
      aq.y = fmaf(cx[q], vv[q].y, aq.y);
      aq.z = fmaf(cx[q], vv[q].z, aq.z);
      aq.w = fmaf(cx[q], vv[q].w, aq.w);
    }
  }
  for (; e < end; ++e){
    int s0 = csr[e];
    float c0 = coef[e];
    float4 v0 = rows[(size_t)s0*32 + fl];
    a0.x=fmaf(c0,v0.x,a0.x); a0.y=fmaf(c0,v0.y,a0.y); a0.z=fmaf(c0,v0.z,a0.z); a0.w=fmaf(c0,v0.w,a0.w);
  }
  float4 own = rows[(size_t)node*32 + fl];
  float4 bv  = ((const float4*)bias)[fl];
  float d2 = dd*dd;
  float4 rr;
  rr.x = fmaxf(fmaf(d2, own.x, (a0.x+a1.x)+(a2.x+a3.x) + bv.x), 0.f);
  rr.y = fmaxf(fmaf(d2, own.y, (a0.y+a1.y)+(a2.y+a3.y) + bv.y), 0.f);
  rr.z = fmaxf(fmaf(d2, own.z, (a0.z+a1.z)+(a2.z+a3.z) + bv.z), 0.f);
  rr.w = fmaxf(fmaf(d2, own.w, (a0.w+a1.w)+(a2.w+a3.w) + bv.w), 0.f);
  ((float4*)(out + (size_t)node*128))[fl] = rr;
  float4 w = ((const float4*)Ws)[fl];
  float p = rr.x*w.x + rr.y*w.y + rr.z*w.z + rr.w*w.w;
  p += __shfl_xor(p, 16);
  p += __shfl_xor(p, 8);
  p += __shfl_xor(p, 4);
  p += __shfl_xor(p, 2);
  p += __shfl_xor(p, 1);
  if (fl == 0) hs[node] = p;
}

// ---------------- per-graph mega (1024 thr, LDS-resident edges) ----------------
template<int NP, int K, int HASNEXT, int FIRST>
__global__ __launch_bounds__(1024) void mega(
    const float* __restrict__ hs, const int* __restrict__ csr_in,
    const int* __restrict__ dst_in, const float* __restrict__ coef_in,
    const int* __restrict__ off_in, const int* __restrict__ cnt_in,
    const float* __restrict__ dinv_in, const float* __restrict__ bs,
    const float* __restrict__ Hm, float* __restrict__ xnew, float* __restrict__ out,
    const int* __restrict__ ecnt_in,
    int* __restrict__ off_o, int* __restrict__ cnt_o, float* __restrict__ dinv_o,
    int* __restrict__ csr_o, int* __restrict__ dst_o, float* __restrict__ coef_o,
    int* __restrict__ ecnt_o)
{
  constexpr int R   = 1024 / NP;
  constexpr int LNP = (NP == 512) ? 9 : ((NP == 256) ? 8 : 7);
  __shared__ int   ss[EPG];
  __shared__ int   sd[EPG];
  __shared__ float scf[EPG];
  __shared__ float shs[NP];
  __shared__ float spart[1024];
  __shared__ float sv[NP];
  __shared__ int   si[NP];
  __shared__ int   lnew[NP];
  __shared__ int   lperm[K];
  __shared__ float ltanh[K];
  __shared__ float smx[1024], ssm[1024];
  __shared__ int   sc[K], sp2[K], cur[K];
  __shared__ float sdvn[K];
  int g = blockIdx.x, t = threadIdx.x;
  int E_in = ecnt_in[g];

  if (t < NP){ shs[t] = hs[g*NP + t]; lnew[t] = -1; }
  for (int e = t; e < E_in; e += 1024){
    ss[e]  = csr_in[g*EPG + e];
    sd[e]  = dst_in[g*EPG + e];
    scf[e] = coef_in[g*EPG + e];
  }
  __syncthreads();

  int n = t & (NP-1);
  int p = t >> LNP;
  {
    int lo = off_in[g*NP + n] - g*EPG, deg = cnt_in[g*NP + n];
    float a = 0.f;
    for (int e = lo + p; e < lo + deg; e += R)
      a = fmaf(scf[e], shs[ss[e] & (NP-1)], a);
    spart[t] = a;
  }
  __syncthreads();
  float v = -INFINITY; int idx = n;
  if (p == 0){
    float a = spart[n];
    #pragma unroll
    for (int q = 1; q < R; ++q) a += spart[n + q*NP];
    float dd = dinv_in[g*NP + n];
    v = a + fmaf(dd*dd, shs[n], bs[0]);
  }
  #pragma unroll
  for (int ksz = 2; ksz <= NP; ksz <<= 1){
    #pragma unroll
    for (int j = ksz >> 1; j > 0; j >>= 1){
      float v2 = 0.f; int i2 = 0;
      if (j >= 64){
        __syncthreads();
        if (t < NP){ sv[t] = v; si[t] = idx; }
        __syncthreads();
        if (t < NP){ v2 = sv[t^j]; i2 = si[t^j]; }
      } else if (t < NP){
        v2 = __shfl_xor(v, j);
        i2 = __shfl_xor(idx, j);
      }
      if (t < NP){
        bool dir = ((t & ksz) == 0);
        bool pf = (v2 > v) || (v2 == v && i2 < idx);
        bool lower = (t & j) == 0;
        if (pf == (lower ? dir : !dir)){ v = v2; idx = i2; }
      }
    }
  }
  if (t < K){
    lperm[t] = idx;
    lnew[idx] = t;
    ltanh[t] = tanhf(v);
  }
  __syncthreads();

  {
    int f = t & 127, q = t >> 7;
    float mx = -INFINITY, sm = 0.f;
    for (int j = q; j < K; j += 8){
      float val = Hm[(size_t)(g*NP + lperm[j])*128 + f] * ltanh[j];
      xnew[(size_t)(g*K + j)*128 + f] = val;
      mx = fmaxf(mx, val); sm += val;
    }
    smx[t] = mx; ssm[t] = sm;
  }
  __syncthreads();
  if (t < 128){
    float mx = smx[t], sm = ssm[t];
    #pragma unroll
    for (int q = 1; q < 8; ++q){ mx = fmaxf(mx, smx[q*128+t]); sm += ssm[q*128+t]; }
    if (FIRST){
      out[g*256 + t]       = mx;
      out[g*256 + 128 + t] = sm / (float)K;
    } else {
      out[g*256 + t]       += mx;
      out[g*256 + 128 + t] += sm / (float)K;
    }
  }
  if (!HASNEXT) return;
  __syncthreads();

  if (t < K) sc[t] = 0;
  __syncthreads();
  for (int e = t; e < E_in; e += 1024){
    int rs = lnew[ss[e] & (NP-1)], rd = lnew[sd[e] & (NP-1)];
    bool ok = (rs | rd) >= 0;
    ss[e] = rs;
    sd[e] = ok ? rd : -1;
    if (ok) atomicAdd(&sc[rd], 1);
  }
  __syncthreads();
  int cv = 0; float dvn = 0.f;
  if (t < K){
    cv = sc[t];
    dvn = rsqrtf((float)cv + 1.f);
    sdvn[t] = dvn;
    dinv_o[g*K + t] = dvn;
    cnt_o[g*K + t] = cv;
    sp2[t] = cv;
  }
  __syncthreads();
  for (int d = 1; d < K; d <<= 1){
    int u = 0;
    if (t >= d && t < K) u = sp2[t-d];
    __syncthreads();
    if (t < K) sp2[t] += u;
    __syncthreads();
  }
  if (t < K){
    int pre = sp2[t] - cv;
    off_o[g*K + t] = g*EPG + pre;
    sc[t] = pre;
    cur[t] = 0;
    if (t == K-1) ecnt_o[g] = pre + cv;
  }
  __syncthreads();
  for (int e = t; e < E_in; e += 1024){
    int ndl = sd[e];
    if (ndl < 0) continue;
    int nsl = ss[e];
    int slot = sc[ndl] + atomicAdd(&cur[ndl], 1);
    csr_o[g*EPG + slot]  = g*K + nsl;
    dst_o[g*EPG + slot]  = g*K + ndl;
    coef_o[g*EPG + slot] = sdvn[nsl] * sdvn[ndl];
  }
}

// ---------------- host launcher ----------------
extern "C" void kernel_launch(void* const* d_in, const int* in_sizes, int n_in,
                              void* d_out, int out_size, void* d_ws, size_t ws_size,
                              hipStream_t stream){
  const float* x0 = (const float*)d_in[0];
  const int*   ei = (const int*)d_in[1];
  const float* Wl[3]  = {(const float*)d_in[3], (const float*)d_in[7],  (const float*)d_in[11]};
  const float* bl[3]  = {(const float*)d_in[4], (const float*)d_in[8],  (const float*)d_in[12]};
  const float* Wsl[3] = {(const float*)d_in[5], (const float*)d_in[9],  (const float*)d_in[13]};
  const float* bsl[3] = {(const float*)d_in[6], (const float*)d_in[10], (const float*)d_in[14]};

  // workspace layout (floats)
  float* A     = (float*)d_ws;                   // hx            65536*128
  float* C     = A + (size_t)65536*128;          // h (post agg)  65536*128
  float* D     = C + (size_t)65536*128;          // xnew / next x 32768*128
  float* dinvA = D + (size_t)32768*128;          // 65536
  float* dinvB = dinvA + 65536;                  // 65536
  float* hs    = dinvB + 65536;                  // 65536
  int* cntA    = (int*)(hs + 65536);             // 65536
  int* cntB    = cntA + 65536;                   // 65536
  int* offA    = cntB + 65536;                   // 65536
  int* offB    = offA + 65536;                   // 65536
  int* csrA    = offB + 65536;                   // 524288
  int* csrB    = csrA + ETOT;                    // 524288
  int* dstA    = csrB + ETOT;                    // 524288
  int* dstB    = dstA + ETOT;                    // 524288
  float* coefA = (float*)(dstB + ETOT);          // 524288
  float* coefB = coefA + ETOT;                   // 524288
  int* ecntA   = (int*)(coefB + ETOT);           // 128
  int* ecntB   = ecntA + 128;                    // 128

  float* out = (float*)d_out;

  // ---- level 1 (NP=512 -> K1=256) ----
  scanfill_l1<<<BGRAPH, 1024, 0, stream>>>(ei, ei + ETOT, offA, cntA, dinvA, csrA, dstA, coefA, ecntA);
  gemm_tile3<<<65536/128, 256, 0, stream>>>(x0, Wl[0], A);
  gather_agg<<<65536/8, 256, 0, stream>>>(A, csrA, coefA, offA, cntA, dinvA, bl[0], Wsl[0], C, hs, 512, 65536);
  mega<512, K1, 1, 1><<<BGRAPH, 1024, 0, stream>>>(hs, csrA, dstA, coefA, offA, cntA, dinvA, bsl[0],
      C, D, out, ecntA, offB, cntB, dinvB, csrB, dstB, coefB, ecntB);
  // ---- level 2 (NP=256 -> K2=128) ----
  gemm_tile3<<<32768/128, 256, 0, stream>>>(D, Wl[1], A);
  gather_agg<<<32768/8, 256, 0, stream>>>(A, csrB, coefB, offB, cntB, dinvB, bl[1], Wsl[1], C, hs, 256, 32768);
  mega<256, K2, 1, 0><<<BGRAPH, 1024, 0, stream>>>(hs, csrB, dstB, coefB, offB, cntB, dinvB, bsl[1],
      C, D, out, ecntB, offA, cntA, dinvA, csrA, dstA, coefA, ecntA);
  // ---- level 3 (NP=128 -> K3=64) ----
  gemm_tile3<<<16384/128, 256, 0, stream>>>(D, Wl[2], A);
  gather_agg<<<16384/8, 256, 0, stream>>>(A, csrA, coefA, offA, cntA, dinvA, bl[2], Wsl[2], C, hs, 128, 16384);
  mega<128, K3, 0, 0><<<BGRAPH, 1024, 0, stream>>>(hs, csrA, dstA, coefA, offA, cntA, dinvA, bsl[2],
      C, D, out, ecntA, offB, cntB, dinvB, csrB, dstB, coefB, ecntB);
}